// Round 1
// baseline (4526.922 us; speedup 1.0000x reference)
//
#include <hip/hip_runtime.h>
#include <hip/hip_bf16.h>
#include <stdint.h>

#define B_ 2
#define S_ 1024
#define E_ 512
#define H_ 8
#define D_ 64
#define M_ 2048
#define V_ 32000
#define L_ 2

// ---------------- numpy legacy RandomState (MT19937) ----------------
struct MTState { unsigned int mt[624]; int idx; };

__device__ void mt_seed(MTState* st, unsigned int s) {
    for (int i = 0; i < 624; ++i) {
        st->mt[i] = s;
        s = 1812433253u * (s ^ (s >> 30)) + (unsigned int)(i + 1);
    }
    st->idx = 624;
}

__device__ unsigned int mt_next(MTState* st) {
    if (st->idx >= 624) {
        for (int i = 0; i < 624; ++i) {
            unsigned int y = (st->mt[i] & 0x80000000u) | (st->mt[(i + 1) % 624] & 0x7fffffffu);
            unsigned int v = st->mt[(i + 397) % 624] ^ (y >> 1);
            if (y & 1u) v ^= 0x9908b0dfu;
            st->mt[i] = v;
        }
        st->idx = 0;
    }
    unsigned int y = st->mt[st->idx++];
    y ^= y >> 11;
    y ^= (y << 7) & 0x9d2c5680u;
    y ^= (y << 15) & 0xefc60000u;
    y ^= y >> 18;
    return y;
}

// numpy random_interval: uniform in [0, mx], mask + reject
__device__ unsigned int rk_interval(MTState* st, unsigned int mx) {
    if (mx == 0u) return 0u;
    unsigned int mask = mx;
    mask |= mask >> 1; mask |= mask >> 2; mask |= mask >> 4;
    mask |= mask >> 8; mask |= mask >> 16;
    unsigned int v;
    while ((v = (mt_next(st) & mask)) > mx) {}
    return v;
}

// 4 block masks (16x16 u8): [self L0 (seed 1000), self L1 (1001), cross L0 (0), cross L1 (1)]
__global__ void build_masks_kernel(unsigned char* masks) {
    int t = threadIdx.x;
    if (t >= 4) return;
    const unsigned int seeds[4] = {1000u, 1001u, 0u, 1u};
    unsigned char* m = masks + t * 256;
    for (int i = 0; i < 16; ++i)
        for (int j = 0; j < 16; ++j) {
            bool v = (j >= i - 1 && j <= i + 1) || i == 0 || i == 15 || j == 0 || j == 15;
            m[i * 16 + j] = v ? 1 : 0;
        }
    MTState st;
    mt_seed(&st, seeds[t]);
    for (int i = 0; i < 16; ++i) {
        int arr[16];
        for (int j = 0; j < 16; ++j) arr[j] = j;
        // legacy shuffle: i = n-1 .. 1, j = interval([0,i])
        for (int k = 15; k > 0; --k) {
            unsigned int j = rk_interval(&st, (unsigned int)k);
            int tmp = arr[k]; arr[k] = arr[j]; arr[j] = tmp;
        }
        m[i * 16 + arr[0]] = 1;
        m[i * 16 + arr[1]] = 1;
        m[i * 16 + arr[2]] = 1;
    }
}

// ---------------- embedding: y = table[shifted] + pos ----------------
__global__ void embed_kernel(const int* __restrict__ targets,
                             const float* __restrict__ table,
                             const float* __restrict__ pos,
                             float* __restrict__ y) {
    int row = blockIdx.x;            // b*S + s
    int s = row & (S_ - 1);
    int b = row >> 10;
    int id = (s == 0) ? 0 : targets[b * S_ + s - 1];
    int c = threadIdx.x * 4;
    float4 e = *(const float4*)&table[(size_t)id * E_ + c];
    float4 p = *(const float4*)&pos[(size_t)s * E_ + c];
    e.x += p.x; e.y += p.y; e.z += p.z; e.w += p.w;
    *(float4*)&y[(size_t)row * E_ + c] = e;
}

// ---------------- layernorm over E=512, one row per block ----------------
__global__ __launch_bounds__(256)
void ln_kernel(const float* __restrict__ x, float* __restrict__ y,
               const float* __restrict__ sc, const float* __restrict__ bi) {
    int row = blockIdx.x;
    int t = threadIdx.x;
    const float* xr = x + (size_t)row * E_;
    float2 v = *(const float2*)&xr[t * 2];
    float sum = v.x + v.y;
    float sq = v.x * v.x + v.y * v.y;
    for (int off = 32; off > 0; off >>= 1) {
        sum += __shfl_xor(sum, off);
        sq  += __shfl_xor(sq, off);
    }
    __shared__ float s0[4], s1[4];
    int w = t >> 6;
    if ((t & 63) == 0) { s0[w] = sum; s1[w] = sq; }
    __syncthreads();
    sum = s0[0] + s0[1] + s0[2] + s0[3];
    sq  = s1[0] + s1[1] + s1[2] + s1[3];
    float mu = sum * (1.0f / (float)E_);
    float var = sq * (1.0f / (float)E_) - mu * mu;
    float rs = rsqrtf(var + 1e-6f);
    float2 s2 = *(const float2*)&sc[t * 2];
    float2 b2 = *(const float2*)&bi[t * 2];
    float2 o;
    o.x = (v.x - mu) * rs * s2.x + b2.x;
    o.y = (v.y - mu) * rs * s2.y + b2.y;
    *(float2*)&y[(size_t)row * E_ + t * 2] = o;
}

// ---------------- fp32 GEMM: C = alpha*A@W (+bias)(relu)(+resid) ----------------
// A: MxK row-major, W: KxN row-major, C: MxN. M%64==0, N%64==0, K%16==0.
__global__ __launch_bounds__(256)
void gemm_kernel(const float* __restrict__ A, const float* __restrict__ W,
                 const float* __restrict__ bias, const float* __restrict__ resid,
                 float* __restrict__ C, int M, int N, int K, float alpha, int relu)
{
    __shared__ float As[64][20];
    __shared__ float Ws[16][68];
    int t = threadIdx.x;
    int n0 = blockIdx.x * 64, m0 = blockIdx.y * 64;
    int tx = t & 15, ty = t >> 4;
    int am = t >> 2, ak = (t & 3) * 4;   // A-loader: row am, 4 k's
    int wr = t >> 4, wc = (t & 15) * 4;  // W-loader: k-row wr, 4 n's
    float acc[4][4] = {};
    for (int k0 = 0; k0 < K; k0 += 16) {
        __syncthreads();
        float4 av = *(const float4*)&A[(size_t)(m0 + am) * K + k0 + ak];
        float4 wv = *(const float4*)&W[(size_t)(k0 + wr) * N + n0 + wc];
        *(float4*)&As[am][ak] = av;
        *(float4*)&Ws[wr][wc] = wv;
        __syncthreads();
        #pragma unroll
        for (int kk = 0; kk < 16; ++kk) {
            float a0 = As[ty * 4 + 0][kk];
            float a1 = As[ty * 4 + 1][kk];
            float a2 = As[ty * 4 + 2][kk];
            float a3 = As[ty * 4 + 3][kk];
            float4 w4 = *(const float4*)&Ws[kk][tx * 4];
            acc[0][0] += a0 * w4.x; acc[0][1] += a0 * w4.y; acc[0][2] += a0 * w4.z; acc[0][3] += a0 * w4.w;
            acc[1][0] += a1 * w4.x; acc[1][1] += a1 * w4.y; acc[1][2] += a1 * w4.z; acc[1][3] += a1 * w4.w;
            acc[2][0] += a2 * w4.x; acc[2][1] += a2 * w4.y; acc[2][2] += a2 * w4.z; acc[2][3] += a2 * w4.w;
            acc[3][0] += a3 * w4.x; acc[3][1] += a3 * w4.y; acc[3][2] += a3 * w4.z; acc[3][3] += a3 * w4.w;
        }
    }
    #pragma unroll
    for (int i = 0; i < 4; ++i) {
        int row = m0 + ty * 4 + i;
        float* cp = &C[(size_t)row * N + n0 + tx * 4];
        const float* rp = resid ? &resid[(size_t)row * N + n0 + tx * 4] : nullptr;
        #pragma unroll
        for (int j = 0; j < 4; ++j) {
            float val = acc[i][j] * alpha;
            if (bias) val += bias[n0 + tx * 4 + j];
            if (relu) val = fmaxf(val, 0.0f);
            if (rp) val += rp[j];
            cp[j] = val;
        }
    }
}

// ---------------- flash-style attention ----------------
// q,k,v,o layout: (B,S,H,D) fp32. One wave per q-row, 8 waves/block share K/V tiles.
// mask = blockmask[qb][kb] && padq && padk && (!causal || kg<=qi); fully-masked rows -> uniform.
__global__ __launch_bounds__(512)
void attn_kernel(const float* __restrict__ q, const float* __restrict__ k,
                 const float* __restrict__ v, float* __restrict__ o,
                 const unsigned char* __restrict__ bm,
                 const int* __restrict__ targets,
                 const float* __restrict__ srcmask,
                 int causal)
{
    __shared__ float Kt[64][65];   // Kt[d][j]
    __shared__ float Vs[64][65];   // Vs[j][d]
    __shared__ float Qs[8][64];
    int bid = blockIdx.x;
    int qc = bid & 127;
    int h = (bid >> 7) & 7;
    int b = bid >> 10;
    int w = threadIdx.x >> 6, lane = threadIdx.x & 63;
    int qi = qc * 8 + w;
    Qs[w][lane] = q[(((size_t)b * S_ + qi) * H_ + h) * D_ + lane];
    bool padq = targets[b * S_ + qi] > 0;
    int qb = qi >> 6;
    float m = -3.0e38f, l = 0.0f, acc = 0.0f;
    int lj = threadIdx.x >> 3;        // 0..63 source row
    int ld = (threadIdx.x & 7) * 8;   // d chunk
    for (int kb = 0; kb < 16; ++kb) {
        __syncthreads();
        {
            const float* kp = &k[(((size_t)b * S_ + kb * 64 + lj) * H_ + h) * D_ + ld];
            const float* vp = &v[(((size_t)b * S_ + kb * 64 + lj) * H_ + h) * D_ + ld];
            float4 k0 = *(const float4*)kp;
            float4 k1 = *(const float4*)(kp + 4);
            float4 v0 = *(const float4*)vp;
            float4 v1 = *(const float4*)(vp + 4);
            Kt[ld + 0][lj] = k0.x; Kt[ld + 1][lj] = k0.y; Kt[ld + 2][lj] = k0.z; Kt[ld + 3][lj] = k0.w;
            Kt[ld + 4][lj] = k1.x; Kt[ld + 5][lj] = k1.y; Kt[ld + 6][lj] = k1.z; Kt[ld + 7][lj] = k1.w;
            Vs[lj][ld + 0] = v0.x; Vs[lj][ld + 1] = v0.y; Vs[lj][ld + 2] = v0.z; Vs[lj][ld + 3] = v0.w;
            Vs[lj][ld + 4] = v1.x; Vs[lj][ld + 5] = v1.y; Vs[lj][ld + 6] = v1.z; Vs[lj][ld + 7] = v1.w;
        }
        __syncthreads();
        int kg = kb * 64 + lane;
        bool padk = srcmask ? (srcmask[b * S_ + kg] > 0.0f) : (targets[b * S_ + kg] > 0);
        bool allowed = (bm[qb * 16 + kb] != 0) && padq && padk && (!causal || kg <= qi);
        float s = 0.0f;
        #pragma unroll
        for (int d = 0; d < 64; ++d) s += Qs[w][d] * Kt[d][lane];
        s = allowed ? s : -1e9f;
        float mt = s;
        for (int off = 32; off > 0; off >>= 1) mt = fmaxf(mt, __shfl_xor(mt, off));
        float mnew = fmaxf(m, mt);
        float scale = expf(m - mnew);
        float p = expf(s - mnew);
        float ps = p;
        for (int off = 32; off > 0; off >>= 1) ps += __shfl_xor(ps, off);
        l = l * scale + ps;
        acc *= scale;
        #pragma unroll
        for (int kk = 0; kk < 64; ++kk) {
            acc += __shfl(p, kk) * Vs[kk][lane];
        }
        m = mnew;
    }
    o[(((size_t)b * S_ + qi) * H_ + h) * D_ + lane] = acc / l;
}

extern "C" void kernel_launch(void* const* d_in, const int* in_sizes, int n_in,
                              void* d_out, int out_size, void* d_ws, size_t ws_size,
                              hipStream_t stream)
{
    const float* encoded  = (const float*)d_in[0];
    const float* srcmask  = (const float*)d_in[1];
    const int*   targets  = (const int*)d_in[2];
    const float* table    = (const float*)d_in[3];
    const float* pos      = (const float*)d_in[4];
    const float* ln1_s = (const float*)d_in[5];
    const float* ln1_b = (const float*)d_in[6];
    const float* ln2_s = (const float*)d_in[7];
    const float* ln2_b = (const float*)d_in[8];
    const float* ln3_s = (const float*)d_in[9];
    const float* ln3_b = (const float*)d_in[10];
    const float* self_wq = (const float*)d_in[11];
    const float* self_wk = (const float*)d_in[12];
    const float* self_wv = (const float*)d_in[13];
    const float* self_wo = (const float*)d_in[14];
    const float* cross_wq = (const float*)d_in[15];
    const float* cross_wk = (const float*)d_in[16];
    const float* cross_wv = (const float*)d_in[17];
    const float* cross_wo = (const float*)d_in[18];
    const float* mlp_w1 = (const float*)d_in[19];
    const float* mlp_b1 = (const float*)d_in[20];
    const float* mlp_w2 = (const float*)d_in[21];
    const float* mlp_b2 = (const float*)d_in[22];
    const float* final_s = (const float*)d_in[23];
    const float* final_b = (const float*)d_in[24];
    const float* logit_w = (const float*)d_in[25];
    const float* logit_b = (const float*)d_in[26];
    float* out = (float*)d_out;

    char* ws = (char*)d_ws;
    unsigned char* masks = (unsigned char*)ws;
    size_t off = 1024;
    auto alloc = [&](size_t bytes) {
        float* p = (float*)(ws + off);
        off += (bytes + 255) & ~(size_t)255;
        return p;
    };
    const size_t BSE = (size_t)B_ * S_ * E_ * sizeof(float);  // 4 MB
    float* y   = alloc(BSE);
    float* ln  = alloc(BSE);
    float* qb  = alloc(BSE);
    float* kb  = alloc(BSE);
    float* vb  = alloc(BSE);
    float* ob  = alloc(BSE);
    float* xb  = alloc(BSE);
    float* zb  = alloc(BSE);
    float* mlp = qb;  // reuse q..o (16 MB contiguous), dead during MLP

    const int R = B_ * S_;  // 2048

    build_masks_kernel<<<1, 64, 0, stream>>>(masks);
    embed_kernel<<<R, 128, 0, stream>>>(targets, table, pos, y);

    dim3 gp(E_ / 64, R / 64);
    dim3 g1(M_ / 64, R / 64);
    dim3 gl(V_ / 64, R / 64);
    int attn_grid = B_ * H_ * (S_ / 8);

    for (int l = 0; l < L_; ++l) {
        // ---- self attention ----
        ln_kernel<<<R, 256, 0, stream>>>(y, ln, ln1_s + l * E_, ln1_b + l * E_);
        gemm_kernel<<<gp, 256, 0, stream>>>(ln, self_wq + (size_t)l * E_ * E_, nullptr, nullptr, qb, R, E_, E_, 0.125f, 0);
        gemm_kernel<<<gp, 256, 0, stream>>>(ln, self_wk + (size_t)l * E_ * E_, nullptr, nullptr, kb, R, E_, E_, 1.0f, 0);
        gemm_kernel<<<gp, 256, 0, stream>>>(ln, self_wv + (size_t)l * E_ * E_, nullptr, nullptr, vb, R, E_, E_, 1.0f, 0);
        attn_kernel<<<attn_grid, 512, 0, stream>>>(qb, kb, vb, ob, masks + l * 256, targets, nullptr, 1);
        gemm_kernel<<<gp, 256, 0, stream>>>(ob, self_wo + (size_t)l * E_ * E_, nullptr, y, xb, R, E_, E_, 1.0f, 0);
        // ---- cross attention ----
        ln_kernel<<<R, 256, 0, stream>>>(xb, ln, ln2_s + l * E_, ln2_b + l * E_);
        gemm_kernel<<<gp, 256, 0, stream>>>(ln, cross_wq + (size_t)l * E_ * E_, nullptr, nullptr, qb, R, E_, E_, 0.125f, 0);
        gemm_kernel<<<gp, 256, 0, stream>>>(encoded, cross_wk + (size_t)l * E_ * E_, nullptr, nullptr, kb, R, E_, E_, 1.0f, 0);
        gemm_kernel<<<gp, 256, 0, stream>>>(encoded, cross_wv + (size_t)l * E_ * E_, nullptr, nullptr, vb, R, E_, E_, 1.0f, 0);
        attn_kernel<<<attn_grid, 512, 0, stream>>>(qb, kb, vb, ob, masks + (2 + l) * 256, targets, srcmask, 0);
        gemm_kernel<<<gp, 256, 0, stream>>>(ob, cross_wo + (size_t)l * E_ * E_, nullptr, xb, zb, R, E_, E_, 1.0f, 0);
        // ---- MLP ----
        ln_kernel<<<R, 256, 0, stream>>>(zb, ln, ln3_s + l * E_, ln3_b + l * E_);
        gemm_kernel<<<g1, 256, 0, stream>>>(ln, mlp_w1 + (size_t)l * E_ * M_, mlp_b1 + (size_t)l * M_, nullptr, mlp, R, M_, E_, 1.0f, 1);
        gemm_kernel<<<gp, 256, 0, stream>>>(mlp, mlp_w2 + (size_t)l * M_ * E_, mlp_b2 + (size_t)l * E_, zb, y, R, E_, M_, 1.0f, 0);
    }

    ln_kernel<<<R, 256, 0, stream>>>(y, ln, final_s, final_b);
    gemm_kernel<<<gl, 256, 0, stream>>>(ln, logit_w, logit_b, nullptr, out, R, V_, E_, 1.0f, 0);
}

// Round 2
// 1994.381 us; speedup vs baseline: 2.2698x; 2.2698x over previous
//
#include <hip/hip_runtime.h>
#include <hip/hip_bf16.h>
#include <stdint.h>

#define B_ 2
#define S_ 1024
#define E_ 512
#define H_ 8
#define D_ 64
#define M_ 2048
#define V_ 32000
#define L_ 2

typedef __hip_bfloat16 bf16;
typedef __attribute__((ext_vector_type(8))) short short8;
typedef __attribute__((ext_vector_type(4))) float f32x4;

// ---------------- numpy legacy RandomState (MT19937) ----------------
struct MTState { unsigned int mt[624]; int idx; };

__device__ void mt_seed(MTState* st, unsigned int s) {
    for (int i = 0; i < 624; ++i) {
        st->mt[i] = s;
        s = 1812433253u * (s ^ (s >> 30)) + (unsigned int)(i + 1);
    }
    st->idx = 624;
}

__device__ unsigned int mt_next(MTState* st) {
    if (st->idx >= 624) {
        for (int i = 0; i < 624; ++i) {
            unsigned int y = (st->mt[i] & 0x80000000u) | (st->mt[(i + 1) % 624] & 0x7fffffffu);
            unsigned int v = st->mt[(i + 397) % 624] ^ (y >> 1);
            if (y & 1u) v ^= 0x9908b0dfu;
            st->mt[i] = v;
        }
        st->idx = 0;
    }
    unsigned int y = st->mt[st->idx++];
    y ^= y >> 11;
    y ^= (y << 7) & 0x9d2c5680u;
    y ^= (y << 15) & 0xefc60000u;
    y ^= y >> 18;
    return y;
}

__device__ unsigned int rk_interval(MTState* st, unsigned int mx) {
    if (mx == 0u) return 0u;
    unsigned int mask = mx;
    mask |= mask >> 1; mask |= mask >> 2; mask |= mask >> 4;
    mask |= mask >> 8; mask |= mask >> 16;
    unsigned int v;
    while ((v = (mt_next(st) & mask)) > mx) {}
    return v;
}

__global__ void build_masks_kernel(unsigned char* masks) {
    int t = threadIdx.x;
    if (t >= 4) return;
    const unsigned int seeds[4] = {1000u, 1001u, 0u, 1u};
    unsigned char* m = masks + t * 256;
    for (int i = 0; i < 16; ++i)
        for (int j = 0; j < 16; ++j) {
            bool v = (j >= i - 1 && j <= i + 1) || i == 0 || i == 15 || j == 0 || j == 15;
            m[i * 16 + j] = v ? 1 : 0;
        }
    MTState st;
    mt_seed(&st, seeds[t]);
    for (int i = 0; i < 16; ++i) {
        int arr[16];
        for (int j = 0; j < 16; ++j) arr[j] = j;
        for (int k = 15; k > 0; --k) {
            unsigned int j = rk_interval(&st, (unsigned int)k);
            int tmp = arr[k]; arr[k] = arr[j]; arr[j] = tmp;
        }
        m[i * 16 + arr[0]] = 1;
        m[i * 16 + arr[1]] = 1;
        m[i * 16 + arr[2]] = 1;
    }
}

// ---------------- embedding: y = table[shifted] + pos (f32 master) ----------------
__global__ void embed_kernel(const int* __restrict__ targets,
                             const float* __restrict__ table,
                             const float* __restrict__ pos,
                             float* __restrict__ y) {
    int row = blockIdx.x;
    int s = row & (S_ - 1);
    int b = row >> 10;
    int id = (s == 0) ? 0 : targets[b * S_ + s - 1];
    int c = threadIdx.x * 4;
    float4 e = *(const float4*)&table[(size_t)id * E_ + c];
    float4 p = *(const float4*)&pos[(size_t)s * E_ + c];
    e.x += p.x; e.y += p.y; e.z += p.z; e.w += p.w;
    *(float4*)&y[(size_t)row * E_ + c] = e;
}

// ---------------- layernorm f32 -> bf16 ----------------
__global__ __launch_bounds__(256)
void ln_kernel(const float* __restrict__ x, bf16* __restrict__ y,
               const float* __restrict__ sc, const float* __restrict__ bi) {
    int row = blockIdx.x;
    int t = threadIdx.x;
    const float* xr = x + (size_t)row * E_;
    float2 v = *(const float2*)&xr[t * 2];
    float sum = v.x + v.y;
    float sq = v.x * v.x + v.y * v.y;
    for (int off = 32; off > 0; off >>= 1) {
        sum += __shfl_xor(sum, off);
        sq  += __shfl_xor(sq, off);
    }
    __shared__ float s0[4], s1[4];
    int w = t >> 6;
    if ((t & 63) == 0) { s0[w] = sum; s1[w] = sq; }
    __syncthreads();
    sum = s0[0] + s0[1] + s0[2] + s0[3];
    sq  = s1[0] + s1[1] + s1[2] + s1[3];
    float mu = sum * (1.0f / (float)E_);
    float var = sq * (1.0f / (float)E_) - mu * mu;
    float rs = rsqrtf(var + 1e-6f);
    float2 s2 = *(const float2*)&sc[t * 2];
    float2 b2 = *(const float2*)&bi[t * 2];
    bf16* yr = y + (size_t)row * E_ + t * 2;
    yr[0] = __float2bfloat16((v.x - mu) * rs * s2.x + b2.x);
    yr[1] = __float2bfloat16((v.y - mu) * rs * s2.y + b2.y);
}

// ---------------- transpose+convert: W[K][N] f32 -> Wt[N][K] bf16 ----------------
__global__ __launch_bounds__(256)
void tconv_kernel(const float* __restrict__ W, bf16* __restrict__ Wt,
                  int K, int N, size_t src_stride, size_t dst_stride) {
    __shared__ float Ts[32][33];
    const float* Wb = W + blockIdx.z * src_stride;
    bf16* Wtb = Wt + blockIdx.z * dst_stride;
    int k0 = blockIdx.x * 32, n0 = blockIdx.y * 32;
    int lx = threadIdx.x & 31, ly = threadIdx.x >> 5;
    for (int r = ly; r < 32; r += 8)
        Ts[r][lx] = Wb[(size_t)(k0 + r) * N + n0 + lx];
    __syncthreads();
    for (int r = ly; r < 32; r += 8)
        Wtb[(size_t)(n0 + r) * K + k0 + lx] = __float2bfloat16(Ts[lx][r]);
}

// ---------------- f32 -> bf16 elementwise ----------------
__global__ void cvt_kernel(const float* __restrict__ x, bf16* __restrict__ y) {
    int i = (blockIdx.x * blockDim.x + threadIdx.x) * 4;
    float4 v = *(const float4*)&x[i];
    y[i + 0] = __float2bfloat16(v.x);
    y[i + 1] = __float2bfloat16(v.y);
    y[i + 2] = __float2bfloat16(v.z);
    y[i + 3] = __float2bfloat16(v.w);
}

// ---------------- vmean[b][h][d] = mean_s v[b][s][h][d] ----------------
__global__ __launch_bounds__(512)
void vmean_kernel(const bf16* __restrict__ v, float* __restrict__ vm) {
    int bh = blockIdx.x; int b = bh >> 3, h = bh & 7;
    int d = threadIdx.x & 63, sl = threadIdx.x >> 6;
    const unsigned short* vu = (const unsigned short*)v;
    float s = 0.0f;
    for (int si = sl; si < S_; si += 8) {
        unsigned short u = vu[(((size_t)b * S_ + si) * H_ + h) * D_ + d];
        s += __uint_as_float((unsigned)u << 16);
    }
    __shared__ float red[512];
    red[threadIdx.x] = s;
    __syncthreads();
    if (sl == 0) {
        float tot = 0.0f;
        for (int j = 0; j < 8; ++j) tot += red[j * 64 + d];
        vm[bh * D_ + d] = tot * (1.0f / (float)S_);
    }
}

// ---------------- bf16 MFMA GEMM (m97 structure) ----------------
// C[M][N] = alpha * A[M][K](bf16,rm) @ Wt[N][K](bf16,rm)^T  (+bias)(relu)(+resid f32)
// BM=BN=128, BK=64, 256 threads (4 waves, 2x2), per-wave 64x64 = 4x4 16x16 frags.
// LDS: linear [128][64] bf16 tiles, XOR-swizzled via pre-swizzled global source (rule #21).
template<int OBF>
__global__ __launch_bounds__(256)
void gemm_mfma(const bf16* __restrict__ A, const bf16* __restrict__ Wt,
               const float* __restrict__ bias, const float* __restrict__ resid,
               void* __restrict__ Cv, int M, int N, int K, float alpha, int relu)
{
    __shared__ bf16 As[128 * 64];
    __shared__ bf16 Bs[128 * 64];
    const int t = threadIdx.x;
    const int lane = t & 63, w = t >> 6;
    const int n0 = blockIdx.x * 128, m0 = blockIdx.y * 128;
    const int wr = w >> 1, wc = w & 1;
    const int srow = w * 8 + (lane >> 3);   // staging row within 32-row chunk group
    const int sslot = lane & 7;             // 16B slot within 128B row
    f32x4 acc[4][4] = {};

    for (int k0 = 0; k0 < K; k0 += 64) {
        __syncthreads();
        #pragma unroll
        for (int i = 0; i < 4; ++i) {
            int r = i * 32 + srow;
            int gslot = sslot ^ (r & 7);
            const bf16* ga = A  + (size_t)(m0 + r) * K + k0 + gslot * 8;
            const bf16* gb = Wt + (size_t)(n0 + r) * K + k0 + gslot * 8;
            __builtin_amdgcn_global_load_lds((const __attribute__((address_space(1))) void*)ga,
                                             (__attribute__((address_space(3))) void*)&As[r * 64 + sslot * 8],
                                             16, 0, 0);
            __builtin_amdgcn_global_load_lds((const __attribute__((address_space(1))) void*)gb,
                                             (__attribute__((address_space(3))) void*)&Bs[r * 64 + sslot * 8],
                                             16, 0, 0);
        }
        __syncthreads();
        #pragma unroll
        for (int kk = 0; kk < 2; ++kk) {
            short8 af[4], bq[4];
            const int q = kk * 4 + (lane >> 4);
            #pragma unroll
            for (int m = 0; m < 4; ++m) {
                int r = wr * 64 + m * 16 + (lane & 15);
                af[m] = *(const short8*)&As[r * 64 + (q ^ (r & 7)) * 8];
            }
            #pragma unroll
            for (int n = 0; n < 4; ++n) {
                int r = wc * 64 + n * 16 + (lane & 15);
                bq[n] = *(const short8*)&Bs[r * 64 + (q ^ (r & 7)) * 8];
            }
            #pragma unroll
            for (int m = 0; m < 4; ++m)
                #pragma unroll
                for (int n = 0; n < 4; ++n)
                    acc[m][n] = __builtin_amdgcn_mfma_f32_16x16x32_bf16(af[m], bq[n], acc[m][n], 0, 0, 0);
        }
    }

    const int lr = lane >> 4, lc = lane & 15;
    #pragma unroll
    for (int n = 0; n < 4; ++n) {
        int col = n0 + wc * 64 + n * 16 + lc;
        float bv = bias ? bias[col] : 0.0f;
        #pragma unroll
        for (int m = 0; m < 4; ++m) {
            #pragma unroll
            for (int r = 0; r < 4; ++r) {
                int row = m0 + wr * 64 + m * 16 + lr * 4 + r;
                float val = acc[m][n][r] * alpha + bv;
                if (relu) val = fmaxf(val, 0.0f);
                if (resid) val += resid[(size_t)row * N + col];
                if (OBF) ((bf16*)Cv)[(size_t)row * N + col] = __float2bfloat16(val);
                else     ((float*)Cv)[(size_t)row * N + col] = val;
            }
        }
    }
}

// ---------------- flash attention, bf16 in/out, exact block skip ----------------
// Skipped blocks contribute exp(-1e9 - m) == 0.0f exactly in fp32 (same as reference).
// padq=false rows: reference softmax is uniform over ALL S -> output = mean(V) = vmean.
__global__ __launch_bounds__(512)
void attn_kernel(const bf16* __restrict__ q, const bf16* __restrict__ k,
                 const bf16* __restrict__ v, bf16* __restrict__ o,
                 const unsigned char* __restrict__ bm,
                 const int* __restrict__ targets,
                 const float* __restrict__ srcmask,
                 const float* __restrict__ vmean,
                 int causal)
{
    __shared__ float Kt[64][65];
    __shared__ float Vs[64][65];
    __shared__ float Qs[8][64];
    int bid = blockIdx.x;
    int qc = bid & 127;
    int h = (bid >> 7) & 7;
    int b = bid >> 10;
    int w = threadIdx.x >> 6, lane = threadIdx.x & 63;
    int qi = qc * 8 + w;
    const unsigned short* qu = (const unsigned short*)q;
    const unsigned short* ku = (const unsigned short*)k;
    const unsigned short* vu = (const unsigned short*)v;
    Qs[w][lane] = __uint_as_float((unsigned)qu[(((size_t)b * S_ + qi) * H_ + h) * D_ + lane] << 16);
    bool padq = targets[b * S_ + qi] > 0;
    int qb = qi >> 6;
    float m = -3.0e38f, l = 0.0f, acc = 0.0f;
    int lj = threadIdx.x >> 3;
    int ld = (threadIdx.x & 7) * 8;
    int kbmax = causal ? qb : 15;
    for (int kb = 0; kb <= kbmax; ++kb) {
        if (!bm[qb * 16 + kb]) continue;   // block-uniform
        __syncthreads();
        {
            const unsigned short* kp = &ku[(((size_t)b * S_ + kb * 64 + lj) * H_ + h) * D_ + ld];
            const unsigned short* vp = &vu[(((size_t)b * S_ + kb * 64 + lj) * H_ + h) * D_ + ld];
            short8 k8 = *(const short8*)kp;
            short8 v8 = *(const short8*)vp;
            #pragma unroll
            for (int j = 0; j < 8; ++j) {
                Kt[ld + j][lj] = __uint_as_float((unsigned)(unsigned short)k8[j] << 16);
                Vs[lj][ld + j] = __uint_as_float((unsigned)(unsigned short)v8[j] << 16);
            }
        }
        __syncthreads();
        int kg = kb * 64 + lane;
        bool padk = srcmask ? (srcmask[b * S_ + kg] > 0.0f) : (targets[b * S_ + kg] > 0);
        bool allowed = padq && padk && (!causal || kg <= qi);
        float s = 0.0f;
        #pragma unroll
        for (int d = 0; d < 64; ++d) s += Qs[w][d] * Kt[d][lane];
        s = allowed ? s : -1e9f;
        float mt = s;
        for (int off = 32; off > 0; off >>= 1) mt = fmaxf(mt, __shfl_xor(mt, off));
        float mnew = fmaxf(m, mt);
        float scale = expf(m - mnew);
        float p = expf(s - mnew);
        float ps = p;
        for (int off = 32; off > 0; off >>= 1) ps += __shfl_xor(ps, off);
        l = l * scale + ps;
        acc *= scale;
        #pragma unroll
        for (int kk = 0; kk < 64; ++kk) {
            acc += __shfl(p, kk) * Vs[kk][lane];
        }
        m = mnew;
    }
    float res = padq ? (acc / l) : vmean[(b * 8 + h) * 64 + lane];
    o[(((size_t)b * S_ + qi) * H_ + h) * D_ + lane] = __float2bfloat16(res);
}

extern "C" void kernel_launch(void* const* d_in, const int* in_sizes, int n_in,
                              void* d_out, int out_size, void* d_ws, size_t ws_size,
                              hipStream_t stream)
{
    const float* encoded  = (const float*)d_in[0];
    const float* srcmask  = (const float*)d_in[1];
    const int*   targets  = (const int*)d_in[2];
    const float* table    = (const float*)d_in[3];
    const float* pos      = (const float*)d_in[4];
    const float* ln1_s = (const float*)d_in[5];
    const float* ln1_b = (const float*)d_in[6];
    const float* ln2_s = (const float*)d_in[7];
    const float* ln2_b = (const float*)d_in[8];
    const float* ln3_s = (const float*)d_in[9];
    const float* ln3_b = (const float*)d_in[10];
    const float* self_wq = (const float*)d_in[11];
    const float* self_wk = (const float*)d_in[12];
    const float* self_wv = (const float*)d_in[13];
    const float* self_wo = (const float*)d_in[14];
    const float* cross_wq = (const float*)d_in[15];
    const float* cross_wk = (const float*)d_in[16];
    const float* cross_wv = (const float*)d_in[17];
    const float* cross_wo = (const float*)d_in[18];
    const float* mlp_w1 = (const float*)d_in[19];
    const float* mlp_b1 = (const float*)d_in[20];
    const float* mlp_w2 = (const float*)d_in[21];
    const float* mlp_b2 = (const float*)d_in[22];
    const float* final_s = (const float*)d_in[23];
    const float* final_b = (const float*)d_in[24];
    const float* logit_w = (const float*)d_in[25];
    const float* logit_b = (const float*)d_in[26];
    float* out = (float*)d_out;

    char* ws = (char*)d_ws;
    unsigned char* masks = (unsigned char*)ws;
    size_t off = 1024;
    auto alloc = [&](size_t bytes) {
        char* p = ws + off;
        off += (bytes + 255) & ~(size_t)255;
        return p;
    };
    const size_t RS = (size_t)B_ * S_;           // 2048 rows
    float* y    = (float*)alloc(RS * E_ * 4);
    float* xb   = (float*)alloc(RS * E_ * 4);
    float* zb   = (float*)alloc(RS * E_ * 4);
    bf16* lnb   = (bf16*)alloc(RS * E_ * 2);
    bf16* qb    = (bf16*)alloc(RS * E_ * 2);
    bf16* kb    = (bf16*)alloc(RS * E_ * 2);
    bf16* vb    = (bf16*)alloc(RS * E_ * 2);
    bf16* ob    = (bf16*)alloc(RS * E_ * 2);
    bf16* hid   = (bf16*)alloc(RS * M_ * 2);
    bf16* encb  = (bf16*)alloc(RS * E_ * 2);
    float* vmean = (float*)alloc(B_ * H_ * D_ * 4);
    bf16* swq_t = (bf16*)alloc((size_t)L_ * E_ * E_ * 2);
    bf16* swk_t = (bf16*)alloc((size_t)L_ * E_ * E_ * 2);
    bf16* swv_t = (bf16*)alloc((size_t)L_ * E_ * E_ * 2);
    bf16* swo_t = (bf16*)alloc((size_t)L_ * E_ * E_ * 2);
    bf16* cwq_t = (bf16*)alloc((size_t)L_ * E_ * E_ * 2);
    bf16* cwk_t = (bf16*)alloc((size_t)L_ * E_ * E_ * 2);
    bf16* cwv_t = (bf16*)alloc((size_t)L_ * E_ * E_ * 2);
    bf16* cwo_t = (bf16*)alloc((size_t)L_ * E_ * E_ * 2);
    bf16* w1_t  = (bf16*)alloc((size_t)L_ * E_ * M_ * 2);
    bf16* w2_t  = (bf16*)alloc((size_t)L_ * M_ * E_ * 2);
    bf16* wl_t  = (bf16*)alloc((size_t)E_ * V_ * 2);

    const int R = (int)RS;

    build_masks_kernel<<<1, 64, 0, stream>>>(masks);
    embed_kernel<<<R, 128, 0, stream>>>(targets, table, pos, y);
    cvt_kernel<<<(R * E_) / 1024, 256, 0, stream>>>(encoded, encb);

    // weight transposes (K x N f32 -> N x K bf16), batched over L via grid.z
    {
        dim3 gpp(E_ / 32, E_ / 32, L_);
        size_t ss = (size_t)E_ * E_;
        tconv_kernel<<<gpp, 256, 0, stream>>>(self_wq, swq_t, E_, E_, ss, ss);
        tconv_kernel<<<gpp, 256, 0, stream>>>(self_wk, swk_t, E_, E_, ss, ss);
        tconv_kernel<<<gpp, 256, 0, stream>>>(self_wv, swv_t, E_, E_, ss, ss);
        tconv_kernel<<<gpp, 256, 0, stream>>>(self_wo, swo_t, E_, E_, ss, ss);
        tconv_kernel<<<gpp, 256, 0, stream>>>(cross_wq, cwq_t, E_, E_, ss, ss);
        tconv_kernel<<<gpp, 256, 0, stream>>>(cross_wk, cwk_t, E_, E_, ss, ss);
        tconv_kernel<<<gpp, 256, 0, stream>>>(cross_wv, cwv_t, E_, E_, ss, ss);
        tconv_kernel<<<gpp, 256, 0, stream>>>(cross_wo, cwo_t, E_, E_, ss, ss);
        dim3 g1(E_ / 32, M_ / 32, L_);
        tconv_kernel<<<g1, 256, 0, stream>>>(mlp_w1, w1_t, E_, M_, (size_t)E_ * M_, (size_t)E_ * M_);
        dim3 g2(M_ / 32, E_ / 32, L_);
        tconv_kernel<<<g2, 256, 0, stream>>>(mlp_w2, w2_t, M_, E_, (size_t)M_ * E_, (size_t)M_ * E_);
        dim3 g3(E_ / 32, V_ / 32, 1);
        tconv_kernel<<<g3, 256, 0, stream>>>(logit_w, wl_t, E_, V_, 0, 0);
    }

    dim3 gp(E_ / 128, R / 128);       // N=512
    dim3 g1(M_ / 128, R / 128);       // N=2048
    dim3 gl(V_ / 128, R / 128);       // N=32000
    int attn_grid = B_ * H_ * (S_ / 8);
    size_t we = (size_t)E_ * E_;

    for (int l = 0; l < L_; ++l) {
        // ---- self attention ----
        ln_kernel<<<R, 256, 0, stream>>>(y, lnb, ln1_s + l * E_, ln1_b + l * E_);
        gemm_mfma<1><<<gp, 256, 0, stream>>>(lnb, swq_t + l * we, nullptr, nullptr, qb, R, E_, E_, 0.125f, 0);
        gemm_mfma<1><<<gp, 256, 0, stream>>>(lnb, swk_t + l * we, nullptr, nullptr, kb, R, E_, E_, 1.0f, 0);
        gemm_mfma<1><<<gp, 256, 0, stream>>>(lnb, swv_t + l * we, nullptr, nullptr, vb, R, E_, E_, 1.0f, 0);
        vmean_kernel<<<B_ * H_, 512, 0, stream>>>(vb, vmean);
        attn_kernel<<<attn_grid, 512, 0, stream>>>(qb, kb, vb, ob, masks + l * 256, targets, nullptr, vmean, 1);
        gemm_mfma<0><<<gp, 256, 0, stream>>>(ob, swo_t + l * we, nullptr, y, xb, R, E_, E_, 1.0f, 0);
        // ---- cross attention ----
        ln_kernel<<<R, 256, 0, stream>>>(xb, lnb, ln2_s + l * E_, ln2_b + l * E_);
        gemm_mfma<1><<<gp, 256, 0, stream>>>(lnb, cwq_t + l * we, nullptr, nullptr, qb, R, E_, E_, 0.125f, 0);
        gemm_mfma<1><<<gp, 256, 0, stream>>>(encb, cwk_t + l * we, nullptr, nullptr, kb, R, E_, E_, 1.0f, 0);
        gemm_mfma<1><<<gp, 256, 0, stream>>>(encb, cwv_t + l * we, nullptr, nullptr, vb, R, E_, E_, 1.0f, 0);
        vmean_kernel<<<B_ * H_, 512, 0, stream>>>(vb, vmean);
        attn_kernel<<<attn_grid, 512, 0, stream>>>(qb, kb, vb, ob, masks + (2 + l) * 256, targets, srcmask, vmean, 0);
        gemm_mfma<0><<<gp, 256, 0, stream>>>(ob, cwo_t + l * we, nullptr, xb, zb, R, E_, E_, 1.0f, 0);
        // ---- MLP ----
        ln_kernel<<<R, 256, 0, stream>>>(zb, lnb, ln3_s + l * E_, ln3_b + l * E_);
        gemm_mfma<1><<<g1, 256, 0, stream>>>(lnb, w1_t + (size_t)l * E_ * M_, mlp_b1 + (size_t)l * M_, nullptr, hid, R, M_, E_, 1.0f, 1);
        gemm_mfma<0><<<gp, 256, 0, stream>>>(hid, w2_t + (size_t)l * M_ * E_, mlp_b2 + (size_t)l * E_, zb, y, R, E_, M_, 1.0f, 0);
    }

    ln_kernel<<<R, 256, 0, stream>>>(y, lnb, final_s, final_b);
    gemm_mfma<0><<<gl, 256, 0, stream>>>(lnb, wl_t, logit_b, nullptr, out, R, V_, E_, 1.0f, 0);
}

// Round 6
// 1226.153 us; speedup vs baseline: 3.6920x; 1.6265x over previous
//
#include <hip/hip_runtime.h>
#include <hip/hip_bf16.h>
#include <stdint.h>

#define B_ 2
#define S_ 1024
#define E_ 512
#define H_ 8
#define D_ 64
#define M_ 2048
#define V_ 32000
#define L_ 2

typedef __hip_bfloat16 bf16;
typedef __attribute__((ext_vector_type(8))) short short8;
typedef __attribute__((ext_vector_type(4))) float f32x4;
typedef __attribute__((ext_vector_type(16))) float f32x16;
typedef __attribute__((ext_vector_type(4))) unsigned int uint4v;

__device__ inline unsigned int pack2bf(float lo, float hi) {
    __hip_bfloat16 a = __float2bfloat16(lo), b = __float2bfloat16(hi);
    unsigned short ua = *(unsigned short*)&a, ub = *(unsigned short*)&b;
    return (unsigned int)ua | ((unsigned int)ub << 16);
}

// ---------------- numpy legacy RandomState (MT19937) ----------------
struct MTState { unsigned int mt[624]; int idx; };

__device__ void mt_seed(MTState* st, unsigned int s) {
    for (int i = 0; i < 624; ++i) {
        st->mt[i] = s;
        s = 1812433253u * (s ^ (s >> 30)) + (unsigned int)(i + 1);
    }
    st->idx = 624;
}

__device__ unsigned int mt_next(MTState* st) {
    if (st->idx >= 624) {
        for (int i = 0; i < 624; ++i) {
            unsigned int y = (st->mt[i] & 0x80000000u) | (st->mt[(i + 1) % 624] & 0x7fffffffu);
            unsigned int v = st->mt[(i + 397) % 624] ^ (y >> 1);
            if (y & 1u) v ^= 0x9908b0dfu;
            st->mt[i] = v;
        }
        st->idx = 0;
    }
    unsigned int y = st->mt[st->idx++];
    y ^= y >> 11;
    y ^= (y << 7) & 0x9d2c5680u;
    y ^= (y << 15) & 0xefc60000u;
    y ^= y >> 18;
    return y;
}

__device__ unsigned int rk_interval(MTState* st, unsigned int mx) {
    if (mx == 0u) return 0u;
    unsigned int mask = mx;
    mask |= mask >> 1; mask |= mask >> 2; mask |= mask >> 4;
    mask |= mask >> 8; mask |= mask >> 16;
    unsigned int v;
    while ((v = (mt_next(st) & mask)) > mx) {}
    return v;
}

__global__ void build_masks_kernel(unsigned char* masks) {
    int t = threadIdx.x;
    if (t >= 4) return;
    const unsigned int seeds[4] = {1000u, 1001u, 0u, 1u};
    unsigned char* m = masks + t * 256;
    for (int i = 0; i < 16; ++i)
        for (int j = 0; j < 16; ++j) {
            bool v = (j >= i - 1 && j <= i + 1) || i == 0 || i == 15 || j == 0 || j == 15;
            m[i * 16 + j] = v ? 1 : 0;
        }
    MTState st;
    mt_seed(&st, seeds[t]);
    for (int i = 0; i < 16; ++i) {
        int arr[16];
        for (int j = 0; j < 16; ++j) arr[j] = j;
        for (int k = 15; k > 0; --k) {
            unsigned int j = rk_interval(&st, (unsigned int)k);
            int tmp = arr[k]; arr[k] = arr[j]; arr[j] = tmp;
        }
        m[i * 16 + arr[0]] = 1;
        m[i * 16 + arr[1]] = 1;
        m[i * 16 + arr[2]] = 1;
    }
}

// ---------------- embedding ----------------
__global__ void embed_kernel(const int* __restrict__ targets,
                             const float* __restrict__ table,
                             const float* __restrict__ pos,
                             float* __restrict__ y) {
    int row = blockIdx.x;
    int s = row & (S_ - 1);
    int b = row >> 10;
    int id = (s == 0) ? 0 : targets[b * S_ + s - 1];
    int c = threadIdx.x * 4;
    float4 e = *(const float4*)&table[(size_t)id * E_ + c];
    float4 p = *(const float4*)&pos[(size_t)s * E_ + c];
    e.x += p.x; e.y += p.y; e.z += p.z; e.w += p.w;
    *(float4*)&y[(size_t)row * E_ + c] = e;
}

// ---------------- layernorm f32 -> bf16 ----------------
__global__ __launch_bounds__(256)
void ln_kernel(const float* __restrict__ x, bf16* __restrict__ y,
               const float* __restrict__ sc, const float* __restrict__ bi) {
    int row = blockIdx.x;
    int t = threadIdx.x;
    const float* xr = x + (size_t)row * E_;
    float2 v = *(const float2*)&xr[t * 2];
    float sum = v.x + v.y;
    float sq = v.x * v.x + v.y * v.y;
    for (int off = 32; off > 0; off >>= 1) {
        sum += __shfl_xor(sum, off);
        sq  += __shfl_xor(sq, off);
    }
    __shared__ float s0[4], s1[4];
    int w = t >> 6;
    if ((t & 63) == 0) { s0[w] = sum; s1[w] = sq; }
    __syncthreads();
    sum = s0[0] + s0[1] + s0[2] + s0[3];
    sq  = s1[0] + s1[1] + s1[2] + s1[3];
    float mu = sum * (1.0f / (float)E_);
    float var = sq * (1.0f / (float)E_) - mu * mu;
    float rs = rsqrtf(var + 1e-6f);
    float2 s2 = *(const float2*)&sc[t * 2];
    float2 b2 = *(const float2*)&bi[t * 2];
    bf16* yr = y + (size_t)row * E_ + t * 2;
    yr[0] = __float2bfloat16((v.x - mu) * rs * s2.x + b2.x);
    yr[1] = __float2bfloat16((v.y - mu) * rs * s2.y + b2.y);
}

// ---------------- transpose+convert: W[K][N] f32 -> Wt[N][K] bf16 ----------------
__global__ __launch_bounds__(256)
void tconv_kernel(const float* __restrict__ W, bf16* __restrict__ Wt,
                  int K, int N, size_t src_stride, size_t dst_stride) {
    __shared__ float Ts[32][33];
    const float* Wb = W + blockIdx.z * src_stride;
    bf16* Wtb = Wt + blockIdx.z * dst_stride;
    int k0 = blockIdx.x * 32, n0 = blockIdx.y * 32;
    int lx = threadIdx.x & 31, ly = threadIdx.x >> 5;
    for (int r = ly; r < 32; r += 8)
        Ts[r][lx] = Wb[(size_t)(k0 + r) * N + n0 + lx];
    __syncthreads();
    for (int r = ly; r < 32; r += 8)
        Wtb[(size_t)(n0 + r) * K + k0 + lx] = __float2bfloat16(Ts[lx][r]);
}

// ---------------- f32 -> bf16 elementwise ----------------
__global__ void cvt_kernel(const float* __restrict__ x, bf16* __restrict__ y) {
    int i = (blockIdx.x * blockDim.x + threadIdx.x) * 4;
    float4 v = *(const float4*)&x[i];
    y[i + 0] = __float2bfloat16(v.x);
    y[i + 1] = __float2bfloat16(v.y);
    y[i + 2] = __float2bfloat16(v.z);
    y[i + 3] = __float2bfloat16(v.w);
}

// ---------------- vmean[b][h][d] = mean_s v[b][s][h][d] ----------------
__global__ __launch_bounds__(512)
void vmean_kernel(const bf16* __restrict__ v, int sv, float* __restrict__ vm) {
    int bh = blockIdx.x; int b = bh >> 3, h = bh & 7;
    int d = threadIdx.x & 63, sl = threadIdx.x >> 6;
    const unsigned short* vu = (const unsigned short*)v;
    float s = 0.0f;
    for (int si = sl; si < S_; si += 8) {
        unsigned short u = vu[(size_t)(b * S_ + si) * sv + h * D_ + d];
        s += __uint_as_float((unsigned)u << 16);
    }
    __shared__ float red[512];
    red[threadIdx.x] = s;
    __syncthreads();
    if (sl == 0) {
        float tot = 0.0f;
        for (int j = 0; j < 8; ++j) tot += red[j * 64 + d];
        vm[bh * D_ + d] = tot * (1.0f / (float)S_);
    }
}

// ---------------- bf16 MFMA GEMM (m97 structure) ----------------
template<int OBF>
__global__ __launch_bounds__(256)
void gemm_mfma(const bf16* __restrict__ A, const bf16* __restrict__ Wt,
               const float* __restrict__ bias, const float* __restrict__ resid,
               void* __restrict__ Cv, int M, int N, int K, float alpha, int relu)
{
    __shared__ bf16 As[128 * 64];
    __shared__ bf16 Bs[128 * 64];
    const int t = threadIdx.x;
    const int lane = t & 63, w = t >> 6;
    const int n0 = blockIdx.x * 128, m0 = blockIdx.y * 128;
    const int wr = w >> 1, wc = w & 1;
    const int srow = w * 8 + (lane >> 3);
    const int sslot = lane & 7;
    f32x4 acc[4][4] = {};

    for (int k0 = 0; k0 < K; k0 += 64) {
        __syncthreads();
        #pragma unroll
        for (int i = 0; i < 4; ++i) {
            int r = i * 32 + srow;
            int gslot = sslot ^ (r & 7);
            const bf16* ga = A  + (size_t)(m0 + r) * K + k0 + gslot * 8;
            const bf16* gb = Wt + (size_t)(n0 + r) * K + k0 + gslot * 8;
            __builtin_amdgcn_global_load_lds((const __attribute__((address_space(1))) void*)ga,
                                             (__attribute__((address_space(3))) void*)&As[r * 64 + sslot * 8],
                                             16, 0, 0);
            __builtin_amdgcn_global_load_lds((const __attribute__((address_space(1))) void*)gb,
                                             (__attribute__((address_space(3))) void*)&Bs[r * 64 + sslot * 8],
                                             16, 0, 0);
        }
        __syncthreads();
        #pragma unroll
        for (int kk = 0; kk < 2; ++kk) {
            short8 af[4], bq[4];
            const int q = kk * 4 + (lane >> 4);
            #pragma unroll
            for (int m = 0; m < 4; ++m) {
                int r = wr * 64 + m * 16 + (lane & 15);
                af[m] = *(const short8*)&As[r * 64 + (q ^ (r & 7)) * 8];
            }
            #pragma unroll
            for (int n = 0; n < 4; ++n) {
                int r = wc * 64 + n * 16 + (lane & 15);
                bq[n] = *(const short8*)&Bs[r * 64 + (q ^ (r & 7)) * 8];
            }
            #pragma unroll
            for (int m = 0; m < 4; ++m)
                #pragma unroll
                for (int n = 0; n < 4; ++n)
                    acc[m][n] = __builtin_amdgcn_mfma_f32_16x16x32_bf16(af[m], bq[n], acc[m][n], 0, 0, 0);
        }
    }

    const int lr = lane >> 4, lc = lane & 15;
    #pragma unroll
    for (int n = 0; n < 4; ++n) {
        int col = n0 + wc * 64 + n * 16 + lc;
        float bv = bias ? bias[col] : 0.0f;
        #pragma unroll
        for (int m = 0; m < 4; ++m) {
            #pragma unroll
            for (int r = 0; r < 4; ++r) {
                int row = m0 + wr * 64 + m * 16 + lr * 4 + r;
                float val = acc[m][n][r] * alpha + bv;
                if (relu) val = fmaxf(val, 0.0f);
                if (resid) val += resid[(size_t)row * N + col];
                if (OBF) ((bf16*)Cv)[(size_t)row * N + col] = __float2bfloat16(val);
                else     ((float*)Cv)[(size_t)row * N + col] = val;
            }
        }
    }
}

// ---------------- MFMA flash attention (no cross-wave merge) ----------------
// Block: (b, h, qb-pair). 4 waves = 2 q-halves (wq) x 2 q-blocks (wk; qb = 2*qbp+wk).
// Each wave-pair owns one q-block completely. 32x32x16 MFMA.
// Swapped QK^T (lane owns q=lane&31 scores); PV as O^T = V^T P^T (rescale per-lane).
// V slot for PV MUST include the ks half: c = (4*ks + 2*Hh + h5) ^ swizzle.  [R5 bug]
// P fed to PV as two-term bf16 split (hi + residual) -> ~f32 precision.
// Block-sparse skip exact (skipped blocks give p=0 in f32 ref). m<=-5e8 -> vmean.
__global__ __launch_bounds__(256)
void attn_mfma(const bf16* __restrict__ qp, const bf16* __restrict__ kp,
               const bf16* __restrict__ vp, bf16* __restrict__ op,
               const unsigned char* __restrict__ bm,
               const int* __restrict__ targets, const float* __restrict__ srcmask,
               const float* __restrict__ vmean,
               int sq, int sk, int sv, int causal)
{
    __shared__ __align__(16) unsigned char lds[49280];
    // Ks[wk]: wk*8192 | Vt[wk]: 16384+wk*8192 | Qs[wk]: 32768+wk*8192 | padb: 49152
    unsigned long long* padb = (unsigned long long*)(lds + 49152);

    const int bid = blockIdx.x;
    const int qbp = bid & 7, h = (bid >> 3) & 7, b = bid >> 6;
    const int tid = threadIdx.x;
    const int w = tid >> 6, lane = tid & 63;
    const int wq = w & 1, wk = w >> 1;
    const int qb = 2 * qbp + wk;
    const int h5 = lane >> 5, l31 = lane & 31;

    unsigned char* Ks = lds + wk * 8192;
    unsigned char* Vt = lds + 16384 + wk * 8192;
    unsigned char* Qs = lds + 32768 + wk * 8192;

    // ---- stage Q (own pair's 64 rows x 64 d, XOR-swizzled via source) ----
    #pragma unroll
    for (int j = 0; j < 4; ++j) {
        int r = wq * 32 + j * 8 + (lane >> 3);
        int g = (lane & 7) ^ (r & 7);
        const bf16* src = qp + (size_t)(b * S_ + qb * 64 + r) * sq + h * 64 + g * 8;
        __builtin_amdgcn_global_load_lds((const __attribute__((address_space(1))) void*)src,
            (__attribute__((address_space(3))) void*)(Qs + wq * 4096 + j * 1024 + lane * 16),
            16, 0, 0);
    }
    __syncthreads();
    short8 qfrag[4];
    {
        int qrow = wq * 32 + l31;
        #pragma unroll
        for (int t = 0; t < 4; ++t) {
            int c = (2 * t + h5) ^ (qrow & 7);
            qfrag[t] = *(const short8*)(Qs + qrow * 128 + c * 16);
        }
    }

    const int q_in = wq * 32 + l31;
    const int qg = qb * 64 + q_in;
    const bool padq = targets[b * S_ + qg] > 0;

    // full block list for THIS pair's q-block; nIter = max over both pairs (barrier match)
    unsigned long long lstpk = 0ULL;
    int myn = 0;
    {
        int kbmax = causal ? qb : 15;
        for (int kb = 0; kb <= kbmax; ++kb)
            if (bm[qb * 16 + kb]) { lstpk |= ((unsigned long long)kb) << (4 * myn); ++myn; }
    }
    int nIter;
    {
        int qbo = 2 * qbp + 1;
        int kbmaxo = causal ? qbo : 15;
        int cnto = 0;
        for (int kb = 0; kb <= kbmaxo; ++kb) if (bm[qbo * 16 + kb]) ++cnto;
        nIter = cnto > myn ? cnto : myn;
    }

    float mrun = -3.0e38f, lrun = 0.0f;
    f32x16 acc0 = {}, acc1 = {};

    for (int it = 0; it < nIter; ++it) {
        bool active = it < myn;
        int kb = (int)((lstpk >> (4 * it)) & 15ULL);
        if (active) {
            // stage K [64 k][64 d], swizzled source
            #pragma unroll
            for (int j = 0; j < 4; ++j) {
                int r = j * 16 + wq * 8 + (lane >> 3);
                int g = (lane & 7) ^ (r & 7);
                const bf16* src = kp + (size_t)(b * S_ + kb * 64 + r) * sk + h * 64 + g * 8;
                __builtin_amdgcn_global_load_lds((const __attribute__((address_space(1))) void*)src,
                    (__attribute__((address_space(3))) void*)(Ks + (j * 16 + wq * 8) * 128 + lane * 16),
                    16, 0, 0);
            }
            // stage V transposed -> Vt[d][k], packed pair writes, swizzled
            #pragma unroll
            for (int itv = 0; itv < 2; ++itv) {
                int k2 = 2 * l31;
                int d0 = h5 * 8 + (wq * 2 + itv) * 16;
                const unsigned short* v0 = (const unsigned short*)vp +
                    (size_t)(b * S_ + kb * 64 + k2) * sv + h * 64 + d0;
                short8 va = *(const short8*)v0;
                short8 vb = *(const short8*)(v0 + sv);
                #pragma unroll
                for (int j2 = 0; j2 < 8; ++j2) {
                    int d = d0 + j2;
                    unsigned int pkv = ((unsigned int)(unsigned short)va[j2]) |
                                       (((unsigned int)(unsigned short)vb[j2]) << 16);
                    int off = d * 128 + (((k2 >> 3) ^ (d & 7)) * 16) + (k2 & 7) * 2;
                    *(unsigned int*)(Vt + off) = pkv;
                }
            }
            if (wq == 0) {
                int pos = b * S_ + kb * 64 + lane;
                bool pk_ = srcmask ? (srcmask[pos] > 0.0f) : (targets[pos] > 0);
                unsigned long long bits = __ballot(pk_);
                if (lane == 0) padb[wk] = bits;
            }
        }
        __syncthreads();
        if (active) {
            bool diag = causal && (kb == qb);
            unsigned long long pb = padb[wk];
            #pragma unroll
            for (int ks = 0; ks < 2; ++ks) {
                f32x16 sacc = {};
                #pragma unroll
                for (int t = 0; t < 4; ++t) {
                    int row = ks * 32 + l31;
                    int c = (2 * t + h5) ^ (row & 7);
                    short8 kfrag = *(const short8*)(Ks + row * 128 + c * 16);
                    sacc = __builtin_amdgcn_mfma_f32_32x32x16_bf16(kfrag, qfrag[t], sacc, 0, 0, 0);
                }
                float p[16];
                float mloc = -3.0e38f;
                #pragma unroll
                for (int r = 0; r < 16; ++r) {
                    int kl = ks * 32 + (r & 3) + 8 * (r >> 2) + 4 * h5;
                    bool ok = padq && (((pb >> kl) & 1ULL) != 0) && (!diag || kl <= q_in);
                    p[r] = ok ? sacc[r] * 0.125f : -1.0e9f;
                    mloc = fmaxf(mloc, p[r]);
                }
                mloc = fmaxf(mloc, __shfl_xor(mloc, 32));
                float mnew = fmaxf(mrun, mloc);
                float rescale = __expf(mrun - mnew);
                float lsum = 0.0f;
                #pragma unroll
                for (int r = 0; r < 16; ++r) { p[r] = __expf(p[r] - mnew); lsum += p[r]; }
                lsum += __shfl_xor(lsum, 32);
                lrun = lrun * rescale + lsum;
                mrun = mnew;
                acc0 *= rescale;
                acc1 *= rescale;
                // two-term bf16 split of P: p = hi + lo, each packed as 2x bf16
                unsigned int pk_hi[4][2], pk_lo[4][2];
                #pragma unroll
                for (int t4 = 0; t4 < 4; ++t4)
                    #pragma unroll
                    for (int u = 0; u < 2; ++u) {
                        float a = p[4 * t4 + 2 * u];
                        float c = p[4 * t4 + 2 * u + 1];
                        unsigned int ph = pack2bf(a, c);
                        float ah = __uint_as_float(ph << 16);
                        float ch = __uint_as_float(ph & 0xffff0000u);
                        pk_hi[t4][u] = ph;
                        pk_lo[t4][u] = pack2bf(a - ah, c - ch);
                    }
                #pragma unroll
                for (int Hh = 0; Hh < 2; ++Hh) {
                    unsigned int hu0 = (unsigned int)__shfl_xor((int)pk_hi[2 * Hh + 1][0], 32);
                    unsigned int hu1 = (unsigned int)__shfl_xor((int)pk_hi[2 * Hh + 1][1], 32);
                    unsigned int hl0 = (unsigned int)__shfl_xor((int)pk_hi[2 * Hh][0], 32);
                    unsigned int hl1 = (unsigned int)__shfl_xor((int)pk_hi[2 * Hh][1], 32);
                    uint4v hv = {h5 ? hu0 : pk_hi[2 * Hh][0],
                                 h5 ? hu1 : pk_hi[2 * Hh][1],
                                 h5 ? pk_hi[2 * Hh + 1][0] : hl0,
                                 h5 ? pk_hi[2 * Hh + 1][1] : hl1};
                    short8 bfrag_hi = __builtin_bit_cast(short8, hv);
                    unsigned int lu0 = (unsigned int)__shfl_xor((int)pk_lo[2 * Hh + 1][0], 32);
                    unsigned int lu1 = (unsigned int)__shfl_xor((int)pk_lo[2 * Hh + 1][1], 32);
                    unsigned int ll0 = (unsigned int)__shfl_xor((int)pk_lo[2 * Hh][0], 32);
                    unsigned int ll1 = (unsigned int)__shfl_xor((int)pk_lo[2 * Hh][1], 32);
                    uint4v lv = {h5 ? lu0 : pk_lo[2 * Hh][0],
                                 h5 ? lu1 : pk_lo[2 * Hh][1],
                                 h5 ? pk_lo[2 * Hh + 1][0] : ll0,
                                 h5 ? pk_lo[2 * Hh + 1][1] : ll1};
                    short8 bfrag_lo = __builtin_bit_cast(short8, lv);
                    #pragma unroll
                    for (int f = 0; f < 2; ++f) {
                        int row = f * 32 + l31;
                        int c = (4 * ks + 2 * Hh + h5) ^ (row & 7);   // <-- ks-half of V (R5 fix)
                        short8 vfrag = *(const short8*)(Vt + row * 128 + c * 16);
                        if (f == 0) {
                            acc0 = __builtin_amdgcn_mfma_f32_32x32x16_bf16(vfrag, bfrag_hi, acc0, 0, 0, 0);
                            acc0 = __builtin_amdgcn_mfma_f32_32x32x16_bf16(vfrag, bfrag_lo, acc0, 0, 0, 0);
                        } else {
                            acc1 = __builtin_amdgcn_mfma_f32_32x32x16_bf16(vfrag, bfrag_hi, acc1, 0, 0, 0);
                            acc1 = __builtin_amdgcn_mfma_f32_32x32x16_bf16(vfrag, bfrag_lo, acc1, 0, 0, 0);
                        }
                    }
                }
            }
        }
        __syncthreads();
    }

    // ---- direct write-out (each wave owns its 32 q-rows completely) ----
    bool okrow = mrun > -5.0e8f;
    float inv = okrow ? 1.0f / lrun : 0.0f;
    const float* vmp = vmean + (b * 8 + h) * 64;
    unsigned short* orow = (unsigned short*)op + (size_t)(b * S_ + qg) * E_ + h * 64;
    #pragma unroll
    for (int f = 0; f < 2; ++f)
        #pragma unroll
        for (int t4 = 0; t4 < 4; ++t4)
            #pragma unroll
            for (int u = 0; u < 2; ++u) {
                int r = 4 * t4 + 2 * u;
                int d = f * 32 + 2 * u + 8 * t4 + 4 * h5;
                float a0 = f ? acc1[r] : acc0[r];
                float a1 = f ? acc1[r + 1] : acc0[r + 1];
                float v0 = a0 * inv;
                float v1 = a1 * inv;
                if (!okrow) { v0 = vmp[d]; v1 = vmp[d + 1]; }
                *(unsigned int*)(orow + d) = pack2bf(v0, v1);
            }
}

extern "C" void kernel_launch(void* const* d_in, const int* in_sizes, int n_in,
                              void* d_out, int out_size, void* d_ws, size_t ws_size,
                              hipStream_t stream)
{
    const float* encoded  = (const float*)d_in[0];
    const float* srcmask  = (const float*)d_in[1];
    const int*   targets  = (const int*)d_in[2];
    const float* table    = (const float*)d_in[3];
    const float* pos      = (const float*)d_in[4];
    const float* ln1_s = (const float*)d_in[5];
    const float* ln1_b = (const float*)d_in[6];
    const float* ln2_s = (const float*)d_in[7];
    const float* ln2_b = (const float*)d_in[8];
    const float* ln3_s = (const float*)d_in[9];
    const float* ln3_b = (const float*)d_in[10];
    const float* self_wq = (const float*)d_in[11];
    const float* self_wk = (const float*)d_in[12];
    const float* self_wv = (const float*)d_in[13];
    const float* self_wo = (const float*)d_in[14];
    const float* cross_wq = (const float*)d_in[15];
    const float* cross_wk = (const float*)d_in[16];
    const float* cross_wv = (const float*)d_in[17];
    const float* cross_wo = (const float*)d_in[18];
    const float* mlp_w1 = (const float*)d_in[19];
    const float* mlp_b1 = (const float*)d_in[20];
    const float* mlp_w2 = (const float*)d_in[21];
    const float* mlp_b2 = (const float*)d_in[22];
    const float* final_s = (const float*)d_in[23];
    const float* final_b = (const float*)d_in[24];
    const float* logit_w = (const float*)d_in[25];
    const float* logit_b = (const float*)d_in[26];
    float* out = (float*)d_out;

    char* ws = (char*)d_ws;
    unsigned char* masks = (unsigned char*)ws;
    size_t off = 1024;
    auto alloc = [&](size_t bytes) {
        char* p = ws + off;
        off += (bytes + 255) & ~(size_t)255;
        return p;
    };
    const size_t RS = (size_t)B_ * S_;   // 2048
    const size_t EE = (size_t)E_ * E_;
    float* y    = (float*)alloc(RS * E_ * 4);
    float* xb   = (float*)alloc(RS * E_ * 4);
    float* zb   = (float*)alloc(RS * E_ * 4);
    bf16* lnb   = (bf16*)alloc(RS * E_ * 2);
    bf16* qkvb  = (bf16*)alloc(RS * 3 * E_ * 2);
    bf16* kvb   = (bf16*)alloc(RS * 2 * E_ * 2);
    bf16* qb2   = (bf16*)alloc(RS * E_ * 2);
    bf16* ob    = (bf16*)alloc(RS * E_ * 2);
    bf16* hid   = (bf16*)alloc(RS * M_ * 2);
    bf16* encb  = (bf16*)alloc(RS * E_ * 2);
    float* vmean = (float*)alloc(B_ * H_ * D_ * 4);
    bf16* qkv_t = (bf16*)alloc((size_t)L_ * 3 * EE * 2);
    bf16* swo_t = (bf16*)alloc((size_t)L_ * EE * 2);
    bf16* cq_t  = (bf16*)alloc((size_t)L_ * EE * 2);
    bf16* ckv_t = (bf16*)alloc((size_t)L_ * 2 * EE * 2);
    bf16* cwo_t = (bf16*)alloc((size_t)L_ * EE * 2);
    bf16* w1_t  = (bf16*)alloc((size_t)L_ * E_ * M_ * 2);
    bf16* w2_t  = (bf16*)alloc((size_t)L_ * M_ * E_ * 2);
    bf16* wl_t  = (bf16*)alloc((size_t)E_ * V_ * 2);

    const int R = (int)RS;

    build_masks_kernel<<<1, 64, 0, stream>>>(masks);
    embed_kernel<<<R, 128, 0, stream>>>(targets, table, pos, y);
    cvt_kernel<<<(R * E_) / 1024, 256, 0, stream>>>(encoded, encb);

    {
        dim3 gpp(E_ / 32, E_ / 32, L_);
        tconv_kernel<<<gpp, 256, 0, stream>>>(self_wq, qkv_t + 0 * EE, E_, E_, EE, 3 * EE);
        tconv_kernel<<<gpp, 256, 0, stream>>>(self_wk, qkv_t + 1 * EE, E_, E_, EE, 3 * EE);
        tconv_kernel<<<gpp, 256, 0, stream>>>(self_wv, qkv_t + 2 * EE, E_, E_, EE, 3 * EE);
        tconv_kernel<<<gpp, 256, 0, stream>>>(self_wo, swo_t, E_, E_, EE, EE);
        tconv_kernel<<<gpp, 256, 0, stream>>>(cross_wq, cq_t, E_, E_, EE, EE);
        tconv_kernel<<<gpp, 256, 0, stream>>>(cross_wk, ckv_t + 0 * EE, E_, E_, EE, 2 * EE);
        tconv_kernel<<<gpp, 256, 0, stream>>>(cross_wv, ckv_t + 1 * EE, E_, E_, EE, 2 * EE);
        tconv_kernel<<<gpp, 256, 0, stream>>>(cross_wo, cwo_t, E_, E_, EE, EE);
        dim3 g1(E_ / 32, M_ / 32, L_);
        tconv_kernel<<<g1, 256, 0, stream>>>(mlp_w1, w1_t, E_, M_, (size_t)E_ * M_, (size_t)E_ * M_);
        dim3 g2(M_ / 32, E_ / 32, L_);
        tconv_kernel<<<g2, 256, 0, stream>>>(mlp_w2, w2_t, M_, E_, (size_t)M_ * E_, (size_t)M_ * E_);
        dim3 g3(E_ / 32, V_ / 32, 1);
        tconv_kernel<<<g3, 256, 0, stream>>>(logit_w, wl_t, E_, V_, 0, 0);
    }

    dim3 gqkv(3 * E_ / 128, R / 128);
    dim3 gkv(2 * E_ / 128, R / 128);
    dim3 gp(E_ / 128, R / 128);
    dim3 g1(M_ / 128, R / 128);
    dim3 gl(V_ / 128, R / 128);
    const int attn_grid = B_ * H_ * 8;   // (b, h, qb-pair)

    for (int l = 0; l < L_; ++l) {
        // ---- self attention ----
        ln_kernel<<<R, 256, 0, stream>>>(y, lnb, ln1_s + l * E_, ln1_b + l * E_);
        gemm_mfma<1><<<gqkv, 256, 0, stream>>>(lnb, qkv_t + (size_t)l * 3 * EE, nullptr, nullptr, qkvb, R, 3 * E_, E_, 1.0f, 0);
        vmean_kernel<<<B_ * H_, 512, 0, stream>>>(qkvb + 2 * E_, 3 * E_, vmean);
        attn_mfma<<<attn_grid, 256, 0, stream>>>(qkvb, qkvb + E_, qkvb + 2 * E_, ob, masks + l * 256,
                                                 targets, nullptr, vmean, 3 * E_, 3 * E_, 3 * E_, 1);
        gemm_mfma<0><<<gp, 256, 0, stream>>>(ob, swo_t + (size_t)l * EE, nullptr, y, xb, R, E_, E_, 1.0f, 0);
        // ---- cross attention ----
        ln_kernel<<<R, 256, 0, stream>>>(xb, lnb, ln2_s + l * E_, ln2_b + l * E_);
        gemm_mfma<1><<<gp, 256, 0, stream>>>(lnb, cq_t + (size_t)l * EE, nullptr, nullptr, qb2, R, E_, E_, 1.0f, 0);
        gemm_mfma<1><<<gkv, 256, 0, stream>>>(encb, ckv_t + (size_t)l * 2 * EE, nullptr, nullptr, kvb, R, 2 * E_, E_, 1.0f, 0);
        vmean_kernel<<<B_ * H_, 512, 0, stream>>>(kvb + E_, 2 * E_, vmean);
        attn_mfma<<<attn_grid, 256, 0, stream>>>(qb2, kvb, kvb + E_, ob, masks + (2 + l) * 256,
                                                 targets, srcmask, vmean, E_, 2 * E_, 2 * E_, 0);
        gemm_mfma<0><<<gp, 256, 0, stream>>>(ob, cwo_t + (size_t)l * EE, nullptr, xb, zb, R, E_, E_, 1.0f, 0);
        // ---- MLP ----
        ln_kernel<<<R, 256, 0, stream>>>(zb, lnb, ln3_s + l * E_, ln3_b + l * E_);
        gemm_mfma<1><<<g1, 256, 0, stream>>>(lnb, w1_t + (size_t)l * E_ * M_, mlp_b1 + (size_t)l * M_, nullptr, hid, R, M_, E_, 1.0f, 1);
        gemm_mfma<0><<<gp, 256, 0, stream>>>(hid, w2_t + (size_t)l * M_ * E_, mlp_b2 + (size_t)l * E_, zb, y, R, E_, M_, 1.0f, 0);
    }

    ln_kernel<<<R, 256, 0, stream>>>(y, lnb, final_s, final_b);
    gemm_mfma<0><<<gl, 256, 0, stream>>>(lnb, wl_t, logit_b, nullptr, out, R, V_, E_, 1.0f, 0);
}

// Round 7
// 1050.091 us; speedup vs baseline: 4.3110x; 1.1677x over previous
//
#include <hip/hip_runtime.h>
#include <hip/hip_bf16.h>
#include <stdint.h>

#define B_ 2
#define S_ 1024
#define E_ 512
#define H_ 8
#define D_ 64
#define M_ 2048
#define V_ 32000
#define L_ 2

typedef __hip_bfloat16 bf16;
typedef __attribute__((ext_vector_type(8))) short short8;
typedef __attribute__((ext_vector_type(4))) float f32x4;
typedef __attribute__((ext_vector_type(16))) float f32x16;
typedef __attribute__((ext_vector_type(4))) unsigned int uint4v;

__device__ inline unsigned int pack2bf(float lo, float hi) {
    __hip_bfloat16 a = __float2bfloat16(lo), b = __float2bfloat16(hi);
    unsigned short ua = *(unsigned short*)&a, ub = *(unsigned short*)&b;
    return (unsigned int)ua | ((unsigned int)ub << 16);
}

// ---------------- numpy legacy RandomState (MT19937), LDS-resident ----------------
// One wave per seed. Serial parts (seed recurrence, draws) on lane 0; the twist is
// lane-parallel in 4 phases honoring MT19937's exact in-place dependency structure.
#define MT_N 624
#define MT_M 397
#define MT_UP   0x80000000u
#define MT_LOW  0x7fffffffu
#define MT_MAT  0x9908b0dfu

__device__ inline unsigned int mt_temper(unsigned int y) {
    y ^= y >> 11;
    y ^= (y << 7) & 0x9d2c5680u;
    y ^= (y << 15) & 0xefc60000u;
    y ^= y >> 18;
    return y;
}

__global__ __launch_bounds__(256)
void build_masks_kernel(unsigned char* masks) {
    __shared__ unsigned int mto[4][MT_N];
    __shared__ unsigned int mtn[4][MT_N];
    const int w = threadIdx.x >> 6, lane = threadIdx.x & 63;
    const unsigned int seeds[4] = {1000u, 1001u, 0u, 1u};
    unsigned char* m = masks + w * 256;

    // base pattern (window + global rows/cols), lane-parallel
    for (int idx = lane; idx < 256; idx += 64) {
        int i = idx >> 4, j = idx & 15;
        bool v = (j >= i - 1 && j <= i + 1) || i == 0 || i == 15 || j == 0 || j == 15;
        m[idx] = v ? 1 : 0;
    }

    // serial seed recurrence (lane 0), state into LDS
    if (lane == 0) {
        unsigned int s = seeds[w];
        for (int i = 0; i < MT_N; ++i) {
            mto[w][i] = s;
            s = 1812433253u * (s ^ (s >> 30)) + (unsigned int)(i + 1);
        }
    }
    __syncthreads();

    // lane-parallel twist, double-buffered, 4 phases:
    //  A : i in [0,227)    uses o[i], o[i+1], o[i+397]
    //  B1: i in [227,454)  uses o[i], o[i+1], n[i-227]   (n from A)
    //  B2: i in [454,623)  uses o[i], o[i+1], n[i-227]   (n from B1)
    //  C : i = 623         uses o[623], n[0], n[396]
    for (int i = lane; i < MT_N - MT_M; i += 64) {             // A: 227 elems
        unsigned int y = (mto[w][i] & MT_UP) | (mto[w][i + 1] & MT_LOW);
        mtn[w][i] = mto[w][i + MT_M] ^ (y >> 1) ^ ((y & 1u) ? MT_MAT : 0u);
    }
    __syncthreads();
    for (int i = 227 + lane; i < 454; i += 64) {               // B1
        unsigned int y = (mto[w][i] & MT_UP) | (mto[w][i + 1] & MT_LOW);
        mtn[w][i] = mtn[w][i - 227] ^ (y >> 1) ^ ((y & 1u) ? MT_MAT : 0u);
    }
    __syncthreads();
    for (int i = 454 + lane; i < MT_N - 1; i += 64) {          // B2
        unsigned int y = (mto[w][i] & MT_UP) | (mto[w][i + 1] & MT_LOW);
        mtn[w][i] = mtn[w][i - 227] ^ (y >> 1) ^ ((y & 1u) ? MT_MAT : 0u);
    }
    __syncthreads();
    if (lane == 0) {                                           // C: i = 623
        unsigned int y = (mto[w][MT_N - 1] & MT_UP) | (mtn[w][0] & MT_LOW);
        mtn[w][MT_N - 1] = mtn[w][MT_M - 1] ^ (y >> 1) ^ ((y & 1u) ? MT_MAT : 0u);
    }
    __syncthreads();

    // serial draws (lane 0): Fisher-Yates over 16 nibbles packed in a u64 (no scratch)
    if (lane == 0) {
        int idx = 0;
        for (int i = 0; i < 16; ++i) {
            unsigned long long arr = 0xFEDCBA9876543210ULL;
            for (int k = 15; k > 0; --k) {
                unsigned int mask = k;
                mask |= mask >> 1; mask |= mask >> 2; mask |= mask >> 4;
                unsigned int j;
                for (;;) {
                    if (idx >= MT_N) {
                        // serial in-place re-twist (statistically never reached)
                        int i2 = 0;
                        for (; i2 < MT_N - MT_M; ++i2) {
                            unsigned int y2 = (mtn[w][i2] & MT_UP) | (mtn[w][i2 + 1] & MT_LOW);
                            mtn[w][i2] = mtn[w][i2 + MT_M] ^ (y2 >> 1) ^ ((y2 & 1u) ? MT_MAT : 0u);
                        }
                        for (; i2 < MT_N - 1; ++i2) {
                            unsigned int y2 = (mtn[w][i2] & MT_UP) | (mtn[w][i2 + 1] & MT_LOW);
                            mtn[w][i2] = mtn[w][i2 - 227] ^ (y2 >> 1) ^ ((y2 & 1u) ? MT_MAT : 0u);
                        }
                        unsigned int y2 = (mtn[w][MT_N - 1] & MT_UP) | (mtn[w][0] & MT_LOW);
                        mtn[w][MT_N - 1] = mtn[w][MT_M - 1] ^ (y2 >> 1) ^ ((y2 & 1u) ? MT_MAT : 0u);
                        idx = 0;
                    }
                    j = mt_temper(mtn[w][idx++]) & mask;
                    if (j <= (unsigned int)k) break;
                }
                // swap nibbles k <-> j
                unsigned int a = (unsigned int)(arr >> (4 * k)) & 15u;
                unsigned int bnib = (unsigned int)(arr >> (4 * j)) & 15u;
                arr &= ~((15ULL << (4 * k)) | (15ULL << (4 * j)));
                arr |= ((unsigned long long)a << (4 * j)) | ((unsigned long long)bnib << (4 * k));
            }
            m[i * 16 + ((arr >> 0) & 15)] = 1;
            m[i * 16 + ((arr >> 4) & 15)] = 1;
            m[i * 16 + ((arr >> 8) & 15)] = 1;
        }
    }
}

// ---------------- embedding ----------------
__global__ void embed_kernel(const int* __restrict__ targets,
                             const float* __restrict__ table,
                             const float* __restrict__ pos,
                             float* __restrict__ y) {
    int row = blockIdx.x;
    int s = row & (S_ - 1);
    int b = row >> 10;
    int id = (s == 0) ? 0 : targets[b * S_ + s - 1];
    int c = threadIdx.x * 4;
    float4 e = *(const float4*)&table[(size_t)id * E_ + c];
    float4 p = *(const float4*)&pos[(size_t)s * E_ + c];
    e.x += p.x; e.y += p.y; e.z += p.z; e.w += p.w;
    *(float4*)&y[(size_t)row * E_ + c] = e;
}

// ---------------- layernorm f32 -> bf16 ----------------
__global__ __launch_bounds__(256)
void ln_kernel(const float* __restrict__ x, bf16* __restrict__ y,
               const float* __restrict__ sc, const float* __restrict__ bi) {
    int row = blockIdx.x;
    int t = threadIdx.x;
    const float* xr = x + (size_t)row * E_;
    float2 v = *(const float2*)&xr[t * 2];
    float sum = v.x + v.y;
    float sq = v.x * v.x + v.y * v.y;
    for (int off = 32; off > 0; off >>= 1) {
        sum += __shfl_xor(sum, off);
        sq  += __shfl_xor(sq, off);
    }
    __shared__ float s0[4], s1[4];
    int w = t >> 6;
    if ((t & 63) == 0) { s0[w] = sum; s1[w] = sq; }
    __syncthreads();
    sum = s0[0] + s0[1] + s0[2] + s0[3];
    sq  = s1[0] + s1[1] + s1[2] + s1[3];
    float mu = sum * (1.0f / (float)E_);
    float var = sq * (1.0f / (float)E_) - mu * mu;
    float rs = rsqrtf(var + 1e-6f);
    float2 s2 = *(const float2*)&sc[t * 2];
    float2 b2 = *(const float2*)&bi[t * 2];
    bf16* yr = y + (size_t)row * E_ + t * 2;
    yr[0] = __float2bfloat16((v.x - mu) * rs * s2.x + b2.x);
    yr[1] = __float2bfloat16((v.y - mu) * rs * s2.y + b2.y);
}

// ---------------- transpose+convert: W[K][N] f32 -> Wt[N][K] bf16 ----------------
__global__ __launch_bounds__(256)
void tconv_kernel(const float* __restrict__ W, bf16* __restrict__ Wt,
                  int K, int N, size_t src_stride, size_t dst_stride) {
    __shared__ float Ts[32][33];
    const float* Wb = W + blockIdx.z * src_stride;
    bf16* Wtb = Wt + blockIdx.z * dst_stride;
    int k0 = blockIdx.x * 32, n0 = blockIdx.y * 32;
    int lx = threadIdx.x & 31, ly = threadIdx.x >> 5;
    for (int r = ly; r < 32; r += 8)
        Ts[r][lx] = Wb[(size_t)(k0 + r) * N + n0 + lx];
    __syncthreads();
    for (int r = ly; r < 32; r += 8)
        Wtb[(size_t)(n0 + r) * K + k0 + lx] = __float2bfloat16(Ts[lx][r]);
}

// ---------------- f32 -> bf16 elementwise ----------------
__global__ void cvt_kernel(const float* __restrict__ x, bf16* __restrict__ y) {
    int i = (blockIdx.x * blockDim.x + threadIdx.x) * 4;
    float4 v = *(const float4*)&x[i];
    y[i + 0] = __float2bfloat16(v.x);
    y[i + 1] = __float2bfloat16(v.y);
    y[i + 2] = __float2bfloat16(v.z);
    y[i + 3] = __float2bfloat16(v.w);
}

// ---------------- vmean[b][h][d] = mean_s v[b][s][h][d] ----------------
__global__ __launch_bounds__(512)
void vmean_kernel(const bf16* __restrict__ v, int sv, float* __restrict__ vm) {
    int bh = blockIdx.x; int b = bh >> 3, h = bh & 7;
    int d = threadIdx.x & 63, sl = threadIdx.x >> 6;
    const unsigned short* vu = (const unsigned short*)v;
    float s = 0.0f;
    for (int si = sl; si < S_; si += 8) {
        unsigned short u = vu[(size_t)(b * S_ + si) * sv + h * D_ + d];
        s += __uint_as_float((unsigned)u << 16);
    }
    __shared__ float red[512];
    red[threadIdx.x] = s;
    __syncthreads();
    if (sl == 0) {
        float tot = 0.0f;
        for (int j = 0; j < 8; ++j) tot += red[j * 64 + d];
        vm[bh * D_ + d] = tot * (1.0f / (float)S_);
    }
}

// ---------------- bf16 MFMA GEMM (m97 structure) ----------------
template<int OBF>
__global__ __launch_bounds__(256)
void gemm_mfma(const bf16* __restrict__ A, const bf16* __restrict__ Wt,
               const float* __restrict__ bias, const float* __restrict__ resid,
               void* __restrict__ Cv, int M, int N, int K, float alpha, int relu)
{
    __shared__ bf16 As[128 * 64];
    __shared__ bf16 Bs[128 * 64];
    const int t = threadIdx.x;
    const int lane = t & 63, w = t >> 6;
    const int n0 = blockIdx.x * 128, m0 = blockIdx.y * 128;
    const int wr = w >> 1, wc = w & 1;
    const int srow = w * 8 + (lane >> 3);
    const int sslot = lane & 7;
    f32x4 acc[4][4] = {};

    for (int k0 = 0; k0 < K; k0 += 64) {
        __syncthreads();
        #pragma unroll
        for (int i = 0; i < 4; ++i) {
            int r = i * 32 + srow;
            int gslot = sslot ^ (r & 7);
            const bf16* ga = A  + (size_t)(m0 + r) * K + k0 + gslot * 8;
            const bf16* gb = Wt + (size_t)(n0 + r) * K + k0 + gslot * 8;
            __builtin_amdgcn_global_load_lds((const __attribute__((address_space(1))) void*)ga,
                                             (__attribute__((address_space(3))) void*)&As[r * 64 + sslot * 8],
                                             16, 0, 0);
            __builtin_amdgcn_global_load_lds((const __attribute__((address_space(1))) void*)gb,
                                             (__attribute__((address_space(3))) void*)&Bs[r * 64 + sslot * 8],
                                             16, 0, 0);
        }
        __syncthreads();
        #pragma unroll
        for (int kk = 0; kk < 2; ++kk) {
            short8 af[4], bq[4];
            const int q = kk * 4 + (lane >> 4);
            #pragma unroll
            for (int m = 0; m < 4; ++m) {
                int r = wr * 64 + m * 16 + (lane & 15);
                af[m] = *(const short8*)&As[r * 64 + (q ^ (r & 7)) * 8];
            }
            #pragma unroll
            for (int n = 0; n < 4; ++n) {
                int r = wc * 64 + n * 16 + (lane & 15);
                bq[n] = *(const short8*)&Bs[r * 64 + (q ^ (r & 7)) * 8];
            }
            #pragma unroll
            for (int m = 0; m < 4; ++m)
                #pragma unroll
                for (int n = 0; n < 4; ++n)
                    acc[m][n] = __builtin_amdgcn_mfma_f32_16x16x32_bf16(af[m], bq[n], acc[m][n], 0, 0, 0);
        }
    }

    const int lr = lane >> 4, lc = lane & 15;
    #pragma unroll
    for (int n = 0; n < 4; ++n) {
        int col = n0 + wc * 64 + n * 16 + lc;
        float bv = bias ? bias[col] : 0.0f;
        #pragma unroll
        for (int m = 0; m < 4; ++m) {
            #pragma unroll
            for (int r = 0; r < 4; ++r) {
                int row = m0 + wr * 64 + m * 16 + lr * 4 + r;
                float val = acc[m][n][r] * alpha + bv;
                if (relu) val = fmaxf(val, 0.0f);
                if (resid) val += resid[(size_t)row * N + col];
                if (OBF) ((bf16*)Cv)[(size_t)row * N + col] = __float2bfloat16(val);
                else     ((float*)Cv)[(size_t)row * N + col] = val;
            }
        }
    }
}

// ---------------- MFMA flash attention (no cross-wave merge) ----------------
// Block: (b, h, qb-pair). 4 waves = 2 q-halves (wq) x 2 q-blocks (wk; qb = 2*qbp+wk).
// Each wave-pair owns one q-block completely. 32x32x16 MFMA.
// Swapped QK^T (lane owns q=lane&31 scores); PV as O^T = V^T P^T (rescale per-lane).
// V slot for PV includes the ks half: c = (4*ks + 2*Hh + h5) ^ swizzle.
// P fed to PV as two-term bf16 split (hi + residual) -> ~f32 precision.
// Block-sparse skip exact (skipped blocks give p=0 in f32 ref). m<=-5e8 -> vmean.
__global__ __launch_bounds__(256)
void attn_mfma(const bf16* __restrict__ qp, const bf16* __restrict__ kp,
               const bf16* __restrict__ vp, bf16* __restrict__ op,
               const unsigned char* __restrict__ bm,
               const int* __restrict__ targets, const float* __restrict__ srcmask,
               const float* __restrict__ vmean,
               int sq, int sk, int sv, int causal)
{
    __shared__ __align__(16) unsigned char lds[49280];
    // Ks[wk]: wk*8192 | Vt[wk]: 16384+wk*8192 | Qs[wk]: 32768+wk*8192 | padb: 49152
    unsigned long long* padb = (unsigned long long*)(lds + 49152);

    const int bid = blockIdx.x;
    const int qbp = bid & 7, h = (bid >> 3) & 7, b = bid >> 6;
    const int tid = threadIdx.x;
    const int w = tid >> 6, lane = tid & 63;
    const int wq = w & 1, wk = w >> 1;
    const int qb = 2 * qbp + wk;
    const int h5 = lane >> 5, l31 = lane & 31;

    unsigned char* Ks = lds + wk * 8192;
    unsigned char* Vt = lds + 16384 + wk * 8192;
    unsigned char* Qs = lds + 32768 + wk * 8192;

    // ---- stage Q (own pair's 64 rows x 64 d, XOR-swizzled via source) ----
    #pragma unroll
    for (int j = 0; j < 4; ++j) {
        int r = wq * 32 + j * 8 + (lane >> 3);
        int g = (lane & 7) ^ (r & 7);
        const bf16* src = qp + (size_t)(b * S_ + qb * 64 + r) * sq + h * 64 + g * 8;
        __builtin_amdgcn_global_load_lds((const __attribute__((address_space(1))) void*)src,
            (__attribute__((address_space(3))) void*)(Qs + wq * 4096 + j * 1024 + lane * 16),
            16, 0, 0);
    }
    __syncthreads();
    short8 qfrag[4];
    {
        int qrow = wq * 32 + l31;
        #pragma unroll
        for (int t = 0; t < 4; ++t) {
            int c = (2 * t + h5) ^ (qrow & 7);
            qfrag[t] = *(const short8*)(Qs + qrow * 128 + c * 16);
        }
    }

    const int q_in = wq * 32 + l31;
    const int qg = qb * 64 + q_in;
    const bool padq = targets[b * S_ + qg] > 0;

    // full block list for THIS pair's q-block; nIter = max over both pairs (barrier match)
    unsigned long long lstpk = 0ULL;
    int myn = 0;
    {
        int kbmax = causal ? qb : 15;
        for (int kb = 0; kb <= kbmax; ++kb)
            if (bm[qb * 16 + kb]) { lstpk |= ((unsigned long long)kb) << (4 * myn); ++myn; }
    }
    int nIter;
    {
        int qbo = 2 * qbp + 1;
        int kbmaxo = causal ? qbo : 15;
        int cnto = 0;
        for (int kb = 0; kb <= kbmaxo; ++kb) if (bm[qbo * 16 + kb]) ++cnto;
        nIter = cnto > myn ? cnto : myn;
    }

    float mrun = -3.0e38f, lrun = 0.0f;
    f32x16 acc0 = {}, acc1 = {};

    for (int it = 0; it < nIter; ++it) {
        bool active = it < myn;
        int kb = (int)((lstpk >> (4 * it)) & 15ULL);
        if (active) {
            // stage K [64 k][64 d], swizzled source
            #pragma unroll
            for (int j = 0; j < 4; ++j) {
                int r = j * 16 + wq * 8 + (lane >> 3);
                int g = (lane & 7) ^ (r & 7);
                const bf16* src = kp + (size_t)(b * S_ + kb * 64 + r) * sk + h * 64 + g * 8;
                __builtin_amdgcn_global_load_lds((const __attribute__((address_space(1))) void*)src,
                    (__attribute__((address_space(3))) void*)(Ks + (j * 16 + wq * 8) * 128 + lane * 16),
                    16, 0, 0);
            }
            // stage V transposed -> Vt[d][k], packed pair writes, swizzled
            #pragma unroll
            for (int itv = 0; itv < 2; ++itv) {
                int k2 = 2 * l31;
                int d0 = h5 * 8 + (wq * 2 + itv) * 16;
                const unsigned short* v0 = (const unsigned short*)vp +
                    (size_t)(b * S_ + kb * 64 + k2) * sv + h * 64 + d0;
                short8 va = *(const short8*)v0;
                short8 vb = *(const short8*)(v0 + sv);
                #pragma unroll
                for (int j2 = 0; j2 < 8; ++j2) {
                    int d = d0 + j2;
                    unsigned int pkv = ((unsigned int)(unsigned short)va[j2]) |
                                       (((unsigned int)(unsigned short)vb[j2]) << 16);
                    int off = d * 128 + (((k2 >> 3) ^ (d & 7)) * 16) + (k2 & 7) * 2;
                    *(unsigned int*)(Vt + off) = pkv;
                }
            }
            if (wq == 0) {
                int pos = b * S_ + kb * 64 + lane;
                bool pk_ = srcmask ? (srcmask[pos] > 0.0f) : (targets[pos] > 0);
                unsigned long long bits = __ballot(pk_);
                if (lane == 0) padb[wk] = bits;
            }
        }
        __syncthreads();
        if (active) {
            bool diag = causal && (kb == qb);
            unsigned long long pb = padb[wk];
            #pragma unroll
            for (int ks = 0; ks < 2; ++ks) {
                f32x16 sacc = {};
                #pragma unroll
                for (int t = 0; t < 4; ++t) {
                    int row = ks * 32 + l31;
                    int c = (2 * t + h5) ^ (row & 7);
                    short8 kfrag = *(const short8*)(Ks + row * 128 + c * 16);
                    sacc = __builtin_amdgcn_mfma_f32_32x32x16_bf16(kfrag, qfrag[t], sacc, 0, 0, 0);
                }
                float p[16];
                float mloc = -3.0e38f;
                #pragma unroll
                for (int r = 0; r < 16; ++r) {
                    int kl = ks * 32 + (r & 3) + 8 * (r >> 2) + 4 * h5;
                    bool ok = padq && (((pb >> kl) & 1ULL) != 0) && (!diag || kl <= q_in);
                    p[r] = ok ? sacc[r] * 0.125f : -1.0e9f;
                    mloc = fmaxf(mloc, p[r]);
                }
                mloc = fmaxf(mloc, __shfl_xor(mloc, 32));
                float mnew = fmaxf(mrun, mloc);
                float rescale = __expf(mrun - mnew);
                float lsum = 0.0f;
                #pragma unroll
                for (int r = 0; r < 16; ++r) { p[r] = __expf(p[r] - mnew); lsum += p[r]; }
                lsum += __shfl_xor(lsum, 32);
                lrun = lrun * rescale + lsum;
                mrun = mnew;
                acc0 *= rescale;
                acc1 *= rescale;
                // two-term bf16 split of P: p = hi + lo, each packed as 2x bf16
                unsigned int pk_hi[4][2], pk_lo[4][2];
                #pragma unroll
                for (int t4 = 0; t4 < 4; ++t4)
                    #pragma unroll
                    for (int u = 0; u < 2; ++u) {
                        float a = p[4 * t4 + 2 * u];
                        float c = p[4 * t4 + 2 * u + 1];
                        unsigned int ph = pack2bf(a, c);
                        float ah = __uint_as_float(ph << 16);
                        float ch = __uint_as_float(ph & 0xffff0000u);
                        pk_hi[t4][u] = ph;
                        pk_lo[t4][u] = pack2bf(a - ah, c - ch);
                    }
                #pragma unroll
                for (int Hh = 0; Hh < 2; ++Hh) {
                    unsigned int hu0 = (unsigned int)__shfl_xor((int)pk_hi[2 * Hh + 1][0], 32);
                    unsigned int hu1 = (unsigned int)__shfl_xor((int)pk_hi[2 * Hh + 1][1], 32);
                    unsigned int hl0 = (unsigned int)__shfl_xor((int)pk_hi[2 * Hh][0], 32);
                    unsigned int hl1 = (unsigned int)__shfl_xor((int)pk_hi[2 * Hh][1], 32);
                    uint4v hv = {h5 ? hu0 : pk_hi[2 * Hh][0],
                                 h5 ? hu1 : pk_hi[2 * Hh][1],
                                 h5 ? pk_hi[2 * Hh + 1][0] : hl0,
                                 h5 ? pk_hi[2 * Hh + 1][1] : hl1};
                    short8 bfrag_hi = __builtin_bit_cast(short8, hv);
                    unsigned int lu0 = (unsigned int)__shfl_xor((int)pk_lo[2 * Hh + 1][0], 32);
                    unsigned int lu1 = (unsigned int)__shfl_xor((int)pk_lo[2 * Hh + 1][1], 32);
                    unsigned int ll0 = (unsigned int)__shfl_xor((int)pk_lo[2 * Hh][0], 32);
                    unsigned int ll1 = (unsigned int)__shfl_xor((int)pk_lo[2 * Hh][1], 32);
                    uint4v lv = {h5 ? lu0 : pk_lo[2 * Hh][0],
                                 h5 ? lu1 : pk_lo[2 * Hh][1],
                                 h5 ? pk_lo[2 * Hh + 1][0] : ll0,
                                 h5 ? pk_lo[2 * Hh + 1][1] : ll1};
                    short8 bfrag_lo = __builtin_bit_cast(short8, lv);
                    #pragma unroll
                    for (int f = 0; f < 2; ++f) {
                        int row = f * 32 + l31;
                        int c = (4 * ks + 2 * Hh + h5) ^ (row & 7);   // ks-half of V
                        short8 vfrag = *(const short8*)(Vt + row * 128 + c * 16);
                        if (f == 0) {
                            acc0 = __builtin_amdgcn_mfma_f32_32x32x16_bf16(vfrag, bfrag_hi, acc0, 0, 0, 0);
                            acc0 = __builtin_amdgcn_mfma_f32_32x32x16_bf16(vfrag, bfrag_lo, acc0, 0, 0, 0);
                        } else {
                            acc1 = __builtin_amdgcn_mfma_f32_32x32x16_bf16(vfrag, bfrag_hi, acc1, 0, 0, 0);
                            acc1 = __builtin_amdgcn_mfma_f32_32x32x16_bf16(vfrag, bfrag_lo, acc1, 0, 0, 0);
                        }
                    }
                }
            }
        }
        __syncthreads();
    }

    // ---- direct write-out (each wave owns its 32 q-rows completely) ----
    bool okrow = mrun > -5.0e8f;
    float inv = okrow ? 1.0f / lrun : 0.0f;
    const float* vmp = vmean + (b * 8 + h) * 64;
    unsigned short* orow = (unsigned short*)op + (size_t)(b * S_ + qg) * E_ + h * 64;
    #pragma unroll
    for (int f = 0; f < 2; ++f)
        #pragma unroll
        for (int t4 = 0; t4 < 4; ++t4)
            #pragma unroll
            for (int u = 0; u < 2; ++u) {
                int r = 4 * t4 + 2 * u;
                int d = f * 32 + 2 * u + 8 * t4 + 4 * h5;
                float a0 = f ? acc1[r] : acc0[r];
                float a1 = f ? acc1[r + 1] : acc0[r + 1];
                float v0 = a0 * inv;
                float v1 = a1 * inv;
                if (!okrow) { v0 = vmp[d]; v1 = vmp[d + 1]; }
                *(unsigned int*)(orow + d) = pack2bf(v0, v1);
            }
}

extern "C" void kernel_launch(void* const* d_in, const int* in_sizes, int n_in,
                              void* d_out, int out_size, void* d_ws, size_t ws_size,
                              hipStream_t stream)
{
    const float* encoded  = (const float*)d_in[0];
    const float* srcmask  = (const float*)d_in[1];
    const int*   targets  = (const int*)d_in[2];
    const float* table    = (const float*)d_in[3];
    const float* pos      = (const float*)d_in[4];
    const float* ln1_s = (const float*)d_in[5];
    const float* ln1_b = (const float*)d_in[6];
    const float* ln2_s = (const float*)d_in[7];
    const float* ln2_b = (const float*)d_in[8];
    const float* ln3_s = (const float*)d_in[9];
    const float* ln3_b = (const float*)d_in[10];
    const float* self_wq = (const float*)d_in[11];
    const float* self_wk = (const float*)d_in[12];
    const float* self_wv = (const float*)d_in[13];
    const float* self_wo = (const float*)d_in[14];
    const float* cross_wq = (const float*)d_in[15];
    const float* cross_wk = (const float*)d_in[16];
    const float* cross_wv = (const float*)d_in[17];
    const float* cross_wo = (const float*)d_in[18];
    const float* mlp_w1 = (const float*)d_in[19];
    const float* mlp_b1 = (const float*)d_in[20];
    const float* mlp_w2 = (const float*)d_in[21];
    const float* mlp_b2 = (const float*)d_in[22];
    const float* final_s = (const float*)d_in[23];
    const float* final_b = (const float*)d_in[24];
    const float* logit_w = (const float*)d_in[25];
    const float* logit_b = (const float*)d_in[26];
    float* out = (float*)d_out;

    char* ws = (char*)d_ws;
    unsigned char* masks = (unsigned char*)ws;
    size_t off = 1024;
    auto alloc = [&](size_t bytes) {
        char* p = ws + off;
        off += (bytes + 255) & ~(size_t)255;
        return p;
    };
    const size_t RS = (size_t)B_ * S_;   // 2048
    const size_t EE = (size_t)E_ * E_;
    float* y    = (float*)alloc(RS * E_ * 4);
    float* xb   = (float*)alloc(RS * E_ * 4);
    float* zb   = (float*)alloc(RS * E_ * 4);
    bf16* lnb   = (bf16*)alloc(RS * E_ * 2);
    bf16* qkvb  = (bf16*)alloc(RS * 3 * E_ * 2);
    bf16* kvb   = (bf16*)alloc(RS * 2 * E_ * 2);
    bf16* qb2   = (bf16*)alloc(RS * E_ * 2);
    bf16* ob    = (bf16*)alloc(RS * E_ * 2);
    bf16* hid   = (bf16*)alloc(RS * M_ * 2);
    bf16* encb  = (bf16*)alloc(RS * E_ * 2);
    float* vmean = (float*)alloc(B_ * H_ * D_ * 4);
    bf16* qkv_t = (bf16*)alloc((size_t)L_ * 3 * EE * 2);
    bf16* swo_t = (bf16*)alloc((size_t)L_ * EE * 2);
    bf16* cq_t  = (bf16*)alloc((size_t)L_ * EE * 2);
    bf16* ckv_t = (bf16*)alloc((size_t)L_ * 2 * EE * 2);
    bf16* cwo_t = (bf16*)alloc((size_t)L_ * EE * 2);
    bf16* w1_t  = (bf16*)alloc((size_t)L_ * E_ * M_ * 2);
    bf16* w2_t  = (bf16*)alloc((size_t)L_ * M_ * E_ * 2);
    bf16* wl_t  = (bf16*)alloc((size_t)E_ * V_ * 2);

    const int R = (int)RS;

    build_masks_kernel<<<1, 256, 0, stream>>>(masks);
    embed_kernel<<<R, 128, 0, stream>>>(targets, table, pos, y);
    cvt_kernel<<<(R * E_) / 1024, 256, 0, stream>>>(encoded, encb);

    {
        dim3 gpp(E_ / 32, E_ / 32, L_);
        tconv_kernel<<<gpp, 256, 0, stream>>>(self_wq, qkv_t + 0 * EE, E_, E_, EE, 3 * EE);
        tconv_kernel<<<gpp, 256, 0, stream>>>(self_wk, qkv_t + 1 * EE, E_, E_, EE, 3 * EE);
        tconv_kernel<<<gpp, 256, 0, stream>>>(self_wv, qkv_t + 2 * EE, E_, E_, EE, 3 * EE);
        tconv_kernel<<<gpp, 256, 0, stream>>>(self_wo, swo_t, E_, E_, EE, EE);
        tconv_kernel<<<gpp, 256, 0, stream>>>(cross_wq, cq_t, E_, E_, EE, EE);
        tconv_kernel<<<gpp, 256, 0, stream>>>(cross_wk, ckv_t + 0 * EE, E_, E_, EE, 2 * EE);
        tconv_kernel<<<gpp, 256, 0, stream>>>(cross_wv, ckv_t + 1 * EE, E_, E_, EE, 2 * EE);
        tconv_kernel<<<gpp, 256, 0, stream>>>(cross_wo, cwo_t, E_, E_, EE, EE);
        dim3 g1(E_ / 32, M_ / 32, L_);
        tconv_kernel<<<g1, 256, 0, stream>>>(mlp_w1, w1_t, E_, M_, (size_t)E_ * M_, (size_t)E_ * M_);
        dim3 g2(M_ / 32, E_ / 32, L_);
        tconv_kernel<<<g2, 256, 0, stream>>>(mlp_w2, w2_t, M_, E_, (size_t)M_ * E_, (size_t)M_ * E_);
        dim3 g3(E_ / 32, V_ / 32, 1);
        tconv_kernel<<<g3, 256, 0, stream>>>(logit_w, wl_t, E_, V_, 0, 0);
    }

    dim3 gqkv(3 * E_ / 128, R / 128);
    dim3 gkv(2 * E_ / 128, R / 128);
    dim3 gp(E_ / 128, R / 128);
    dim3 g1(M_ / 128, R / 128);
    dim3 gl(V_ / 128, R / 128);
    const int attn_grid = B_ * H_ * 8;   // (b, h, qb-pair)

    for (int l = 0; l < L_; ++l) {
        // ---- self attention ----
        ln_kernel<<<R, 256, 0, stream>>>(y, lnb, ln1_s + l * E_, ln1_b + l * E_);
        gemm_mfma<1><<<gqkv, 256, 0, stream>>>(lnb, qkv_t + (size_t)l * 3 * EE, nullptr, nullptr, qkvb, R, 3 * E_, E_, 1.0f, 0);
        vmean_kernel<<<B_ * H_, 512, 0, stream>>>(qkvb + 2 * E_, 3 * E_, vmean);
        attn_mfma<<<attn_grid, 256, 0, stream>>>(qkvb, qkvb + E_, qkvb + 2 * E_, ob, masks + l * 256,
                                                 targets, nullptr, vmean, 3 * E_, 3 * E_, 3 * E_, 1);
        gemm_mfma<0><<<gp, 256, 0, stream>>>(ob, swo_t + (size_t)l * EE, nullptr, y, xb, R, E_, E_, 1.0f, 0);
        // ---- cross attention ----
        ln_kernel<<<R, 256, 0, stream>>>(xb, lnb, ln2_s + l * E_, ln2_b + l * E_);
        gemm_mfma<1><<<gp, 256, 0, stream>>>(lnb, cq_t + (size_t)l * EE, nullptr, nullptr, qb2, R, E_, E_, 1.0f, 0);
        gemm_mfma<1><<<gkv, 256, 0, stream>>>(encb, ckv_t + (size_t)l * 2 * EE, nullptr, nullptr, kvb, R, 2 * E_, E_, 1.0f, 0);
        vmean_kernel<<<B_ * H_, 512, 0, stream>>>(kvb + E_, 2 * E_, vmean);
        attn_mfma<<<attn_grid, 256, 0, stream>>>(qb2, kvb, kvb + E_, ob, masks + (2 + l) * 256,
                                                 targets, srcmask, vmean, E_, 2 * E_, 2 * E_, 0);
        gemm_mfma<0><<<gp, 256, 0, stream>>>(ob, cwo_t + (size_t)l * EE, nullptr, xb, zb, R, E_, E_, 1.0f, 0);
        // ---- MLP ----
        ln_kernel<<<R, 256, 0, stream>>>(zb, lnb, ln3_s + l * E_, ln3_b + l * E_);
        gemm_mfma<1><<<g1, 256, 0, stream>>>(lnb, w1_t + (size_t)l * E_ * M_, mlp_b1 + (size_t)l * M_, nullptr, hid, R, M_, E_, 1.0f, 1);
        gemm_mfma<0><<<gp, 256, 0, stream>>>(hid, w2_t + (size_t)l * M_ * E_, mlp_b2 + (size_t)l * E_, zb, y, R, E_, M_, 1.0f, 0);
    }

    ln_kernel<<<R, 256, 0, stream>>>(y, lnb, final_s, final_b);
    gemm_mfma<0><<<gl, 256, 0, stream>>>(lnb, wl_t, logit_b, nullptr, out, R, V_, E_, 1.0f, 0);
}

// Round 8
// 1023.600 us; speedup vs baseline: 4.4225x; 1.0259x over previous
//
#include <hip/hip_runtime.h>
#include <hip/hip_bf16.h>
#include <stdint.h>

#define B_ 2
#define S_ 1024
#define E_ 512
#define H_ 8
#define D_ 64
#define M_ 2048
#define V_ 32000
#define L_ 2

typedef __hip_bfloat16 bf16;
typedef __attribute__((ext_vector_type(8))) short short8;
typedef __attribute__((ext_vector_type(4))) float f32x4;
typedef __attribute__((ext_vector_type(16))) float f32x16;
typedef __attribute__((ext_vector_type(4))) unsigned int uint4v;

__device__ inline unsigned int pack2bf(float lo, float hi) {
    __hip_bfloat16 a = __float2bfloat16(lo), b = __float2bfloat16(hi);
    unsigned short ua = *(unsigned short*)&a, ub = *(unsigned short*)&b;
    return (unsigned int)ua | ((unsigned int)ub << 16);
}

// ---------------- numpy legacy RandomState (MT19937), LDS-resident ----------------
#define MT_N 624
#define MT_M 397
#define MT_UP   0x80000000u
#define MT_LOW  0x7fffffffu
#define MT_MAT  0x9908b0dfu

__device__ inline unsigned int mt_temper(unsigned int y) {
    y ^= y >> 11;
    y ^= (y << 7) & 0x9d2c5680u;
    y ^= (y << 15) & 0xefc60000u;
    y ^= y >> 18;
    return y;
}

__global__ __launch_bounds__(256)
void build_masks_kernel(unsigned char* masks) {
    __shared__ unsigned int mto[4][MT_N];
    __shared__ unsigned int mtn[4][MT_N];
    const int w = threadIdx.x >> 6, lane = threadIdx.x & 63;
    const unsigned int seeds[4] = {1000u, 1001u, 0u, 1u};
    unsigned char* m = masks + w * 256;

    for (int idx = lane; idx < 256; idx += 64) {
        int i = idx >> 4, j = idx & 15;
        bool v = (j >= i - 1 && j <= i + 1) || i == 0 || i == 15 || j == 0 || j == 15;
        m[idx] = v ? 1 : 0;
    }

    if (lane == 0) {
        unsigned int s = seeds[w];
        for (int i = 0; i < MT_N; ++i) {
            mto[w][i] = s;
            s = 1812433253u * (s ^ (s >> 30)) + (unsigned int)(i + 1);
        }
    }
    __syncthreads();

    for (int i = lane; i < MT_N - MT_M; i += 64) {             // A: 227 elems
        unsigned int y = (mto[w][i] & MT_UP) | (mto[w][i + 1] & MT_LOW);
        mtn[w][i] = mto[w][i + MT_M] ^ (y >> 1) ^ ((y & 1u) ? MT_MAT : 0u);
    }
    __syncthreads();
    for (int i = 227 + lane; i < 454; i += 64) {               // B1
        unsigned int y = (mto[w][i] & MT_UP) | (mto[w][i + 1] & MT_LOW);
        mtn[w][i] = mtn[w][i - 227] ^ (y >> 1) ^ ((y & 1u) ? MT_MAT : 0u);
    }
    __syncthreads();
    for (int i = 454 + lane; i < MT_N - 1; i += 64) {          // B2
        unsigned int y = (mto[w][i] & MT_UP) | (mto[w][i + 1] & MT_LOW);
        mtn[w][i] = mtn[w][i - 227] ^ (y >> 1) ^ ((y & 1u) ? MT_MAT : 0u);
    }
    __syncthreads();
    if (lane == 0) {                                           // C: i = 623
        unsigned int y = (mto[w][MT_N - 1] & MT_UP) | (mtn[w][0] & MT_LOW);
        mtn[w][MT_N - 1] = mtn[w][MT_M - 1] ^ (y >> 1) ^ ((y & 1u) ? MT_MAT : 0u);
    }
    __syncthreads();

    if (lane == 0) {
        int idx = 0;
        for (int i = 0; i < 16; ++i) {
            unsigned long long arr = 0xFEDCBA9876543210ULL;
            for (int k = 15; k > 0; --k) {
                unsigned int mask = k;
                mask |= mask >> 1; mask |= mask >> 2; mask |= mask >> 4;
                unsigned int j;
                for (;;) {
                    if (idx >= MT_N) {
                        int i2 = 0;
                        for (; i2 < MT_N - MT_M; ++i2) {
                            unsigned int y2 = (mtn[w][i2] & MT_UP) | (mtn[w][i2 + 1] & MT_LOW);
                            mtn[w][i2] = mtn[w][i2 + MT_M] ^ (y2 >> 1) ^ ((y2 & 1u) ? MT_MAT : 0u);
                        }
                        for (; i2 < MT_N - 1; ++i2) {
                            unsigned int y2 = (mtn[w][i2] & MT_UP) | (mtn[w][i2 + 1] & MT_LOW);
                            mtn[w][i2] = mtn[w][i2 - 227] ^ (y2 >> 1) ^ ((y2 & 1u) ? MT_MAT : 0u);
                        }
                        unsigned int y2 = (mtn[w][MT_N - 1] & MT_UP) | (mtn[w][0] & MT_LOW);
                        mtn[w][MT_N - 1] = mtn[w][MT_M - 1] ^ (y2 >> 1) ^ ((y2 & 1u) ? MT_MAT : 0u);
                        idx = 0;
                    }
                    j = mt_temper(mtn[w][idx++]) & mask;
                    if (j <= (unsigned int)k) break;
                }
                unsigned int a = (unsigned int)(arr >> (4 * k)) & 15u;
                unsigned int bnib = (unsigned int)(arr >> (4 * j)) & 15u;
                arr &= ~((15ULL << (4 * k)) | (15ULL << (4 * j)));
                arr |= ((unsigned long long)a << (4 * j)) | ((unsigned long long)bnib << (4 * k));
            }
            m[i * 16 + ((arr >> 0) & 15)] = 1;
            m[i * 16 + ((arr >> 4) & 15)] = 1;
            m[i * 16 + ((arr >> 8) & 15)] = 1;
        }
    }
}

// ---------------- embedding ----------------
__global__ void embed_kernel(const int* __restrict__ targets,
                             const float* __restrict__ table,
                             const float* __restrict__ pos,
                             float* __restrict__ y) {
    int row = blockIdx.x;
    int s = row & (S_ - 1);
    int b = row >> 10;
    int id = (s == 0) ? 0 : targets[b * S_ + s - 1];
    int c = threadIdx.x * 4;
    float4 e = *(const float4*)&table[(size_t)id * E_ + c];
    float4 p = *(const float4*)&pos[(size_t)s * E_ + c];
    e.x += p.x; e.y += p.y; e.z += p.z; e.w += p.w;
    *(float4*)&y[(size_t)row * E_ + c] = e;
}

// ---------------- layernorm f32 -> bf16 ----------------
__global__ __launch_bounds__(256)
void ln_kernel(const float* __restrict__ x, bf16* __restrict__ y,
               const float* __restrict__ sc, const float* __restrict__ bi) {
    int row = blockIdx.x;
    int t = threadIdx.x;
    const float* xr = x + (size_t)row * E_;
    float2 v = *(const float2*)&xr[t * 2];
    float sum = v.x + v.y;
    float sq = v.x * v.x + v.y * v.y;
    for (int off = 32; off > 0; off >>= 1) {
        sum += __shfl_xor(sum, off);
        sq  += __shfl_xor(sq, off);
    }
    __shared__ float s0[4], s1[4];
    int w = t >> 6;
    if ((t & 63) == 0) { s0[w] = sum; s1[w] = sq; }
    __syncthreads();
    sum = s0[0] + s0[1] + s0[2] + s0[3];
    sq  = s1[0] + s1[1] + s1[2] + s1[3];
    float mu = sum * (1.0f / (float)E_);
    float var = sq * (1.0f / (float)E_) - mu * mu;
    float rs = rsqrtf(var + 1e-6f);
    float2 s2 = *(const float2*)&sc[t * 2];
    float2 b2 = *(const float2*)&bi[t * 2];
    bf16* yr = y + (size_t)row * E_ + t * 2;
    yr[0] = __float2bfloat16((v.x - mu) * rs * s2.x + b2.x);
    yr[1] = __float2bfloat16((v.y - mu) * rs * s2.y + b2.y);
}

// ---------------- transpose+convert: W[K][N] f32 -> Wt[N][K] bf16 ----------------
__global__ __launch_bounds__(256)
void tconv_kernel(const float* __restrict__ W, bf16* __restrict__ Wt,
                  int K, int N, size_t src_stride, size_t dst_stride) {
    __shared__ float Ts[32][33];
    const float* Wb = W + blockIdx.z * src_stride;
    bf16* Wtb = Wt + blockIdx.z * dst_stride;
    int k0 = blockIdx.x * 32, n0 = blockIdx.y * 32;
    int lx = threadIdx.x & 31, ly = threadIdx.x >> 5;
    for (int r = ly; r < 32; r += 8)
        Ts[r][lx] = Wb[(size_t)(k0 + r) * N + n0 + lx];
    __syncthreads();
    for (int r = ly; r < 32; r += 8)
        Wtb[(size_t)(n0 + r) * K + k0 + lx] = __float2bfloat16(Ts[lx][r]);
}

// ---------------- fused 16x E_xE_ transpose+convert (one launch) ----------------
struct TP16 { const float* s[16]; bf16* d[16]; };
__global__ __launch_bounds__(256)
void tconv16_kernel(TP16 p) {
    __shared__ float Ts[32][33];
    const float* W = p.s[blockIdx.z];
    bf16* Wt = p.d[blockIdx.z];
    int k0 = blockIdx.x * 32, n0 = blockIdx.y * 32;
    int lx = threadIdx.x & 31, ly = threadIdx.x >> 5;
    for (int r = ly; r < 32; r += 8)
        Ts[r][lx] = W[(size_t)(k0 + r) * E_ + n0 + lx];
    __syncthreads();
    for (int r = ly; r < 32; r += 8)
        Wt[(size_t)(n0 + r) * E_ + k0 + lx] = __float2bfloat16(Ts[lx][r]);
}

// ---------------- f32 -> bf16 elementwise ----------------
__global__ void cvt_kernel(const float* __restrict__ x, bf16* __restrict__ y) {
    int i = (blockIdx.x * blockDim.x + threadIdx.x) * 4;
    float4 v = *(const float4*)&x[i];
    y[i + 0] = __float2bfloat16(v.x);
    y[i + 1] = __float2bfloat16(v.y);
    y[i + 2] = __float2bfloat16(v.z);
    y[i + 3] = __float2bfloat16(v.w);
}

// ---------------- vmean[b][h][d] = mean_s v[b][s][h][d] ----------------
__global__ __launch_bounds__(512)
void vmean_kernel(const bf16* __restrict__ v, int sv, float* __restrict__ vm) {
    int bh = blockIdx.x; int b = bh >> 3, h = bh & 7;
    int d = threadIdx.x & 63, sl = threadIdx.x >> 6;
    const unsigned short* vu = (const unsigned short*)v;
    float s = 0.0f;
    for (int si = sl; si < S_; si += 8) {
        unsigned short u = vu[(size_t)(b * S_ + si) * sv + h * D_ + d];
        s += __uint_as_float((unsigned)u << 16);
    }
    __shared__ float red[512];
    red[threadIdx.x] = s;
    __syncthreads();
    if (sl == 0) {
        float tot = 0.0f;
        for (int j = 0; j < 8; ++j) tot += red[j * 64 + d];
        vm[bh * D_ + d] = tot * (1.0f / (float)S_);
    }
}

// ---------------- bf16 MFMA GEMM (m97 structure, XCD-swizzled) ----------------
template<int OBF>
__global__ __launch_bounds__(256)
void gemm_mfma(const bf16* __restrict__ A, const bf16* __restrict__ Wt,
               const float* __restrict__ bias, const float* __restrict__ resid,
               void* __restrict__ Cv, int M, int N, int K, float alpha, int relu)
{
    __shared__ bf16 As[128 * 64];
    __shared__ bf16 Bs[128 * 64];
    const int t = threadIdx.x;
    const int lane = t & 63, w = t >> 6;
    // bijective XCD swizzle (m204): contiguous chunk per XCD; M-tiles fastest so
    // consecutive blocks on an XCD share the same Wt panel (B reuse in L2).
    int m0, n0;
    {
        int nwg = gridDim.x * gridDim.y;
        int lin = blockIdx.x + gridDim.x * blockIdx.y;
        int q = nwg >> 3, r = nwg & 7;
        int xcd = lin & 7, off8 = lin >> 3;
        int swz = ((xcd < r) ? xcd * (q + 1) : r * (q + 1) + (xcd - r) * q) + off8;
        int gridM = gridDim.y;
        m0 = (swz % gridM) * 128;
        n0 = (swz / gridM) * 128;
    }
    const int wr = w >> 1, wc = w & 1;
    const int srow = w * 8 + (lane >> 3);
    const int sslot = lane & 7;
    f32x4 acc[4][4] = {};

    for (int k0 = 0; k0 < K; k0 += 64) {
        __syncthreads();
        #pragma unroll
        for (int i = 0; i < 4; ++i) {
            int r = i * 32 + srow;
            int gslot = sslot ^ (r & 7);
            const bf16* ga = A  + (size_t)(m0 + r) * K + k0 + gslot * 8;
            const bf16* gb = Wt + (size_t)(n0 + r) * K + k0 + gslot * 8;
            __builtin_amdgcn_global_load_lds((const __attribute__((address_space(1))) void*)ga,
                                             (__attribute__((address_space(3))) void*)&As[r * 64 + sslot * 8],
                                             16, 0, 0);
            __builtin_amdgcn_global_load_lds((const __attribute__((address_space(1))) void*)gb,
                                             (__attribute__((address_space(3))) void*)&Bs[r * 64 + sslot * 8],
                                             16, 0, 0);
        }
        __syncthreads();
        #pragma unroll
        for (int kk = 0; kk < 2; ++kk) {
            short8 af[4], bq[4];
            const int q = kk * 4 + (lane >> 4);
            #pragma unroll
            for (int m = 0; m < 4; ++m) {
                int r = wr * 64 + m * 16 + (lane & 15);
                af[m] = *(const short8*)&As[r * 64 + (q ^ (r & 7)) * 8];
            }
            #pragma unroll
            for (int n = 0; n < 4; ++n) {
                int r = wc * 64 + n * 16 + (lane & 15);
                bq[n] = *(const short8*)&Bs[r * 64 + (q ^ (r & 7)) * 8];
            }
            #pragma unroll
            for (int m = 0; m < 4; ++m)
                #pragma unroll
                for (int n = 0; n < 4; ++n)
                    acc[m][n] = __builtin_amdgcn_mfma_f32_16x16x32_bf16(af[m], bq[n], acc[m][n], 0, 0, 0);
        }
    }

    const int lr = lane >> 4, lc = lane & 15;
    #pragma unroll
    for (int n = 0; n < 4; ++n) {
        int col = n0 + wc * 64 + n * 16 + lc;
        float bv = bias ? bias[col] : 0.0f;
        #pragma unroll
        for (int m = 0; m < 4; ++m) {
            #pragma unroll
            for (int r = 0; r < 4; ++r) {
                int row = m0 + wr * 64 + m * 16 + lr * 4 + r;
                float val = acc[m][n][r] * alpha + bv;
                if (relu) val = fmaxf(val, 0.0f);
                if (resid) val += resid[(size_t)row * N + col];
                if (OBF) ((bf16*)Cv)[(size_t)row * N + col] = __float2bfloat16(val);
                else     ((float*)Cv)[(size_t)row * N + col] = val;
            }
        }
    }
}

// ---------------- MFMA flash attention ----------------
// Block: (b, h, qb). 2 waves = 2 q-halves (wq). One q-block per workgroup:
// exact per-block list, no padding iterations, 256 blocks -> full CU coverage.
// 32x32x16 MFMA; swapped QK^T; PV as O^T = V^T P^T; V slot includes ks half.
// P fed to PV as two-term bf16 split (hi + residual) -> ~f32 precision.
// Block-sparse skip exact. m<=-5e8 -> vmean fallback (fully-masked row).
__global__ __launch_bounds__(128)
void attn_mfma(const bf16* __restrict__ qp, const bf16* __restrict__ kp,
               const bf16* __restrict__ vp, bf16* __restrict__ op,
               const unsigned char* __restrict__ bm,
               const int* __restrict__ targets, const float* __restrict__ srcmask,
               const float* __restrict__ vmean,
               int sq, int sk, int sv, int causal)
{
    __shared__ __align__(16) unsigned char lds[24592];
    // Ks: 0 | Vt: 8192 | Qs: 16384 | padb: 24576
    unsigned long long* padb = (unsigned long long*)(lds + 24576);

    const int bid = blockIdx.x;
    const int qb = bid & 15, h = (bid >> 4) & 7, b = bid >> 7;
    const int tid = threadIdx.x;
    const int wq = tid >> 6, lane = tid & 63;
    const int h5 = lane >> 5, l31 = lane & 31;

    unsigned char* Ks = lds;
    unsigned char* Vt = lds + 8192;
    unsigned char* Qs = lds + 16384;

    // ---- stage Q (64 rows x 64 d, XOR-swizzled via source) ----
    #pragma unroll
    for (int j = 0; j < 4; ++j) {
        int r = wq * 32 + j * 8 + (lane >> 3);
        int g = (lane & 7) ^ (r & 7);
        const bf16* src = qp + (size_t)(b * S_ + qb * 64 + r) * sq + h * 64 + g * 8;
        __builtin_amdgcn_global_load_lds((const __attribute__((address_space(1))) void*)src,
            (__attribute__((address_space(3))) void*)(Qs + wq * 4096 + j * 1024 + lane * 16),
            16, 0, 0);
    }
    __syncthreads();
    short8 qfrag[4];
    {
        int qrow = wq * 32 + l31;
        #pragma unroll
        for (int t = 0; t < 4; ++t) {
            int c = (2 * t + h5) ^ (qrow & 7);
            qfrag[t] = *(const short8*)(Qs + qrow * 128 + c * 16);
        }
    }

    const int q_in = wq * 32 + l31;
    const int qg = qb * 64 + q_in;
    const bool padq = targets[b * S_ + qg] > 0;

    // exact block list for this q-block
    unsigned long long lstpk = 0ULL;
    int myn = 0;
    {
        int kbmax = causal ? qb : 15;
        for (int kb = 0; kb <= kbmax; ++kb)
            if (bm[qb * 16 + kb]) { lstpk |= ((unsigned long long)kb) << (4 * myn); ++myn; }
    }

    float mrun = -3.0e38f, lrun = 0.0f;
    f32x16 acc0 = {}, acc1 = {};

    for (int it = 0; it < myn; ++it) {
        int kb = (int)((lstpk >> (4 * it)) & 15ULL);
        // stage K [64 k][64 d], swizzled source
        #pragma unroll
        for (int j = 0; j < 4; ++j) {
            int r = j * 16 + wq * 8 + (lane >> 3);
            int g = (lane & 7) ^ (r & 7);
            const bf16* src = kp + (size_t)(b * S_ + kb * 64 + r) * sk + h * 64 + g * 8;
            __builtin_amdgcn_global_load_lds((const __attribute__((address_space(1))) void*)src,
                (__attribute__((address_space(3))) void*)(Ks + (j * 16 + wq * 8) * 128 + lane * 16),
                16, 0, 0);
        }
        // stage V transposed -> Vt[d][k], packed pair writes, swizzled
        #pragma unroll
        for (int itv = 0; itv < 2; ++itv) {
            int k2 = 2 * l31;
            int d0 = h5 * 8 + (wq * 2 + itv) * 16;
            const unsigned short* v0 = (const unsigned short*)vp +
                (size_t)(b * S_ + kb * 64 + k2) * sv + h * 64 + d0;
            short8 va = *(const short8*)v0;
            short8 vb = *(const short8*)(v0 + sv);
            #pragma unroll
            for (int j2 = 0; j2 < 8; ++j2) {
                int d = d0 + j2;
                unsigned int pkv = ((unsigned int)(unsigned short)va[j2]) |
                                   (((unsigned int)(unsigned short)vb[j2]) << 16);
                int off = d * 128 + (((k2 >> 3) ^ (d & 7)) * 16) + (k2 & 7) * 2;
                *(unsigned int*)(Vt + off) = pkv;
            }
        }
        if (wq == 0) {
            int pos = b * S_ + kb * 64 + lane;
            bool pk_ = srcmask ? (srcmask[pos] > 0.0f) : (targets[pos] > 0);
            unsigned long long bits = __ballot(pk_);
            if (lane == 0) padb[0] = bits;
        }
        __syncthreads();
        {
            bool diag = causal && (kb == qb);
            unsigned long long pb = padb[0];
            #pragma unroll
            for (int ks = 0; ks < 2; ++ks) {
                f32x16 sacc = {};
                #pragma unroll
                for (int t = 0; t < 4; ++t) {
                    int row = ks * 32 + l31;
                    int c = (2 * t + h5) ^ (row & 7);
                    short8 kfrag = *(const short8*)(Ks + row * 128 + c * 16);
                    sacc = __builtin_amdgcn_mfma_f32_32x32x16_bf16(kfrag, qfrag[t], sacc, 0, 0, 0);
                }
                float p[16];
                float mloc = -3.0e38f;
                #pragma unroll
                for (int r = 0; r < 16; ++r) {
                    int kl = ks * 32 + (r & 3) + 8 * (r >> 2) + 4 * h5;
                    bool ok = padq && (((pb >> kl) & 1ULL) != 0) && (!diag || kl <= q_in);
                    p[r] = ok ? sacc[r] * 0.125f : -1.0e9f;
                    mloc = fmaxf(mloc, p[r]);
                }
                mloc = fmaxf(mloc, __shfl_xor(mloc, 32));
                float mnew = fmaxf(mrun, mloc);
                float rescale = __expf(mrun - mnew);
                float lsum = 0.0f;
                #pragma unroll
                for (int r = 0; r < 16; ++r) { p[r] = __expf(p[r] - mnew); lsum += p[r]; }
                lsum += __shfl_xor(lsum, 32);
                lrun = lrun * rescale + lsum;
                mrun = mnew;
                acc0 *= rescale;
                acc1 *= rescale;
                // two-term bf16 split of P: p = hi + lo, each packed as 2x bf16
                unsigned int pk_hi[4][2], pk_lo[4][2];
                #pragma unroll
                for (int t4 = 0; t4 < 4; ++t4)
                    #pragma unroll
                    for (int u = 0; u < 2; ++u) {
                        float a = p[4 * t4 + 2 * u];
                        float c = p[4 * t4 + 2 * u + 1];
                        unsigned int ph = pack2bf(a, c);
                        float ah = __uint_as_float(ph << 16);
                        float ch = __uint_as_float(ph & 0xffff0000u);
                        pk_hi[t4][u] = ph;
                        pk_lo[t4][u] = pack2bf(a - ah, c - ch);
                    }
                #pragma unroll
                for (int Hh = 0; Hh < 2; ++Hh) {
                    unsigned int hu0 = (unsigned int)__shfl_xor((int)pk_hi[2 * Hh + 1][0], 32);
                    unsigned int hu1 = (unsigned int)__shfl_xor((int)pk_hi[2 * Hh + 1][1], 32);
                    unsigned int hl0 = (unsigned int)__shfl_xor((int)pk_hi[2 * Hh][0], 32);
                    unsigned int hl1 = (unsigned int)__shfl_xor((int)pk_hi[2 * Hh][1], 32);
                    uint4v hv = {h5 ? hu0 : pk_hi[2 * Hh][0],
                                 h5 ? hu1 : pk_hi[2 * Hh][1],
                                 h5 ? pk_hi[2 * Hh + 1][0] : hl0,
                                 h5 ? pk_hi[2 * Hh + 1][1] : hl1};
                    short8 bfrag_hi = __builtin_bit_cast(short8, hv);
                    unsigned int lu0 = (unsigned int)__shfl_xor((int)pk_lo[2 * Hh + 1][0], 32);
                    unsigned int lu1 = (unsigned int)__shfl_xor((int)pk_lo[2 * Hh + 1][1], 32);
                    unsigned int ll0 = (unsigned int)__shfl_xor((int)pk_lo[2 * Hh][0], 32);
                    unsigned int ll1 = (unsigned int)__shfl_xor((int)pk_lo[2 * Hh][1], 32);
                    uint4v lv = {h5 ? lu0 : pk_lo[2 * Hh][0],
                                 h5 ? lu1 : pk_lo[2 * Hh][1],
                                 h5 ? pk_lo[2 * Hh + 1][0] : ll0,
                                 h5 ? pk_lo[2 * Hh + 1][1] : ll1};
                    short8 bfrag_lo = __builtin_bit_cast(short8, lv);
                    #pragma unroll
                    for (int f = 0; f < 2; ++f) {
                        int row = f * 32 + l31;
                        int c = (4 * ks + 2 * Hh + h5) ^ (row & 7);   // ks-half of V
                        short8 vfrag = *(const short8*)(Vt + row * 128 + c * 16);
                        if (f == 0) {
                            acc0 = __builtin_amdgcn_mfma_f32_32x32x16_bf16(vfrag, bfrag_hi, acc0, 0, 0, 0);
                            acc0 = __builtin_amdgcn_mfma_f32_32x32x16_bf16(vfrag, bfrag_lo, acc0, 0, 0, 0);
                        } else {
                            acc1 = __builtin_amdgcn_mfma_f32_32x32x16_bf16(vfrag, bfrag_hi, acc1, 0, 0, 0);
                            acc1 = __builtin_amdgcn_mfma_f32_32x32x16_bf16(vfrag, bfrag_lo, acc1, 0, 0, 0);
                        }
                    }
                }
            }
        }
        __syncthreads();
    }

    // ---- direct write-out (each wave owns its 32 q-rows completely) ----
    bool okrow = mrun > -5.0e8f;
    float inv = okrow ? 1.0f / lrun : 0.0f;
    const float* vmp = vmean + (b * 8 + h) * 64;
    unsigned short* orow = (unsigned short*)op + (size_t)(b * S_ + qg) * E_ + h * 64;
    #pragma unroll
    for (int f = 0; f < 2; ++f)
        #pragma unroll
        for (int t4 = 0; t4 < 4; ++t4)
            #pragma unroll
            for (int u = 0; u < 2; ++u) {
                int r = 4 * t4 + 2 * u;
                int d = f * 32 + 2 * u + 8 * t4 + 4 * h5;
                float a0 = f ? acc1[r] : acc0[r];
                float a1 = f ? acc1[r + 1] : acc0[r + 1];
                float v0 = a0 * inv;
                float v1 = a1 * inv;
                if (!okrow) { v0 = vmp[d]; v1 = vmp[d + 1]; }
                *(unsigned int*)(orow + d) = pack2bf(v0, v1);
            }
}

extern "C" void kernel_launch(void* const* d_in, const int* in_sizes, int n_in,
                              void* d_out, int out_size, void* d_ws, size_t ws_size,
                              hipStream_t stream)
{
    const float* encoded  = (const float*)d_in[0];
    const float* srcmask  = (const float*)d_in[1];
    const int*   targets  = (const int*)d_in[2];
    const float* table    = (const float*)d_in[3];
    const float* pos      = (const float*)d_in[4];
    const float* ln1_s = (const float*)d_in[5];
    const float* ln1_b = (const float*)d_in[6];
    const float* ln2_s = (const float*)d_in[7];
    const float* ln2_b = (const float*)d_in[8];
    const float* ln3_s = (const float*)d_in[9];
    const float* ln3_b = (const float*)d_in[10];
    const float* self_wq = (const float*)d_in[11];
    const float* self_wk = (const float*)d_in[12];
    const float* self_wv = (const float*)d_in[13];
    const float* self_wo = (const float*)d_in[14];
    const float* cross_wq = (const float*)d_in[15];
    const float* cross_wk = (const float*)d_in[16];
    const float* cross_wv = (const float*)d_in[17];
    const float* cross_wo = (const float*)d_in[18];
    const float* mlp_w1 = (const float*)d_in[19];
    const float* mlp_b1 = (const float*)d_in[20];
    const float* mlp_w2 = (const float*)d_in[21];
    const float* mlp_b2 = (const float*)d_in[22];
    const float* final_s = (const float*)d_in[23];
    const float* final_b = (const float*)d_in[24];
    const float* logit_w = (const float*)d_in[25];
    const float* logit_b = (const float*)d_in[26];
    float* out = (float*)d_out;

    char* ws = (char*)d_ws;
    unsigned char* masks = (unsigned char*)ws;
    size_t off = 1024;
    auto alloc = [&](size_t bytes) {
        char* p = ws + off;
        off += (bytes + 255) & ~(size_t)255;
        return p;
    };
    const size_t RS = (size_t)B_ * S_;   // 2048
    const size_t EE = (size_t)E_ * E_;
    float* y    = (float*)alloc(RS * E_ * 4);
    float* xb   = (float*)alloc(RS * E_ * 4);
    float* zb   = (float*)alloc(RS * E_ * 4);
    bf16* lnb   = (bf16*)alloc(RS * E_ * 2);
    bf16* qkvb  = (bf16*)alloc(RS * 3 * E_ * 2);
    bf16* kvb   = (bf16*)alloc(RS * 2 * E_ * 2);
    bf16* qb2   = (bf16*)alloc(RS * E_ * 2);
    bf16* ob    = (bf16*)alloc(RS * E_ * 2);
    bf16* hid   = (bf16*)alloc(RS * M_ * 2);
    bf16* encb  = (bf16*)alloc(RS * E_ * 2);
    float* vmean = (float*)alloc(B_ * H_ * D_ * 4);
    bf16* qkv_t = (bf16*)alloc((size_t)L_ * 3 * EE * 2);
    bf16* swo_t = (bf16*)alloc((size_t)L_ * EE * 2);
    bf16* cq_t  = (bf16*)alloc((size_t)L_ * EE * 2);
    bf16* ckv_t = (bf16*)alloc((size_t)L_ * 2 * EE * 2);
    bf16* cwo_t = (bf16*)alloc((size_t)L_ * EE * 2);
    bf16* w1_t  = (bf16*)alloc((size_t)L_ * E_ * M_ * 2);
    bf16* w2_t  = (bf16*)alloc((size_t)L_ * M_ * E_ * 2);
    bf16* wl_t  = (bf16*)alloc((size_t)E_ * V_ * 2);

    const int R = (int)RS;

    build_masks_kernel<<<1, 256, 0, stream>>>(masks);
    embed_kernel<<<R, 128, 0, stream>>>(targets, table, pos, y);
    cvt_kernel<<<(R * E_) / 1024, 256, 0, stream>>>(encoded, encb);

    {
        // fused 16x E x E transposes (8 weights x 2 layers) in one launch
        TP16 p;
        for (int l = 0; l < L_; ++l) {
            p.s[l * 8 + 0] = self_wq + l * EE;  p.d[l * 8 + 0] = qkv_t + (size_t)l * 3 * EE + 0 * EE;
            p.s[l * 8 + 1] = self_wk + l * EE;  p.d[l * 8 + 1] = qkv_t + (size_t)l * 3 * EE + 1 * EE;
            p.s[l * 8 + 2] = self_wv + l * EE;  p.d[l * 8 + 2] = qkv_t + (size_t)l * 3 * EE + 2 * EE;
            p.s[l * 8 + 3] = self_wo + l * EE;  p.d[l * 8 + 3] = swo_t + (size_t)l * EE;
            p.s[l * 8 + 4] = cross_wq + l * EE; p.d[l * 8 + 4] = cq_t + (size_t)l * EE;
            p.s[l * 8 + 5] = cross_wk + l * EE; p.d[l * 8 + 5] = ckv_t + (size_t)l * 2 * EE + 0 * EE;
            p.s[l * 8 + 6] = cross_wv + l * EE; p.d[l * 8 + 6] = ckv_t + (size_t)l * 2 * EE + 1 * EE;
            p.s[l * 8 + 7] = cross_wo + l * EE; p.d[l * 8 + 7] = cwo_t + (size_t)l * EE;
        }
        dim3 gf(E_ / 32, E_ / 32, 16);
        tconv16_kernel<<<gf, 256, 0, stream>>>(p);
        dim3 g1(E_ / 32, M_ / 32, L_);
        tconv_kernel<<<g1, 256, 0, stream>>>(mlp_w1, w1_t, E_, M_, (size_t)E_ * M_, (size_t)E_ * M_);
        dim3 g2(M_ / 32, E_ / 32, L_);
        tconv_kernel<<<g2, 256, 0, stream>>>(mlp_w2, w2_t, M_, E_, (size_t)M_ * E_, (size_t)M_ * E_);
        dim3 g3(E_ / 32, V_ / 32, 1);
        tconv_kernel<<<g3, 256, 0, stream>>>(logit_w, wl_t, E_, V_, 0, 0);
    }

    dim3 gqkv(3 * E_ / 128, R / 128);
    dim3 gkv(2 * E_ / 128, R / 128);
    dim3 gp(E_ / 128, R / 128);
    dim3 g1(M_ / 128, R / 128);
    dim3 gl(V_ / 128, R / 128);
    const int attn_grid = B_ * H_ * 16;   // (b, h, qb)

    for (int l = 0; l < L_; ++l) {
        // ---- self attention ----
        ln_kernel<<<R, 256, 0, stream>>>(y, lnb, ln1_s + l * E_, ln1_b + l * E_);
        gemm_mfma<1><<<gqkv, 256, 0, stream>>>(lnb, qkv_t + (size_t)l * 3 * EE, nullptr, nullptr, qkvb, R, 3 * E_, E_, 1.0f, 0);
        vmean_kernel<<<B_ * H_, 512, 0, stream>>>(qkvb + 2 * E_, 3 * E_, vmean);
        attn_mfma<<<attn_grid, 128, 0, stream>>>(qkvb, qkvb + E_, qkvb + 2 * E_, ob, masks + l * 256,
                                                 targets, nullptr, vmean, 3 * E_, 3 * E_, 3 * E_, 1);
        gemm_mfma<0><<<gp, 256, 0, stream>>>(ob, swo_t + (size_t)l * EE, nullptr, y, xb, R, E_, E_, 1.0f, 0);
        // ---- cross attention ----
        ln_kernel<<<R, 256, 0, stream>>>(xb, lnb, ln2_s + l * E_, ln2_b + l * E_);
        gemm_mfma<1><<<gp, 256, 0, stream>>>(lnb, cq_t + (size_t)l * EE, nullptr, nullptr, qb2, R, E_, E_, 1.0f, 0);
        gemm_mfma<1><<<gkv, 256, 0, stream>>>(encb, ckv_t + (size_t)l * 2 * EE, nullptr, nullptr, kvb, R, 2 * E_, E_, 1.0f, 0);
        vmean_kernel<<<B_ * H_, 512, 0, stream>>>(kvb + E_, 2 * E_, vmean);
        attn_mfma<<<attn_grid, 128, 0, stream>>>(qb2, kvb, kvb + E_, ob, masks + (2 + l) * 256,
                                                 targets, srcmask, vmean, E_, 2 * E_, 2 * E_, 0);
        gemm_mfma<0><<<gp, 256, 0, stream>>>(ob, cwo_t + (size_t)l * EE, nullptr, xb, zb, R, E_, E_, 1.0f, 0);
        // ---- MLP ----
        ln_kernel<<<R, 256, 0, stream>>>(zb, lnb, ln3_s + l * E_, ln3_b + l * E_);
        gemm_mfma<1><<<g1, 256, 0, stream>>>(lnb, w1_t + (size_t)l * E_ * M_, mlp_b1 + (size_t)l * M_, nullptr, hid, R, M_, E_, 1.0f, 1);
        gemm_mfma<0><<<gp, 256, 0, stream>>>(hid, w2_t + (size_t)l * M_ * E_, mlp_b2 + (size_t)l * E_, zb, y, R, E_, M_, 1.0f, 0);
    }

    ln_kernel<<<R, 256, 0, stream>>>(y, lnb, final_s, final_b);
    gemm_mfma<0><<<gl, 256, 0, stream>>>(lnb, wl_t, logit_b, nullptr, out, R, V_, E_, 1.0f, 0);
}

// Round 9
// 939.833 us; speedup vs baseline: 4.8167x; 1.0891x over previous
//
#include <hip/hip_runtime.h>
#include <hip/hip_bf16.h>
#include <stdint.h>

#define B_ 2
#define S_ 1024
#define E_ 512
#define H_ 8
#define D_ 64
#define M_ 2048
#define V_ 32000
#define L_ 2

typedef __hip_bfloat16 bf16;
typedef __attribute__((ext_vector_type(8))) short short8;
typedef __attribute__((ext_vector_type(4))) float f32x4;
typedef __attribute__((ext_vector_type(16))) float f32x16;
typedef __attribute__((ext_vector_type(4))) unsigned int uint4v;

__device__ inline unsigned int pack2bf(float lo, float hi) {
    __hip_bfloat16 a = __float2bfloat16(lo), b = __float2bfloat16(hi);
    unsigned short ua = *(unsigned short*)&a, ub = *(unsigned short*)&b;
    return (unsigned int)ua | ((unsigned int)ub << 16);
}

// ---------------- numpy legacy RandomState (MT19937), LDS-resident ----------------
#define MT_N 624
#define MT_M 397
#define MT_UP   0x80000000u
#define MT_LOW  0x7fffffffu
#define MT_MAT  0x9908b0dfu

__device__ inline unsigned int mt_temper(unsigned int y) {
    y ^= y >> 11;
    y ^= (y << 7) & 0x9d2c5680u;
    y ^= (y << 15) & 0xefc60000u;
    y ^= y >> 18;
    return y;
}

__global__ __launch_bounds__(256)
void build_masks_kernel(unsigned char* masks) {
    __shared__ unsigned int mto[4][MT_N];
    __shared__ unsigned int mtn[4][MT_N];
    const int w = threadIdx.x >> 6, lane = threadIdx.x & 63;
    const unsigned int seeds[4] = {1000u, 1001u, 0u, 1u};
    unsigned char* m = masks + w * 256;

    for (int idx = lane; idx < 256; idx += 64) {
        int i = idx >> 4, j = idx & 15;
        bool v = (j >= i - 1 && j <= i + 1) || i == 0 || i == 15 || j == 0 || j == 15;
        m[idx] = v ? 1 : 0;
    }

    if (lane == 0) {
        unsigned int s = seeds[w];
        for (int i = 0; i < MT_N; ++i) {
            mto[w][i] = s;
            s = 1812433253u * (s ^ (s >> 30)) + (unsigned int)(i + 1);
        }
    }
    __syncthreads();

    for (int i = lane; i < MT_N - MT_M; i += 64) {             // A: 227 elems
        unsigned int y = (mto[w][i] & MT_UP) | (mto[w][i + 1] & MT_LOW);
        mtn[w][i] = mto[w][i + MT_M] ^ (y >> 1) ^ ((y & 1u) ? MT_MAT : 0u);
    }
    __syncthreads();
    for (int i = 227 + lane; i < 454; i += 64) {               // B1
        unsigned int y = (mto[w][i] & MT_UP) | (mto[w][i + 1] & MT_LOW);
        mtn[w][i] = mtn[w][i - 227] ^ (y >> 1) ^ ((y & 1u) ? MT_MAT : 0u);
    }
    __syncthreads();
    for (int i = 454 + lane; i < MT_N - 1; i += 64) {          // B2
        unsigned int y = (mto[w][i] & MT_UP) | (mto[w][i + 1] & MT_LOW);
        mtn[w][i] = mtn[w][i - 227] ^ (y >> 1) ^ ((y & 1u) ? MT_MAT : 0u);
    }
    __syncthreads();
    if (lane == 0) {                                           // C: i = 623
        unsigned int y = (mto[w][MT_N - 1] & MT_UP) | (mtn[w][0] & MT_LOW);
        mtn[w][MT_N - 1] = mtn[w][MT_M - 1] ^ (y >> 1) ^ ((y & 1u) ? MT_MAT : 0u);
    }
    __syncthreads();

    if (lane == 0) {
        int idx = 0;
        for (int i = 0; i < 16; ++i) {
            unsigned long long arr = 0xFEDCBA9876543210ULL;
            for (int k = 15; k > 0; --k) {
                unsigned int mask = k;
                mask |= mask >> 1; mask |= mask >> 2; mask |= mask >> 4;
                unsigned int j;
                for (;;) {
                    if (idx >= MT_N) {
                        int i2 = 0;
                        for (; i2 < MT_N - MT_M; ++i2) {
                            unsigned int y2 = (mtn[w][i2] & MT_UP) | (mtn[w][i2 + 1] & MT_LOW);
                            mtn[w][i2] = mtn[w][i2 + MT_M] ^ (y2 >> 1) ^ ((y2 & 1u) ? MT_MAT : 0u);
                        }
                        for (; i2 < MT_N - 1; ++i2) {
                            unsigned int y2 = (mtn[w][i2] & MT_UP) | (mtn[w][i2 + 1] & MT_LOW);
                            mtn[w][i2] = mtn[w][i2 - 227] ^ (y2 >> 1) ^ ((y2 & 1u) ? MT_MAT : 0u);
                        }
                        unsigned int y2 = (mtn[w][MT_N - 1] & MT_UP) | (mtn[w][0] & MT_LOW);
                        mtn[w][MT_N - 1] = mtn[w][MT_M - 1] ^ (y2 >> 1) ^ ((y2 & 1u) ? MT_MAT : 0u);
                        idx = 0;
                    }
                    j = mt_temper(mtn[w][idx++]) & mask;
                    if (j <= (unsigned int)k) break;
                }
                unsigned int a = (unsigned int)(arr >> (4 * k)) & 15u;
                unsigned int bnib = (unsigned int)(arr >> (4 * j)) & 15u;
                arr &= ~((15ULL << (4 * k)) | (15ULL << (4 * j)));
                arr |= ((unsigned long long)a << (4 * j)) | ((unsigned long long)bnib << (4 * k));
            }
            m[i * 16 + ((arr >> 0) & 15)] = 1;
            m[i * 16 + ((arr >> 4) & 15)] = 1;
            m[i * 16 + ((arr >> 8) & 15)] = 1;
        }
    }
}

// ---------------- embedding ----------------
__global__ void embed_kernel(const int* __restrict__ targets,
                             const float* __restrict__ table,
                             const float* __restrict__ pos,
                             float* __restrict__ y) {
    int row = blockIdx.x;
    int s = row & (S_ - 1);
    int b = row >> 10;
    int id = (s == 0) ? 0 : targets[b * S_ + s - 1];
    int c = threadIdx.x * 4;
    float4 e = *(const float4*)&table[(size_t)id * E_ + c];
    float4 p = *(const float4*)&pos[(size_t)s * E_ + c];
    e.x += p.x; e.y += p.y; e.z += p.z; e.w += p.w;
    *(float4*)&y[(size_t)row * E_ + c] = e;
}

// ---------------- layernorm f32 -> bf16 ----------------
__global__ __launch_bounds__(256)
void ln_kernel(const float* __restrict__ x, bf16* __restrict__ y,
               const float* __restrict__ sc, const float* __restrict__ bi) {
    int row = blockIdx.x;
    int t = threadIdx.x;
    const float* xr = x + (size_t)row * E_;
    float2 v = *(const float2*)&xr[t * 2];
    float sum = v.x + v.y;
    float sq = v.x * v.x + v.y * v.y;
    for (int off = 32; off > 0; off >>= 1) {
        sum += __shfl_xor(sum, off);
        sq  += __shfl_xor(sq, off);
    }
    __shared__ float s0[4], s1[4];
    int w = t >> 6;
    if ((t & 63) == 0) { s0[w] = sum; s1[w] = sq; }
    __syncthreads();
    sum = s0[0] + s0[1] + s0[2] + s0[3];
    sq  = s1[0] + s1[1] + s1[2] + s1[3];
    float mu = sum * (1.0f / (float)E_);
    float var = sq * (1.0f / (float)E_) - mu * mu;
    float rs = rsqrtf(var + 1e-6f);
    float2 s2 = *(const float2*)&sc[t * 2];
    float2 b2 = *(const float2*)&bi[t * 2];
    bf16* yr = y + (size_t)row * E_ + t * 2;
    yr[0] = __float2bfloat16((v.x - mu) * rs * s2.x + b2.x);
    yr[1] = __float2bfloat16((v.y - mu) * rs * s2.y + b2.y);
}

// ---------------- transpose+convert: W[K][N] f32 -> Wt[N][K] bf16 ----------------
__global__ __launch_bounds__(256)
void tconv_kernel(const float* __restrict__ W, bf16* __restrict__ Wt,
                  int K, int N, size_t src_stride, size_t dst_stride) {
    __shared__ float Ts[32][33];
    const float* Wb = W + blockIdx.z * src_stride;
    bf16* Wtb = Wt + blockIdx.z * dst_stride;
    int k0 = blockIdx.x * 32, n0 = blockIdx.y * 32;
    int lx = threadIdx.x & 31, ly = threadIdx.x >> 5;
    for (int r = ly; r < 32; r += 8)
        Ts[r][lx] = Wb[(size_t)(k0 + r) * N + n0 + lx];
    __syncthreads();
    for (int r = ly; r < 32; r += 8)
        Wtb[(size_t)(n0 + r) * K + k0 + lx] = __float2bfloat16(Ts[lx][r]);
}

// ---------------- fused 16x E_xE_ transpose+convert (one launch) ----------------
struct TP16 { const float* s[16]; bf16* d[16]; };
__global__ __launch_bounds__(256)
void tconv16_kernel(TP16 p) {
    __shared__ float Ts[32][33];
    const float* W = p.s[blockIdx.z];
    bf16* Wt = p.d[blockIdx.z];
    int k0 = blockIdx.x * 32, n0 = blockIdx.y * 32;
    int lx = threadIdx.x & 31, ly = threadIdx.x >> 5;
    for (int r = ly; r < 32; r += 8)
        Ts[r][lx] = W[(size_t)(k0 + r) * E_ + n0 + lx];
    __syncthreads();
    for (int r = ly; r < 32; r += 8)
        Wt[(size_t)(n0 + r) * E_ + k0 + lx] = __float2bfloat16(Ts[lx][r]);
}

// ---------------- f32 -> bf16 elementwise ----------------
__global__ void cvt_kernel(const float* __restrict__ x, bf16* __restrict__ y) {
    int i = (blockIdx.x * blockDim.x + threadIdx.x) * 4;
    float4 v = *(const float4*)&x[i];
    y[i + 0] = __float2bfloat16(v.x);
    y[i + 1] = __float2bfloat16(v.y);
    y[i + 2] = __float2bfloat16(v.z);
    y[i + 3] = __float2bfloat16(v.w);
}

// ---------------- vmean[b][h][d] = mean_s v[b][s][h][d] ----------------
__global__ __launch_bounds__(512)
void vmean_kernel(const bf16* __restrict__ v, int sv, float* __restrict__ vm) {
    int bh = blockIdx.x; int b = bh >> 3, h = bh & 7;
    int d = threadIdx.x & 63, sl = threadIdx.x >> 6;
    const unsigned short* vu = (const unsigned short*)v;
    float s = 0.0f;
    for (int si = sl; si < S_; si += 8) {
        unsigned short u = vu[(size_t)(b * S_ + si) * sv + h * D_ + d];
        s += __uint_as_float((unsigned)u << 16);
    }
    __shared__ float red[512];
    red[threadIdx.x] = s;
    __syncthreads();
    if (sl == 0) {
        float tot = 0.0f;
        for (int j = 0; j < 8; ++j) tot += red[j * 64 + d];
        vm[bh * D_ + d] = tot * (1.0f / (float)S_);
    }
}

// ---------------- bf16 MFMA GEMM (m97 structure, XCD-swizzled) ----------------
// Swapped-operand MFMA: acc = mfma(B-frag, A-frag) so that the C fragment's
// reg axis spans 4 CONSECUTIVE COLUMNS -> float4/uint2 vectorized epilogue.
template<int OBF>
__global__ __launch_bounds__(256)
void gemm_mfma(const bf16* __restrict__ A, const bf16* __restrict__ Wt,
               const float* __restrict__ bias, const float* __restrict__ resid,
               void* __restrict__ Cv, int M, int N, int K, float alpha, int relu)
{
    __shared__ bf16 As[128 * 64];
    __shared__ bf16 Bs[128 * 64];
    const int t = threadIdx.x;
    const int lane = t & 63, w = t >> 6;
    // bijective XCD swizzle (m204): M-tiles fastest so consecutive blocks on an
    // XCD share the same Wt panel (B reuse in L2).
    int m0, n0;
    {
        int nwg = gridDim.x * gridDim.y;
        int lin = blockIdx.x + gridDim.x * blockIdx.y;
        int q = nwg >> 3, r = nwg & 7;
        int xcd = lin & 7, off8 = lin >> 3;
        int swz = ((xcd < r) ? xcd * (q + 1) : r * (q + 1) + (xcd - r) * q) + off8;
        int gridM = gridDim.y;
        m0 = (swz % gridM) * 128;
        n0 = (swz / gridM) * 128;
    }
    const int wr = w >> 1, wc = w & 1;
    const int srow = w * 8 + (lane >> 3);
    const int sslot = lane & 7;
    f32x4 acc[4][4] = {};

    for (int k0 = 0; k0 < K; k0 += 64) {
        __syncthreads();
        #pragma unroll
        for (int i = 0; i < 4; ++i) {
            int r = i * 32 + srow;
            int gslot = sslot ^ (r & 7);
            const bf16* ga = A  + (size_t)(m0 + r) * K + k0 + gslot * 8;
            const bf16* gb = Wt + (size_t)(n0 + r) * K + k0 + gslot * 8;
            __builtin_amdgcn_global_load_lds((const __attribute__((address_space(1))) void*)ga,
                                             (__attribute__((address_space(3))) void*)&As[r * 64 + sslot * 8],
                                             16, 0, 0);
            __builtin_amdgcn_global_load_lds((const __attribute__((address_space(1))) void*)gb,
                                             (__attribute__((address_space(3))) void*)&Bs[r * 64 + sslot * 8],
                                             16, 0, 0);
        }
        __syncthreads();
        #pragma unroll
        for (int kk = 0; kk < 2; ++kk) {
            short8 af[4], bq[4];
            const int q = kk * 4 + (lane >> 4);
            #pragma unroll
            for (int m = 0; m < 4; ++m) {
                int r = wr * 64 + m * 16 + (lane & 15);
                af[m] = *(const short8*)&As[r * 64 + (q ^ (r & 7)) * 8];
            }
            #pragma unroll
            for (int n = 0; n < 4; ++n) {
                int r = wc * 64 + n * 16 + (lane & 15);
                bq[n] = *(const short8*)&Bs[r * 64 + (q ^ (r & 7)) * 8];
            }
            #pragma unroll
            for (int m = 0; m < 4; ++m)
                #pragma unroll
                for (int n = 0; n < 4; ++n)
                    acc[m][n] = __builtin_amdgcn_mfma_f32_16x16x32_bf16(bq[n], af[m], acc[m][n], 0, 0, 0);
        }
    }

    // epilogue: C-row = lane&15 within m-frag; C-cols = lr*4 + r (4 consecutive)
    const int lr = lane >> 4, lc = lane & 15;
    #pragma unroll
    for (int m = 0; m < 4; ++m) {
        int row = m0 + wr * 64 + m * 16 + lc;
        #pragma unroll
        for (int n = 0; n < 4; ++n) {
            int colb = n0 + wc * 64 + n * 16 + lr * 4;
            float v0 = acc[m][n][0] * alpha, v1 = acc[m][n][1] * alpha;
            float v2 = acc[m][n][2] * alpha, v3 = acc[m][n][3] * alpha;
            if (bias) {
                float4 bv = *(const float4*)&bias[colb];
                v0 += bv.x; v1 += bv.y; v2 += bv.z; v3 += bv.w;
            }
            if (relu) {
                v0 = fmaxf(v0, 0.0f); v1 = fmaxf(v1, 0.0f);
                v2 = fmaxf(v2, 0.0f); v3 = fmaxf(v3, 0.0f);
            }
            if (resid) {
                float4 rv = *(const float4*)&resid[(size_t)row * N + colb];
                v0 += rv.x; v1 += rv.y; v2 += rv.z; v3 += rv.w;
            }
            if (OBF) {
                uint2 pp = {pack2bf(v0, v1), pack2bf(v2, v3)};
                *(uint2*)((bf16*)Cv + (size_t)row * N + colb) = pp;
            } else {
                float4 o = {v0, v1, v2, v3};
                *(float4*)((float*)Cv + (size_t)row * N + colb) = o;
            }
        }
    }
}

// ---------------- MFMA flash attention ----------------
// Block: (b, h, qb). 2 waves = 2 q-halves (wq). One q-block per workgroup.
// 32x32x16 MFMA; swapped QK^T; PV as O^T = V^T P^T; V slot includes ks half.
// P fed to PV as two-term bf16 split (hi + residual) -> ~f32 precision.
// Block-sparse skip exact. m<=-5e8 -> vmean fallback (fully-masked row).
__global__ __launch_bounds__(128)
void attn_mfma(const bf16* __restrict__ qp, const bf16* __restrict__ kp,
               const bf16* __restrict__ vp, bf16* __restrict__ op,
               const unsigned char* __restrict__ bm,
               const int* __restrict__ targets, const float* __restrict__ srcmask,
               const float* __restrict__ vmean,
               int sq, int sk, int sv, int causal)
{
    __shared__ __align__(16) unsigned char lds[24592];
    unsigned long long* padb = (unsigned long long*)(lds + 24576);

    const int bid = blockIdx.x;
    const int qb = bid & 15, h = (bid >> 4) & 7, b = bid >> 7;
    const int tid = threadIdx.x;
    const int wq = tid >> 6, lane = tid & 63;
    const int h5 = lane >> 5, l31 = lane & 31;

    unsigned char* Ks = lds;
    unsigned char* Vt = lds + 8192;
    unsigned char* Qs = lds + 16384;

    #pragma unroll
    for (int j = 0; j < 4; ++j) {
        int r = wq * 32 + j * 8 + (lane >> 3);
        int g = (lane & 7) ^ (r & 7);
        const bf16* src = qp + (size_t)(b * S_ + qb * 64 + r) * sq + h * 64 + g * 8;
        __builtin_amdgcn_global_load_lds((const __attribute__((address_space(1))) void*)src,
            (__attribute__((address_space(3))) void*)(Qs + wq * 4096 + j * 1024 + lane * 16),
            16, 0, 0);
    }
    __syncthreads();
    short8 qfrag[4];
    {
        int qrow = wq * 32 + l31;
        #pragma unroll
        for (int t = 0; t < 4; ++t) {
            int c = (2 * t + h5) ^ (qrow & 7);
            qfrag[t] = *(const short8*)(Qs + qrow * 128 + c * 16);
        }
    }

    const int q_in = wq * 32 + l31;
    const int qg = qb * 64 + q_in;
    const bool padq = targets[b * S_ + qg] > 0;

    unsigned long long lstpk = 0ULL;
    int myn = 0;
    {
        int kbmax = causal ? qb : 15;
        for (int kb = 0; kb <= kbmax; ++kb)
            if (bm[qb * 16 + kb]) { lstpk |= ((unsigned long long)kb) << (4 * myn); ++myn; }
    }

    float mrun = -3.0e38f, lrun = 0.0f;
    f32x16 acc0 = {}, acc1 = {};

    for (int it = 0; it < myn; ++it) {
        int kb = (int)((lstpk >> (4 * it)) & 15ULL);
        #pragma unroll
        for (int j = 0; j < 4; ++j) {
            int r = j * 16 + wq * 8 + (lane >> 3);
            int g = (lane & 7) ^ (r & 7);
            const bf16* src = kp + (size_t)(b * S_ + kb * 64 + r) * sk + h * 64 + g * 8;
            __builtin_amdgcn_global_load_lds((const __attribute__((address_space(1))) void*)src,
                (__attribute__((address_space(3))) void*)(Ks + (j * 16 + wq * 8) * 128 + lane * 16),
                16, 0, 0);
        }
        #pragma unroll
        for (int itv = 0; itv < 2; ++itv) {
            int k2 = 2 * l31;
            int d0 = h5 * 8 + (wq * 2 + itv) * 16;
            const unsigned short* v0 = (const unsigned short*)vp +
                (size_t)(b * S_ + kb * 64 + k2) * sv + h * 64 + d0;
            short8 va = *(const short8*)v0;
            short8 vb = *(const short8*)(v0 + sv);
            #pragma unroll
            for (int j2 = 0; j2 < 8; ++j2) {
                int d = d0 + j2;
                unsigned int pkv = ((unsigned int)(unsigned short)va[j2]) |
                                   (((unsigned int)(unsigned short)vb[j2]) << 16);
                int off = d * 128 + (((k2 >> 3) ^ (d & 7)) * 16) + (k2 & 7) * 2;
                *(unsigned int*)(Vt + off) = pkv;
            }
        }
        if (wq == 0) {
            int pos = b * S_ + kb * 64 + lane;
            bool pk_ = srcmask ? (srcmask[pos] > 0.0f) : (targets[pos] > 0);
            unsigned long long bits = __ballot(pk_);
            if (lane == 0) padb[0] = bits;
        }
        __syncthreads();
        {
            bool diag = causal && (kb == qb);
            unsigned long long pb = padb[0];
            #pragma unroll
            for (int ks = 0; ks < 2; ++ks) {
                f32x16 sacc = {};
                #pragma unroll
                for (int t = 0; t < 4; ++t) {
                    int row = ks * 32 + l31;
                    int c = (2 * t + h5) ^ (row & 7);
                    short8 kfrag = *(const short8*)(Ks + row * 128 + c * 16);
                    sacc = __builtin_amdgcn_mfma_f32_32x32x16_bf16(kfrag, qfrag[t], sacc, 0, 0, 0);
                }
                float p[16];
                float mloc = -3.0e38f;
                #pragma unroll
                for (int r = 0; r < 16; ++r) {
                    int kl = ks * 32 + (r & 3) + 8 * (r >> 2) + 4 * h5;
                    bool ok = padq && (((pb >> kl) & 1ULL) != 0) && (!diag || kl <= q_in);
                    p[r] = ok ? sacc[r] * 0.125f : -1.0e9f;
                    mloc = fmaxf(mloc, p[r]);
                }
                mloc = fmaxf(mloc, __shfl_xor(mloc, 32));
                float mnew = fmaxf(mrun, mloc);
                float rescale = __expf(mrun - mnew);
                float lsum = 0.0f;
                #pragma unroll
                for (int r = 0; r < 16; ++r) { p[r] = __expf(p[r] - mnew); lsum += p[r]; }
                lsum += __shfl_xor(lsum, 32);
                lrun = lrun * rescale + lsum;
                mrun = mnew;
                acc0 *= rescale;
                acc1 *= rescale;
                unsigned int pk_hi[4][2], pk_lo[4][2];
                #pragma unroll
                for (int t4 = 0; t4 < 4; ++t4)
                    #pragma unroll
                    for (int u = 0; u < 2; ++u) {
                        float a = p[4 * t4 + 2 * u];
                        float c = p[4 * t4 + 2 * u + 1];
                        unsigned int ph = pack2bf(a, c);
                        float ah = __uint_as_float(ph << 16);
                        float ch = __uint_as_float(ph & 0xffff0000u);
                        pk_hi[t4][u] = ph;
                        pk_lo[t4][u] = pack2bf(a - ah, c - ch);
                    }
                #pragma unroll
                for (int Hh = 0; Hh < 2; ++Hh) {
                    unsigned int hu0 = (unsigned int)__shfl_xor((int)pk_hi[2 * Hh + 1][0], 32);
                    unsigned int hu1 = (unsigned int)__shfl_xor((int)pk_hi[2 * Hh + 1][1], 32);
                    unsigned int hl0 = (unsigned int)__shfl_xor((int)pk_hi[2 * Hh][0], 32);
                    unsigned int hl1 = (unsigned int)__shfl_xor((int)pk_hi[2 * Hh][1], 32);
                    uint4v hv = {h5 ? hu0 : pk_hi[2 * Hh][0],
                                 h5 ? hu1 : pk_hi[2 * Hh][1],
                                 h5 ? pk_hi[2 * Hh + 1][0] : hl0,
                                 h5 ? pk_hi[2 * Hh + 1][1] : hl1};
                    short8 bfrag_hi = __builtin_bit_cast(short8, hv);
                    unsigned int lu0 = (unsigned int)__shfl_xor((int)pk_lo[2 * Hh + 1][0], 32);
                    unsigned int lu1 = (unsigned int)__shfl_xor((int)pk_lo[2 * Hh + 1][1], 32);
                    unsigned int ll0 = (unsigned int)__shfl_xor((int)pk_lo[2 * Hh][0], 32);
                    unsigned int ll1 = (unsigned int)__shfl_xor((int)pk_lo[2 * Hh][1], 32);
                    uint4v lv = {h5 ? lu0 : pk_lo[2 * Hh][0],
                                 h5 ? lu1 : pk_lo[2 * Hh][1],
                                 h5 ? pk_lo[2 * Hh + 1][0] : ll0,
                                 h5 ? pk_lo[2 * Hh + 1][1] : ll1};
                    short8 bfrag_lo = __builtin_bit_cast(short8, lv);
                    #pragma unroll
                    for (int f = 0; f < 2; ++f) {
                        int row = f * 32 + l31;
                        int c = (4 * ks + 2 * Hh + h5) ^ (row & 7);   // ks-half of V
                        short8 vfrag = *(const short8*)(Vt + row * 128 + c * 16);
                        if (f == 0) {
                            acc0 = __builtin_amdgcn_mfma_f32_32x32x16_bf16(vfrag, bfrag_hi, acc0, 0, 0, 0);
                            acc0 = __builtin_amdgcn_mfma_f32_32x32x16_bf16(vfrag, bfrag_lo, acc0, 0, 0, 0);
                        } else {
                            acc1 = __builtin_amdgcn_mfma_f32_32x32x16_bf16(vfrag, bfrag_hi, acc1, 0, 0, 0);
                            acc1 = __builtin_amdgcn_mfma_f32_32x32x16_bf16(vfrag, bfrag_lo, acc1, 0, 0, 0);
                        }
                    }
                }
            }
        }
        __syncthreads();
    }

    bool okrow = mrun > -5.0e8f;
    float inv = okrow ? 1.0f / lrun : 0.0f;
    const float* vmp = vmean + (b * 8 + h) * 64;
    unsigned short* orow = (unsigned short*)op + (size_t)(b * S_ + qg) * E_ + h * 64;
    #pragma unroll
    for (int f = 0; f < 2; ++f)
        #pragma unroll
        for (int t4 = 0; t4 < 4; ++t4)
            #pragma unroll
            for (int u = 0; u < 2; ++u) {
                int r = 4 * t4 + 2 * u;
                int d = f * 32 + 2 * u + 8 * t4 + 4 * h5;
                float a0 = f ? acc1[r] : acc0[r];
                float a1 = f ? acc1[r + 1] : acc0[r + 1];
                float v0 = a0 * inv;
                float v1 = a1 * inv;
                if (!okrow) { v0 = vmp[d]; v1 = vmp[d + 1]; }
                *(unsigned int*)(orow + d) = pack2bf(v0, v1);
            }
}

extern "C" void kernel_launch(void* const* d_in, const int* in_sizes, int n_in,
                              void* d_out, int out_size, void* d_ws, size_t ws_size,
                              hipStream_t stream)
{
    const float* encoded  = (const float*)d_in[0];
    const float* srcmask  = (const float*)d_in[1];
    const int*   targets  = (const int*)d_in[2];
    const float* table    = (const float*)d_in[3];
    const float* pos      = (const float*)d_in[4];
    const float* ln1_s = (const float*)d_in[5];
    const float* ln1_b = (const float*)d_in[6];
    const float* ln2_s = (const float*)d_in[7];
    const float* ln2_b = (const float*)d_in[8];
    const float* ln3_s = (const float*)d_in[9];
    const float* ln3_b = (const float*)d_in[10];
    const float* self_wq = (const float*)d_in[11];
    const float* self_wk = (const float*)d_in[12];
    const float* self_wv = (const float*)d_in[13];
    const float* self_wo = (const float*)d_in[14];
    const float* cross_wq = (const float*)d_in[15];
    const float* cross_wk = (const float*)d_in[16];
    const float* cross_wv = (const float*)d_in[17];
    const float* cross_wo = (const float*)d_in[18];
    const float* mlp_w1 = (const float*)d_in[19];
    const float* mlp_b1 = (const float*)d_in[20];
    const float* mlp_w2 = (const float*)d_in[21];
    const float* mlp_b2 = (const float*)d_in[22];
    const float* final_s = (const float*)d_in[23];
    const float* final_b = (const float*)d_in[24];
    const float* logit_w = (const float*)d_in[25];
    const float* logit_b = (const float*)d_in[26];
    float* out = (float*)d_out;

    char* ws = (char*)d_ws;
    unsigned char* masks = (unsigned char*)ws;
    size_t off = 1024;
    auto alloc = [&](size_t bytes) {
        char* p = ws + off;
        off += (bytes + 255) & ~(size_t)255;
        return p;
    };
    const size_t RS = (size_t)B_ * S_;   // 2048
    const size_t EE = (size_t)E_ * E_;
    float* y    = (float*)alloc(RS * E_ * 4);
    float* xb   = (float*)alloc(RS * E_ * 4);
    float* zb   = (float*)alloc(RS * E_ * 4);
    bf16* lnb   = (bf16*)alloc(RS * E_ * 2);
    bf16* qkvb  = (bf16*)alloc(RS * 3 * E_ * 2);
    bf16* kvb   = (bf16*)alloc(RS * 4 * E_ * 2);   // [k0|v0|k1|v1] per row
    bf16* qb2   = (bf16*)alloc(RS * E_ * 2);
    bf16* ob    = (bf16*)alloc(RS * E_ * 2);
    bf16* hid   = (bf16*)alloc(RS * M_ * 2);
    bf16* encb  = (bf16*)alloc(RS * E_ * 2);
    float* vmeans = (float*)alloc(B_ * H_ * D_ * 4);           // self (per layer, reused)
    float* vmeanc = (float*)alloc(2 * B_ * H_ * D_ * 4);       // cross, both layers
    bf16* qkv_t = (bf16*)alloc((size_t)L_ * 3 * EE * 2);
    bf16* swo_t = (bf16*)alloc((size_t)L_ * EE * 2);
    bf16* cq_t  = (bf16*)alloc((size_t)L_ * EE * 2);
    bf16* ckv_t = (bf16*)alloc((size_t)L_ * 2 * EE * 2);
    bf16* cwo_t = (bf16*)alloc((size_t)L_ * EE * 2);
    bf16* w1_t  = (bf16*)alloc((size_t)L_ * E_ * M_ * 2);
    bf16* w2_t  = (bf16*)alloc((size_t)L_ * M_ * E_ * 2);
    bf16* wl_t  = (bf16*)alloc((size_t)E_ * V_ * 2);

    const int R = (int)RS;

    build_masks_kernel<<<1, 256, 0, stream>>>(masks);
    embed_kernel<<<R, 128, 0, stream>>>(targets, table, pos, y);
    cvt_kernel<<<(R * E_) / 1024, 256, 0, stream>>>(encoded, encb);

    {
        TP16 p;
        for (int l = 0; l < L_; ++l) {
            p.s[l * 8 + 0] = self_wq + l * EE;  p.d[l * 8 + 0] = qkv_t + (size_t)l * 3 * EE + 0 * EE;
            p.s[l * 8 + 1] = self_wk + l * EE;  p.d[l * 8 + 1] = qkv_t + (size_t)l * 3 * EE + 1 * EE;
            p.s[l * 8 + 2] = self_wv + l * EE;  p.d[l * 8 + 2] = qkv_t + (size_t)l * 3 * EE + 2 * EE;
            p.s[l * 8 + 3] = self_wo + l * EE;  p.d[l * 8 + 3] = swo_t + (size_t)l * EE;
            p.s[l * 8 + 4] = cross_wq + l * EE; p.d[l * 8 + 4] = cq_t + (size_t)l * EE;
            p.s[l * 8 + 5] = cross_wk + l * EE; p.d[l * 8 + 5] = ckv_t + (size_t)l * 2 * EE + 0 * EE;
            p.s[l * 8 + 6] = cross_wv + l * EE; p.d[l * 8 + 6] = ckv_t + (size_t)l * 2 * EE + 1 * EE;
            p.s[l * 8 + 7] = cross_wo + l * EE; p.d[l * 8 + 7] = cwo_t + (size_t)l * EE;
        }
        dim3 gf(E_ / 32, E_ / 32, 16);
        tconv16_kernel<<<gf, 256, 0, stream>>>(p);
        dim3 g1(E_ / 32, M_ / 32, L_);
        tconv_kernel<<<g1, 256, 0, stream>>>(mlp_w1, w1_t, E_, M_, (size_t)E_ * M_, (size_t)E_ * M_);
        dim3 g2(M_ / 32, E_ / 32, L_);
        tconv_kernel<<<g2, 256, 0, stream>>>(mlp_w2, w2_t, M_, E_, (size_t)M_ * E_, (size_t)M_ * E_);
        dim3 g3(E_ / 32, V_ / 32, 1);
        tconv_kernel<<<g3, 256, 0, stream>>>(logit_w, wl_t, E_, V_, 0, 0);
    }

    dim3 gqkv(3 * E_ / 128, R / 128);
    dim3 gkv4(4 * E_ / 128, R / 128);   // both layers' cross K/V at once
    dim3 gp(E_ / 128, R / 128);
    dim3 g1(M_ / 128, R / 128);
    dim3 gl(V_ / 128, R / 128);
    const int attn_grid = B_ * H_ * 16;

    // cross K/V for BOTH layers upfront (depends only on encoder output)
    gemm_mfma<1><<<gkv4, 256, 0, stream>>>(encb, ckv_t, nullptr, nullptr, kvb, R, 4 * E_, E_, 1.0f, 0);
    vmean_kernel<<<B_ * H_, 512, 0, stream>>>(kvb + E_, 4 * E_, vmeanc);
    vmean_kernel<<<B_ * H_, 512, 0, stream>>>(kvb + 3 * E_, 4 * E_, vmeanc + B_ * H_ * D_);

    for (int l = 0; l < L_; ++l) {
        // ---- self attention ----
        ln_kernel<<<R, 256, 0, stream>>>(y, lnb, ln1_s + l * E_, ln1_b + l * E_);
        gemm_mfma<1><<<gqkv, 256, 0, stream>>>(lnb, qkv_t + (size_t)l * 3 * EE, nullptr, nullptr, qkvb, R, 3 * E_, E_, 1.0f, 0);
        vmean_kernel<<<B_ * H_, 512, 0, stream>>>(qkvb + 2 * E_, 3 * E_, vmeans);
        attn_mfma<<<attn_grid, 128, 0, stream>>>(qkvb, qkvb + E_, qkvb + 2 * E_, ob, masks + l * 256,
                                                 targets, nullptr, vmeans, 3 * E_, 3 * E_, 3 * E_, 1);
        gemm_mfma<0><<<gp, 256, 0, stream>>>(ob, swo_t + (size_t)l * EE, nullptr, y, xb, R, E_, E_, 1.0f, 0);
        // ---- cross attention ----
        ln_kernel<<<R, 256, 0, stream>>>(xb, lnb, ln2_s + l * E_, ln2_b + l * E_);
        gemm_mfma<1><<<gp, 256, 0, stream>>>(lnb, cq_t + (size_t)l * EE, nullptr, nullptr, qb2, R, E_, E_, 1.0f, 0);
        attn_mfma<<<attn_grid, 128, 0, stream>>>(qb2, kvb + (size_t)l * 2 * E_, kvb + (size_t)l * 2 * E_ + E_, ob,
                                                 masks + (2 + l) * 256, targets, srcmask,
                                                 vmeanc + l * B_ * H_ * D_, E_, 4 * E_, 4 * E_, 0);
        gemm_mfma<0><<<gp, 256, 0, stream>>>(ob, cwo_t + (size_t)l * EE, nullptr, xb, zb, R, E_, E_, 1.0f, 0);
        // ---- MLP ----
        ln_kernel<<<R, 256, 0, stream>>>(zb, lnb, ln3_s + l * E_, ln3_b + l * E_);
        gemm_mfma<1><<<g1, 256, 0, stream>>>(lnb, w1_t + (size_t)l * E_ * M_, mlp_b1 + (size_t)l * M_, nullptr, hid, R, M_, E_, 1.0f, 1);
        gemm_mfma<0><<<gp, 256, 0, stream>>>(hid, w2_t + (size_t)l * M_ * E_, mlp_b2 + (size_t)l * E_, zb, y, R, E_, M_, 1.0f, 0);
    }

    ln_kernel<<<R, 256, 0, stream>>>(y, lnb, final_s, final_b);
    gemm_mfma<0><<<gl, 256, 0, stream>>>(lnb, wl_t, logit_b, nullptr, out, R, V_, E_, 1.0f, 0);
}

// Round 10
// 731.114 us; speedup vs baseline: 6.1918x; 1.2855x over previous
//
#include <hip/hip_runtime.h>
#include <hip/hip_bf16.h>
#include <stdint.h>

#define B_ 2
#define S_ 1024
#define E_ 512
#define H_ 8
#define D_ 64
#define M_ 2048
#define V_ 32000
#define L_ 2

typedef __hip_bfloat16 bf16;
typedef __attribute__((ext_vector_type(8))) short short8;
typedef __attribute__((ext_vector_type(4))) float f32x4;
typedef __attribute__((ext_vector_type(16))) float f32x16;
typedef __attribute__((ext_vector_type(4))) unsigned int uint4v;

__device__ inline unsigned int pack2bf(float lo, float hi) {
    __hip_bfloat16 a = __float2bfloat16(lo), b = __float2bfloat16(hi);
    unsigned short ua = *(unsigned short*)&a, ub = *(unsigned short*)&b;
    return (unsigned int)ua | ((unsigned int)ub << 16);
}

// ---------------- numpy legacy RandomState (MT19937) ----------------
#define MT_N 624
#define MT_M 397
#define MT_UP   0x80000000u
#define MT_LOW  0x7fffffffu
#define MT_MAT  0x9908b0dfu

__device__ inline unsigned int mt_temper(unsigned int y) {
    y ^= y >> 11;
    y ^= (y << 7) & 0x9d2c5680u;
    y ^= (y << 15) & 0xefc60000u;
    y ^= y >> 18;
    return y;
}

// ---------------- prep: embed + f32->bf16 cvt + zero vsum ----------------
__global__ __launch_bounds__(256)
void prep_kernel(const int* __restrict__ targets, const float* __restrict__ table,
                 const float* __restrict__ pos, float* __restrict__ y,
                 const float* __restrict__ enc, bf16* __restrict__ encb,
                 float* __restrict__ vmbase) {
    int bid = blockIdx.x, t = threadIdx.x;
    if (bid < 2048) {
        int s = bid & (S_ - 1), b = bid >> 10;
        int id = (s == 0) ? 0 : targets[b * S_ + s - 1];
        int c = t * 2;
        float2 e = *(const float2*)&table[(size_t)id * E_ + c];
        float2 p = *(const float2*)&pos[(size_t)s * E_ + c];
        float2 o = {e.x + p.x, e.y + p.y};
        *(float2*)&y[(size_t)bid * E_ + c] = o;
    } else if (bid < 3072) {
        int i = ((bid - 2048) * 256 + t) * 4;
        float4 v = *(const float4*)&enc[i];
        encb[i + 0] = __float2bfloat16(v.x);
        encb[i + 1] = __float2bfloat16(v.y);
        encb[i + 2] = __float2bfloat16(v.z);
        encb[i + 3] = __float2bfloat16(v.w);
    } else {
        vmbase[(bid - 3072) * 256 + t] = 0.0f;   // 4096 f32 = vms(2048) + vmc(2048)
    }
}

// ---------------- fused: 16x E_xE_ transpose+convert + BigBird masks ----------------
struct TP16 { const float* s[16]; bf16* d[16]; };
__global__ __launch_bounds__(256)
void tconv16m_kernel(TP16 p, unsigned char* masks) {
    __shared__ float Ts[32][33];
    __shared__ unsigned int mto[4][MT_N];
    __shared__ unsigned int mtn[4][MT_N];
    const int z = blockIdx.z;
    if (z == 16) {
        // -------- BigBird block-mask build (one block; 4 waves = 4 masks) --------
        if (blockIdx.x != 0 || blockIdx.y != 0) return;
        const int w = threadIdx.x >> 6, lane = threadIdx.x & 63;
        const unsigned int seeds[4] = {1000u, 1001u, 0u, 1u};
        unsigned char* m = masks + w * 256;
        for (int idx = lane; idx < 256; idx += 64) {
            int i = idx >> 4, j = idx & 15;
            bool v = (j >= i - 1 && j <= i + 1) || i == 0 || i == 15 || j == 0 || j == 15;
            m[idx] = v ? 1 : 0;
        }
        if (lane == 0) {
            unsigned int s = seeds[w];
            for (int i = 0; i < MT_N; ++i) {
                mto[w][i] = s;
                s = 1812433253u * (s ^ (s >> 30)) + (unsigned int)(i + 1);
            }
        }
        __syncthreads();
        for (int i = lane; i < MT_N - MT_M; i += 64) {
            unsigned int y = (mto[w][i] & MT_UP) | (mto[w][i + 1] & MT_LOW);
            mtn[w][i] = mto[w][i + MT_M] ^ (y >> 1) ^ ((y & 1u) ? MT_MAT : 0u);
        }
        __syncthreads();
        for (int i = 227 + lane; i < 454; i += 64) {
            unsigned int y = (mto[w][i] & MT_UP) | (mto[w][i + 1] & MT_LOW);
            mtn[w][i] = mtn[w][i - 227] ^ (y >> 1) ^ ((y & 1u) ? MT_MAT : 0u);
        }
        __syncthreads();
        for (int i = 454 + lane; i < MT_N - 1; i += 64) {
            unsigned int y = (mto[w][i] & MT_UP) | (mto[w][i + 1] & MT_LOW);
            mtn[w][i] = mtn[w][i - 227] ^ (y >> 1) ^ ((y & 1u) ? MT_MAT : 0u);
        }
        __syncthreads();
        if (lane == 0) {
            unsigned int y = (mto[w][MT_N - 1] & MT_UP) | (mtn[w][0] & MT_LOW);
            mtn[w][MT_N - 1] = mtn[w][MT_M - 1] ^ (y >> 1) ^ ((y & 1u) ? MT_MAT : 0u);
        }
        __syncthreads();
        if (lane == 0) {
            int idx = 0;
            for (int i = 0; i < 16; ++i) {
                unsigned long long arr = 0xFEDCBA9876543210ULL;
                for (int k = 15; k > 0; --k) {
                    unsigned int mask = k;
                    mask |= mask >> 1; mask |= mask >> 2; mask |= mask >> 4;
                    unsigned int j;
                    for (;;) {
                        if (idx >= MT_N) {
                            int i2 = 0;
                            for (; i2 < MT_N - MT_M; ++i2) {
                                unsigned int y2 = (mtn[w][i2] & MT_UP) | (mtn[w][i2 + 1] & MT_LOW);
                                mtn[w][i2] = mtn[w][i2 + MT_M] ^ (y2 >> 1) ^ ((y2 & 1u) ? MT_MAT : 0u);
                            }
                            for (; i2 < MT_N - 1; ++i2) {
                                unsigned int y2 = (mtn[w][i2] & MT_UP) | (mtn[w][i2 + 1] & MT_LOW);
                                mtn[w][i2] = mtn[w][i2 - 227] ^ (y2 >> 1) ^ ((y2 & 1u) ? MT_MAT : 0u);
                            }
                            unsigned int y2 = (mtn[w][MT_N - 1] & MT_UP) | (mtn[w][0] & MT_LOW);
                            mtn[w][MT_N - 1] = mtn[w][MT_M - 1] ^ (y2 >> 1) ^ ((y2 & 1u) ? MT_MAT : 0u);
                            idx = 0;
                        }
                        j = mt_temper(mtn[w][idx++]) & mask;
                        if (j <= (unsigned int)k) break;
                    }
                    unsigned int a = (unsigned int)(arr >> (4 * k)) & 15u;
                    unsigned int bnib = (unsigned int)(arr >> (4 * j)) & 15u;
                    arr &= ~((15ULL << (4 * k)) | (15ULL << (4 * j)));
                    arr |= ((unsigned long long)a << (4 * j)) | ((unsigned long long)bnib << (4 * k));
                }
                m[i * 16 + ((arr >> 0) & 15)] = 1;
                m[i * 16 + ((arr >> 4) & 15)] = 1;
                m[i * 16 + ((arr >> 8) & 15)] = 1;
            }
        }
        return;
    }
    // -------- E x E transpose+convert --------
    const float* W = p.s[z];
    bf16* Wt = p.d[z];
    int k0 = blockIdx.x * 32, n0 = blockIdx.y * 32;
    int lx = threadIdx.x & 31, ly = threadIdx.x >> 5;
    for (int r = ly; r < 32; r += 8)
        Ts[r][lx] = W[(size_t)(k0 + r) * E_ + n0 + lx];
    __syncthreads();
    for (int r = ly; r < 32; r += 8)
        Wt[(size_t)(n0 + r) * E_ + k0 + lx] = __float2bfloat16(Ts[lx][r]);
}

// ---------------- mlp w1 + w2 transpose+convert (one launch) ----------------
__global__ __launch_bounds__(256)
void tconv_mlp_kernel(const float* __restrict__ w1, const float* __restrict__ w2,
                      bf16* __restrict__ w1t, bf16* __restrict__ w2t) {
    __shared__ float Ts[32][33];
    int z = blockIdx.z;
    const float* W; bf16* Wt; int K, N, k0, n0;
    if (z < 2) {   // w1: K=E_(16 tiles -> y), N=M_(64 tiles -> x)
        W = w1 + (size_t)z * E_ * M_; Wt = w1t + (size_t)z * E_ * M_;
        K = E_; N = M_; k0 = blockIdx.y * 32; n0 = blockIdx.x * 32;
    } else {       // w2: K=M_(64 tiles -> x), N=E_(16 tiles -> y)
        W = w2 + (size_t)(z - 2) * M_ * E_; Wt = w2t + (size_t)(z - 2) * M_ * E_;
        K = M_; N = E_; k0 = blockIdx.x * 32; n0 = blockIdx.y * 32;
    }
    int lx = threadIdx.x & 31, ly = threadIdx.x >> 5;
    for (int r = ly; r < 32; r += 8)
        Ts[r][lx] = W[(size_t)(k0 + r) * N + n0 + lx];
    __syncthreads();
    for (int r = ly; r < 32; r += 8)
        Wt[(size_t)(n0 + r) * K + k0 + lx] = __float2bfloat16(Ts[lx][r]);
}

// ---------------- generic transpose+convert (logits weight) ----------------
__global__ __launch_bounds__(256)
void tconv_kernel(const float* __restrict__ W, bf16* __restrict__ Wt, int K, int N) {
    __shared__ float Ts[32][33];
    int k0 = blockIdx.x * 32, n0 = blockIdx.y * 32;
    int lx = threadIdx.x & 31, ly = threadIdx.x >> 5;
    for (int r = ly; r < 32; r += 8)
        Ts[r][lx] = W[(size_t)(k0 + r) * N + n0 + lx];
    __syncthreads();
    for (int r = ly; r < 32; r += 8)
        Wt[(size_t)(n0 + r) * K + k0 + lx] = __float2bfloat16(Ts[lx][r]);
}

// ---------------- layernorm f32 -> bf16 ----------------
__global__ __launch_bounds__(256)
void ln_kernel(const float* __restrict__ x, bf16* __restrict__ y,
               const float* __restrict__ sc, const float* __restrict__ bi) {
    int row = blockIdx.x;
    int t = threadIdx.x;
    const float* xr = x + (size_t)row * E_;
    float2 v = *(const float2*)&xr[t * 2];
    float sum = v.x + v.y;
    float sq = v.x * v.x + v.y * v.y;
    for (int off = 32; off > 0; off >>= 1) {
        sum += __shfl_xor(sum, off);
        sq  += __shfl_xor(sq, off);
    }
    __shared__ float s0[4], s1[4];
    int w = t >> 6;
    if ((t & 63) == 0) { s0[w] = sum; s1[w] = sq; }
    __syncthreads();
    sum = s0[0] + s0[1] + s0[2] + s0[3];
    sq  = s1[0] + s1[1] + s1[2] + s1[3];
    float mu = sum * (1.0f / (float)E_);
    float var = sq * (1.0f / (float)E_) - mu * mu;
    float rs = rsqrtf(var + 1e-6f);
    float2 s2 = *(const float2*)&sc[t * 2];
    float2 b2 = *(const float2*)&bi[t * 2];
    bf16* yr = y + (size_t)row * E_ + t * 2;
    yr[0] = __float2bfloat16((v.x - mu) * rs * s2.x + b2.x);
    yr[1] = __float2bfloat16((v.y - mu) * rs * s2.y + b2.y);
}

// ---------------- bf16 MFMA GEMM (m97 structure, XCD-swizzled) ----------------
// FM = per-wave M fragments (4 -> BM=128, 2 -> BM=64).
// VS = fuse column-sum of bf16-rounded V-range outputs into vsum (atomics).
// Swapped-operand MFMA -> vectorized float4/uint2 epilogue.
template<int OBF, int FM, int VS>
__global__ __launch_bounds__(256)
void gemm_mfma(const bf16* __restrict__ A, const bf16* __restrict__ Wt,
               const float* __restrict__ bias, const float* __restrict__ resid,
               void* __restrict__ Cv, int M, int N, int K, float alpha, int relu,
               float* __restrict__ vsum, int vlo)
{
    __shared__ bf16 As[FM * 32 * 64];
    __shared__ bf16 Bs[128 * 64];
    const int t = threadIdx.x;
    const int lane = t & 63, w = t >> 6;
    int m0, n0;
    {
        int nwg = gridDim.x * gridDim.y;
        int lin = blockIdx.x + gridDim.x * blockIdx.y;
        int q = nwg >> 3, r = nwg & 7;
        int xcd = lin & 7, off8 = lin >> 3;
        int swz = ((xcd < r) ? xcd * (q + 1) : r * (q + 1) + (xcd - r) * q) + off8;
        int gridM = gridDim.y;
        m0 = (swz % gridM) * (FM * 32);
        n0 = (swz / gridM) * 128;
    }
    const int wr = w >> 1, wc = w & 1;
    const int srow = w * 8 + (lane >> 3);
    const int sslot = lane & 7;
    f32x4 acc[FM][4] = {};

    for (int k0 = 0; k0 < K; k0 += 64) {
        __syncthreads();
        #pragma unroll
        for (int i = 0; i < FM; ++i) {
            int r = i * 32 + srow;
            int gslot = sslot ^ (r & 7);
            const bf16* ga = A + (size_t)(m0 + r) * K + k0 + gslot * 8;
            __builtin_amdgcn_global_load_lds((const __attribute__((address_space(1))) void*)ga,
                                             (__attribute__((address_space(3))) void*)&As[r * 64 + sslot * 8],
                                             16, 0, 0);
        }
        #pragma unroll
        for (int i = 0; i < 4; ++i) {
            int r = i * 32 + srow;
            int gslot = sslot ^ (r & 7);
            const bf16* gb = Wt + (size_t)(n0 + r) * K + k0 + gslot * 8;
            __builtin_amdgcn_global_load_lds((const __attribute__((address_space(1))) void*)gb,
                                             (__attribute__((address_space(3))) void*)&Bs[r * 64 + sslot * 8],
                                             16, 0, 0);
        }
        __syncthreads();
        #pragma unroll
        for (int kk = 0; kk < 2; ++kk) {
            short8 af[FM], bq[4];
            const int q = kk * 4 + (lane >> 4);
            #pragma unroll
            for (int m = 0; m < FM; ++m) {
                int r = wr * (FM * 16) + m * 16 + (lane & 15);
                af[m] = *(const short8*)&As[r * 64 + (q ^ (r & 7)) * 8];
            }
            #pragma unroll
            for (int n = 0; n < 4; ++n) {
                int r = wc * 64 + n * 16 + (lane & 15);
                bq[n] = *(const short8*)&Bs[r * 64 + (q ^ (r & 7)) * 8];
            }
            #pragma unroll
            for (int m = 0; m < FM; ++m)
                #pragma unroll
                for (int n = 0; n < 4; ++n)
                    acc[m][n] = __builtin_amdgcn_mfma_f32_16x16x32_bf16(bq[n], af[m], acc[m][n], 0, 0, 0);
        }
    }

    const int lr = lane >> 4, lc = lane & 15;
    float vpart[4][4] = {};
    #pragma unroll
    for (int m = 0; m < FM; ++m) {
        int row = m0 + wr * (FM * 16) + m * 16 + lc;
        #pragma unroll
        for (int n = 0; n < 4; ++n) {
            int colb = n0 + wc * 64 + n * 16 + lr * 4;
            float v0 = acc[m][n][0] * alpha, v1 = acc[m][n][1] * alpha;
            float v2 = acc[m][n][2] * alpha, v3 = acc[m][n][3] * alpha;
            if (bias) {
                float4 bv = *(const float4*)&bias[colb];
                v0 += bv.x; v1 += bv.y; v2 += bv.z; v3 += bv.w;
            }
            if (relu) {
                v0 = fmaxf(v0, 0.0f); v1 = fmaxf(v1, 0.0f);
                v2 = fmaxf(v2, 0.0f); v3 = fmaxf(v3, 0.0f);
            }
            if (resid) {
                float4 rv = *(const float4*)&resid[(size_t)row * N + colb];
                v0 += rv.x; v1 += rv.y; v2 += rv.z; v3 += rv.w;
            }
            if (OBF) {
                uint2 pp = {pack2bf(v0, v1), pack2bf(v2, v3)};
                *(uint2*)((bf16*)Cv + (size_t)row * N + colb) = pp;
                if constexpr (VS) {
                    vpart[n][0] += __uint_as_float(pp.x << 16);
                    vpart[n][1] += __uint_as_float(pp.x & 0xffff0000u);
                    vpart[n][2] += __uint_as_float(pp.y << 16);
                    vpart[n][3] += __uint_as_float(pp.y & 0xffff0000u);
                }
            } else {
                float4 o = {v0, v1, v2, v3};
                *(float4*)((float*)Cv + (size_t)row * N + colb) = o;
            }
        }
    }
    if constexpr (VS) {
        // column sums of this wave's FM*16 rows (all same batch b); 16-lane reduce.
        int bidx = (m0 + wr * (FM * 16)) >> 10;
        #pragma unroll
        for (int n = 0; n < 4; ++n) {
            #pragma unroll
            for (int j = 0; j < 4; ++j) {
                float s = vpart[n][j];
                s += __shfl_xor(s, 1); s += __shfl_xor(s, 2);
                s += __shfl_xor(s, 4); s += __shfl_xor(s, 8);
                vpart[n][j] = s;
            }
            if (lc == 0) {
                int colb = n0 + wc * 64 + n * 16 + lr * 4;
                int rr = colb - vlo;
                if (rr >= 0) {
                    int g = rr >> 10, d = rr & 1023;
                    if (d < 512) {
                        float* dst = vsum + g * (B_ * 512) + bidx * 512 + d;
                        atomicAdd(dst + 0, vpart[n][0]);
                        atomicAdd(dst + 1, vpart[n][1]);
                        atomicAdd(dst + 2, vpart[n][2]);
                        atomicAdd(dst + 3, vpart[n][3]);
                    }
                }
            }
        }
    }
}

// ---------------- MFMA flash attention ----------------
// Block: (b, h, qb). 2 waves = 2 q-halves. 32x32x16 MFMA; swapped QK^T;
// PV as O^T = V^T P^T; V slot includes ks half; P = hi+lo bf16 split.
// Block-sparse skip exact. m<=-5e8 -> vsum/S fallback (fully-masked row).
__global__ __launch_bounds__(128)
void attn_mfma(const bf16* __restrict__ qp, const bf16* __restrict__ kp,
               const bf16* __restrict__ vp, bf16* __restrict__ op,
               const unsigned char* __restrict__ bm,
               const int* __restrict__ targets, const float* __restrict__ srcmask,
               const float* __restrict__ vmean,
               int sq, int sk, int sv, int causal)
{
    __shared__ __align__(16) unsigned char lds[24592];
    unsigned long long* padb = (unsigned long long*)(lds + 24576);

    const int bid = blockIdx.x;
    const int qb = bid & 15, h = (bid >> 4) & 7, b = bid >> 7;
    const int tid = threadIdx.x;
    const int wq = tid >> 6, lane = tid & 63;
    const int h5 = lane >> 5, l31 = lane & 31;

    unsigned char* Ks = lds;
    unsigned char* Vt = lds + 8192;
    unsigned char* Qs = lds + 16384;

    #pragma unroll
    for (int j = 0; j < 4; ++j) {
        int r = wq * 32 + j * 8 + (lane >> 3);
        int g = (lane & 7) ^ (r & 7);
        const bf16* src = qp + (size_t)(b * S_ + qb * 64 + r) * sq + h * 64 + g * 8;
        __builtin_amdgcn_global_load_lds((const __attribute__((address_space(1))) void*)src,
            (__attribute__((address_space(3))) void*)(Qs + wq * 4096 + j * 1024 + lane * 16),
            16, 0, 0);
    }
    __syncthreads();
    short8 qfrag[4];
    {
        int qrow = wq * 32 + l31;
        #pragma unroll
        for (int t = 0; t < 4; ++t) {
            int c = (2 * t + h5) ^ (qrow & 7);
            qfrag[t] = *(const short8*)(Qs + qrow * 128 + c * 16);
        }
    }

    const int q_in = wq * 32 + l31;
    const int qg = qb * 64 + q_in;
    const bool padq = targets[b * S_ + qg] > 0;

    unsigned long long lstpk = 0ULL;
    int myn = 0;
    {
        int kbmax = causal ? qb : 15;
        for (int kb = 0; kb <= kbmax; ++kb)
            if (bm[qb * 16 + kb]) { lstpk |= ((unsigned long long)kb) << (4 * myn); ++myn; }
    }

    float mrun = -3.0e38f, lrun = 0.0f;
    f32x16 acc0 = {}, acc1 = {};

    for (int it = 0; it < myn; ++it) {
        int kb = (int)((lstpk >> (4 * it)) & 15ULL);
        #pragma unroll
        for (int j = 0; j < 4; ++j) {
            int r = j * 16 + wq * 8 + (lane >> 3);
            int g = (lane & 7) ^ (r & 7);
            const bf16* src = kp + (size_t)(b * S_ + kb * 64 + r) * sk + h * 64 + g * 8;
            __builtin_amdgcn_global_load_lds((const __attribute__((address_space(1))) void*)src,
                (__attribute__((address_space(3))) void*)(Ks + (j * 16 + wq * 8) * 128 + lane * 16),
                16, 0, 0);
        }
        #pragma unroll
        for (int itv = 0; itv < 2; ++itv) {
            int k2 = 2 * l31;
            int d0 = h5 * 8 + (wq * 2 + itv) * 16;
            const unsigned short* v0 = (const unsigned short*)vp +
                (size_t)(b * S_ + kb * 64 + k2) * sv + h * 64 + d0;
            short8 va = *(const short8*)v0;
            short8 vb = *(const short8*)(v0 + sv);
            #pragma unroll
            for (int j2 = 0; j2 < 8; ++j2) {
                int d = d0 + j2;
                unsigned int pkv = ((unsigned int)(unsigned short)va[j2]) |
                                   (((unsigned int)(unsigned short)vb[j2]) << 16);
                int off = d * 128 + (((k2 >> 3) ^ (d & 7)) * 16) + (k2 & 7) * 2;
                *(unsigned int*)(Vt + off) = pkv;
            }
        }
        if (wq == 0) {
            int pos = b * S_ + kb * 64 + lane;
            bool pk_ = srcmask ? (srcmask[pos] > 0.0f) : (targets[pos] > 0);
            unsigned long long bits = __ballot(pk_);
            if (lane == 0) padb[0] = bits;
        }
        __syncthreads();
        {
            bool diag = causal && (kb == qb);
            unsigned long long pb = padb[0];
            #pragma unroll
            for (int ks = 0; ks < 2; ++ks) {
                f32x16 sacc = {};
                #pragma unroll
                for (int t = 0; t < 4; ++t) {
                    int row = ks * 32 + l31;
                    int c = (2 * t + h5) ^ (row & 7);
                    short8 kfrag = *(const short8*)(Ks + row * 128 + c * 16);
                    sacc = __builtin_amdgcn_mfma_f32_32x32x16_bf16(kfrag, qfrag[t], sacc, 0, 0, 0);
                }
                float p[16];
                float mloc = -3.0e38f;
                #pragma unroll
                for (int r = 0; r < 16; ++r) {
                    int kl = ks * 32 + (r & 3) + 8 * (r >> 2) + 4 * h5;
                    bool ok = padq && (((pb >> kl) & 1ULL) != 0) && (!diag || kl <= q_in);
                    p[r] = ok ? sacc[r] * 0.125f : -1.0e9f;
                    mloc = fmaxf(mloc, p[r]);
                }
                mloc = fmaxf(mloc, __shfl_xor(mloc, 32));
                float mnew = fmaxf(mrun, mloc);
                float rescale = __expf(mrun - mnew);
                float lsum = 0.0f;
                #pragma unroll
                for (int r = 0; r < 16; ++r) { p[r] = __expf(p[r] - mnew); lsum += p[r]; }
                lsum += __shfl_xor(lsum, 32);
                lrun = lrun * rescale + lsum;
                mrun = mnew;
                acc0 *= rescale;
                acc1 *= rescale;
                unsigned int pk_hi[4][2], pk_lo[4][2];
                #pragma unroll
                for (int t4 = 0; t4 < 4; ++t4)
                    #pragma unroll
                    for (int u = 0; u < 2; ++u) {
                        float a = p[4 * t4 + 2 * u];
                        float c = p[4 * t4 + 2 * u + 1];
                        unsigned int ph = pack2bf(a, c);
                        float ah = __uint_as_float(ph << 16);
                        float ch = __uint_as_float(ph & 0xffff0000u);
                        pk_hi[t4][u] = ph;
                        pk_lo[t4][u] = pack2bf(a - ah, c - ch);
                    }
                #pragma unroll
                for (int Hh = 0; Hh < 2; ++Hh) {
                    unsigned int hu0 = (unsigned int)__shfl_xor((int)pk_hi[2 * Hh + 1][0], 32);
                    unsigned int hu1 = (unsigned int)__shfl_xor((int)pk_hi[2 * Hh + 1][1], 32);
                    unsigned int hl0 = (unsigned int)__shfl_xor((int)pk_hi[2 * Hh][0], 32);
                    unsigned int hl1 = (unsigned int)__shfl_xor((int)pk_hi[2 * Hh][1], 32);
                    uint4v hv = {h5 ? hu0 : pk_hi[2 * Hh][0],
                                 h5 ? hu1 : pk_hi[2 * Hh][1],
                                 h5 ? pk_hi[2 * Hh + 1][0] : hl0,
                                 h5 ? pk_hi[2 * Hh + 1][1] : hl1};
                    short8 bfrag_hi = __builtin_bit_cast(short8, hv);
                    unsigned int lu0 = (unsigned int)__shfl_xor((int)pk_lo[2 * Hh + 1][0], 32);
                    unsigned int lu1 = (unsigned int)__shfl_xor((int)pk_lo[2 * Hh + 1][1], 32);
                    unsigned int ll0 = (unsigned int)__shfl_xor((int)pk_lo[2 * Hh][0], 32);
                    unsigned int ll1 = (unsigned int)__shfl_xor((int)pk_lo[2 * Hh][1], 32);
                    uint4v lv = {h5 ? lu0 : pk_lo[2 * Hh][0],
                                 h5 ? lu1 : pk_lo[2 * Hh][1],
                                 h5 ? pk_lo[2 * Hh + 1][0] : ll0,
                                 h5 ? pk_lo[2 * Hh + 1][1] : ll1};
                    short8 bfrag_lo = __builtin_bit_cast(short8, lv);
                    #pragma unroll
                    for (int f = 0; f < 2; ++f) {
                        int row = f * 32 + l31;
                        int c = (4 * ks + 2 * Hh + h5) ^ (row & 7);
                        short8 vfrag = *(const short8*)(Vt + row * 128 + c * 16);
                        if (f == 0) {
                            acc0 = __builtin_amdgcn_mfma_f32_32x32x16_bf16(vfrag, bfrag_hi, acc0, 0, 0, 0);
                            acc0 = __builtin_amdgcn_mfma_f32_32x32x16_bf16(vfrag, bfrag_lo, acc0, 0, 0, 0);
                        } else {
                            acc1 = __builtin_amdgcn_mfma_f32_32x32x16_bf16(vfrag, bfrag_hi, acc1, 0, 0, 0);
                            acc1 = __builtin_amdgcn_mfma_f32_32x32x16_bf16(vfrag, bfrag_lo, acc1, 0, 0, 0);
                        }
                    }
                }
            }
        }
        __syncthreads();
    }

    bool okrow = mrun > -5.0e8f;
    float inv = okrow ? 1.0f / lrun : 0.0f;
    const float* vmp = vmean + (b * 8 + h) * 64;
    const float invS = 1.0f / (float)S_;
    unsigned short* orow = (unsigned short*)op + (size_t)(b * S_ + qg) * E_ + h * 64;
    #pragma unroll
    for (int f = 0; f < 2; ++f)
        #pragma unroll
        for (int t4 = 0; t4 < 4; ++t4)
            #pragma unroll
            for (int u = 0; u < 2; ++u) {
                int r = 4 * t4 + 2 * u;
                int d = f * 32 + 2 * u + 8 * t4 + 4 * h5;
                float a0 = f ? acc1[r] : acc0[r];
                float a1 = f ? acc1[r + 1] : acc0[r + 1];
                float v0 = a0 * inv;
                float v1 = a1 * inv;
                if (!okrow) { v0 = vmp[d] * invS; v1 = vmp[d + 1] * invS; }
                *(unsigned int*)(orow + d) = pack2bf(v0, v1);
            }
}

extern "C" void kernel_launch(void* const* d_in, const int* in_sizes, int n_in,
                              void* d_out, int out_size, void* d_ws, size_t ws_size,
                              hipStream_t stream)
{
    const float* encoded  = (const float*)d_in[0];
    const float* srcmask  = (const float*)d_in[1];
    const int*   targets  = (const int*)d_in[2];
    const float* table    = (const float*)d_in[3];
    const float* pos      = (const float*)d_in[4];
    const float* ln1_s = (const float*)d_in[5];
    const float* ln1_b = (const float*)d_in[6];
    const float* ln2_s = (const float*)d_in[7];
    const float* ln2_b = (const float*)d_in[8];
    const float* ln3_s = (const float*)d_in[9];
    const float* ln3_b = (const float*)d_in[10];
    const float* self_wq = (const float*)d_in[11];
    const float* self_wk = (const float*)d_in[12];
    const float* self_wv = (const float*)d_in[13];
    const float* self_wo = (const float*)d_in[14];
    const float* cross_wq = (const float*)d_in[15];
    const float* cross_wk = (const float*)d_in[16];
    const float* cross_wv = (const float*)d_in[17];
    const float* cross_wo = (const float*)d_in[18];
    const float* mlp_w1 = (const float*)d_in[19];
    const float* mlp_b1 = (const float*)d_in[20];
    const float* mlp_w2 = (const float*)d_in[21];
    const float* mlp_b2 = (const float*)d_in[22];
    const float* final_s = (const float*)d_in[23];
    const float* final_b = (const float*)d_in[24];
    const float* logit_w = (const float*)d_in[25];
    const float* logit_b = (const float*)d_in[26];
    float* out = (float*)d_out;

    char* ws = (char*)d_ws;
    unsigned char* masks = (unsigned char*)ws;
    size_t off = 1024;
    auto alloc = [&](size_t bytes) {
        char* p = ws + off;
        off += (bytes + 255) & ~(size_t)255;
        return p;
    };
    const size_t RS = (size_t)B_ * S_;   // 2048
    const size_t EE = (size_t)E_ * E_;
    float* y    = (float*)alloc(RS * E_ * 4);
    float* xb   = (float*)alloc(RS * E_ * 4);
    float* zb   = (float*)alloc(RS * E_ * 4);
    bf16* lnb   = (bf16*)alloc(RS * E_ * 2);
    bf16* qkvb  = (bf16*)alloc(RS * 3 * E_ * 2);
    bf16* kvb   = (bf16*)alloc(RS * 4 * E_ * 2);   // [k0|v0|k1|v1] per row
    bf16* qb2   = (bf16*)alloc(RS * E_ * 2);
    bf16* ob    = (bf16*)alloc(RS * E_ * 2);
    bf16* hid   = (bf16*)alloc(RS * M_ * 2);
    bf16* encb  = (bf16*)alloc(RS * E_ * 2);
    float* vmbase = (float*)alloc(4096 * 4);       // vms[2][B][512] + vmc[2][B][512]
    float* vms = vmbase;
    float* vmc = vmbase + 2048;
    bf16* qkv_t = (bf16*)alloc((size_t)L_ * 3 * EE * 2);
    bf16* swo_t = (bf16*)alloc((size_t)L_ * EE * 2);
    bf16* cq_t  = (bf16*)alloc((size_t)L_ * EE * 2);
    bf16* ckv_t = (bf16*)alloc((size_t)L_ * 2 * EE * 2);
    bf16* cwo_t = (bf16*)alloc((size_t)L_ * EE * 2);
    bf16* w1_t  = (bf16*)alloc((size_t)L_ * E_ * M_ * 2);
    bf16* w2_t  = (bf16*)alloc((size_t)L_ * M_ * E_ * 2);
    bf16* wl_t  = (bf16*)alloc((size_t)E_ * V_ * 2);

    const int R = (int)RS;

    prep_kernel<<<3088, 256, 0, stream>>>(targets, table, pos, y, encoded, encb, vmbase);

    {
        TP16 p;
        for (int l = 0; l < L_; ++l) {
            p.s[l * 8 + 0] = self_wq + l * EE;  p.d[l * 8 + 0] = qkv_t + (size_t)l * 3 * EE + 0 * EE;
            p.s[l * 8 + 1] = self_wk + l * EE;  p.d[l * 8 + 1] = qkv_t + (size_t)l * 3 * EE + 1 * EE;
            p.s[l * 8 + 2] = self_wv + l * EE;  p.d[l * 8 + 2] = qkv_t + (size_t)l * 3 * EE + 2 * EE;
            p.s[l * 8 + 3] = self_wo + l * EE;  p.d[l * 8 + 3] = swo_t + (size_t)l * EE;
            p.s[l * 8 + 4] = cross_wq + l * EE; p.d[l * 8 + 4] = cq_t + (size_t)l * EE;
            p.s[l * 8 + 5] = cross_wk + l * EE; p.d[l * 8 + 5] = ckv_t + (size_t)l * 2 * EE + 0 * EE;
            p.s[l * 8 + 6] = cross_wv + l * EE; p.d[l * 8 + 6] = ckv_t + (size_t)l * 2 * EE + 1 * EE;
            p.s[l * 8 + 7] = cross_wo + l * EE; p.d[l * 8 + 7] = cwo_t + (size_t)l * EE;
        }
        dim3 gf(E_ / 32, E_ / 32, 17);
        tconv16m_kernel<<<gf, 256, 0, stream>>>(p, masks);
        dim3 gm(64, 16, 4);
        tconv_mlp_kernel<<<gm, 256, 0, stream>>>(mlp_w1, mlp_w2, w1_t, w2_t);
        dim3 g3(E_ / 32, V_ / 32, 1);
        tconv_kernel<<<g3, 256, 0, stream>>>(logit_w, wl_t, E_, V_);
    }

    dim3 gqkv(3 * E_ / 128, R / 128);
    dim3 gkv4(4 * E_ / 128, R / 128);
    dim3 gp2(E_ / 128, R / 64);        // FM=2 variant for N=512 GEMMs
    dim3 g1(M_ / 128, R / 128);
    dim3 gl(V_ / 128, R / 128);
    const int attn_grid = B_ * H_ * 16;

    // cross K/V for BOTH layers upfront, vmeans fused via atomics
    gemm_mfma<1, 4, 1><<<gkv4, 256, 0, stream>>>(encb, ckv_t, nullptr, nullptr, kvb, R, 4 * E_, E_, 1.0f, 0, vmc, 512);

    for (int l = 0; l < L_; ++l) {
        // ---- self attention ----
        ln_kernel<<<R, 256, 0, stream>>>(y, lnb, ln1_s + l * E_, ln1_b + l * E_);
        gemm_mfma<1, 4, 1><<<gqkv, 256, 0, stream>>>(lnb, qkv_t + (size_t)l * 3 * EE, nullptr, nullptr, qkvb, R, 3 * E_, E_, 1.0f, 0, vms + l * (B_ * 512), 1024);
        attn_mfma<<<attn_grid, 128, 0, stream>>>(qkvb, qkvb + E_, qkvb + 2 * E_, ob, masks + l * 256,
                                                 targets, nullptr, vms + l * (B_ * 512), 3 * E_, 3 * E_, 3 * E_, 1);
        gemm_mfma<0, 2, 0><<<gp2, 256, 0, stream>>>(ob, swo_t + (size_t)l * EE, nullptr, y, xb, R, E_, E_, 1.0f, 0, nullptr, 0);
        // ---- cross attention ----
        ln_kernel<<<R, 256, 0, stream>>>(xb, lnb, ln2_s + l * E_, ln2_b + l * E_);
        gemm_mfma<1, 2, 0><<<gp2, 256, 0, stream>>>(lnb, cq_t + (size_t)l * EE, nullptr, nullptr, qb2, R, E_, E_, 1.0f, 0, nullptr, 0);
        attn_mfma<<<attn_grid, 128, 0, stream>>>(qb2, kvb + (size_t)l * 2 * E_, kvb + (size_t)l * 2 * E_ + E_, ob,
                                                 masks + (2 + l) * 256, targets, srcmask,
                                                 vmc + l * (B_ * 512), E_, 4 * E_, 4 * E_, 0);
        gemm_mfma<0, 2, 0><<<gp2, 256, 0, stream>>>(ob, cwo_t + (size_t)l * EE, nullptr, xb, zb, R, E_, E_, 1.0f, 0, nullptr, 0);
        // ---- MLP ----
        ln_kernel<<<R, 256, 0, stream>>>(zb, lnb, ln3_s + l * E_, ln3_b + l * E_);
        gemm_mfma<1, 4, 0><<<g1, 256, 0, stream>>>(lnb, w1_t + (size_t)l * E_ * M_, mlp_b1 + (size_t)l * M_, nullptr, hid, R, M_, E_, 1.0f, 1, nullptr, 0);
        gemm_mfma<0, 2, 0><<<gp2, 256, 0, stream>>>(hid, w2_t + (size_t)l * M_ * E_, mlp_b2 + (size_t)l * E_, zb, y, R, E_, M_, 1.0f, 0, nullptr, 0);
    }

    ln_kernel<<<R, 256, 0, stream>>>(y, lnb, final_s, final_b);
    gemm_mfma<0, 4, 0><<<gl, 256, 0, stream>>>(lnb, wl_t, logit_b, nullptr, out, R, V_, E_, 1.0f, 0, nullptr, 0);
}

// Round 11
// 724.689 us; speedup vs baseline: 6.2467x; 1.0089x over previous
//
#include <hip/hip_runtime.h>
#include <hip/hip_bf16.h>
#include <stdint.h>

#define B_ 2
#define S_ 1024
#define E_ 512
#define H_ 8
#define D_ 64
#define M_ 2048
#define V_ 32000
#define L_ 2

typedef __hip_bfloat16 bf16;
typedef __attribute__((ext_vector_type(8))) short short8;
typedef __attribute__((ext_vector_type(4))) float f32x4;
typedef __attribute__((ext_vector_type(16))) float f32x16;
typedef __attribute__((ext_vector_type(4))) unsigned int uint4v;

__device__ inline unsigned int pack2bf(float lo, float hi) {
    __hip_bfloat16 a = __float2bfloat16(lo), b = __float2bfloat16(hi);
    unsigned short ua = *(unsigned short*)&a, ub = *(unsigned short*)&b;
    return (unsigned int)ua | ((unsigned int)ub << 16);
}

// ---------------- numpy legacy RandomState (MT19937) ----------------
#define MT_N 624
#define MT_M 397
#define MT_UP   0x80000000u
#define MT_LOW  0x7fffffffu
#define MT_MAT  0x9908b0dfu

__device__ inline unsigned int mt_temper(unsigned int y) {
    y ^= y >> 11;
    y ^= (y << 7) & 0x9d2c5680u;
    y ^= (y << 15) & 0xefc60000u;
    y ^= y >> 18;
    return y;
}

// ---------------- prep: embed + f32->bf16 cvt + zero vsum ----------------
__global__ __launch_bounds__(256)
void prep_kernel(const int* __restrict__ targets, const float* __restrict__ table,
                 const float* __restrict__ pos, float* __restrict__ y,
                 const float* __restrict__ enc, bf16* __restrict__ encb,
                 float* __restrict__ vmbase) {
    int bid = blockIdx.x, t = threadIdx.x;
    if (bid < 2048) {
        int s = bid & (S_ - 1), b = bid >> 10;
        int id = (s == 0) ? 0 : targets[b * S_ + s - 1];
        int c = t * 2;
        float2 e = *(const float2*)&table[(size_t)id * E_ + c];
        float2 p = *(const float2*)&pos[(size_t)s * E_ + c];
        float2 o = {e.x + p.x, e.y + p.y};
        *(float2*)&y[(size_t)bid * E_ + c] = o;
    } else if (bid < 3072) {
        int i = ((bid - 2048) * 256 + t) * 4;
        float4 v = *(const float4*)&enc[i];
        encb[i + 0] = __float2bfloat16(v.x);
        encb[i + 1] = __float2bfloat16(v.y);
        encb[i + 2] = __float2bfloat16(v.z);
        encb[i + 3] = __float2bfloat16(v.w);
    } else {
        vmbase[(bid - 3072) * 256 + t] = 0.0f;   // 4096 f32 = vms(2048) + vmc(2048)
    }
}

// ---------------- fused: 16x E_xE_ transpose+convert + BigBird masks ----------------
struct TP16 { const float* s[16]; bf16* d[16]; };
__global__ __launch_bounds__(256)
void tconv16m_kernel(TP16 p, unsigned char* masks) {
    __shared__ float Ts[32][33];
    __shared__ unsigned int mto[4][MT_N];
    __shared__ unsigned int mtn[4][MT_N];
    const int z = blockIdx.z;
    if (z == 16) {
        if (blockIdx.x != 0 || blockIdx.y != 0) return;
        const int w = threadIdx.x >> 6, lane = threadIdx.x & 63;
        const unsigned int seeds[4] = {1000u, 1001u, 0u, 1u};
        unsigned char* m = masks + w * 256;
        for (int idx = lane; idx < 256; idx += 64) {
            int i = idx >> 4, j = idx & 15;
            bool v = (j >= i - 1 && j <= i + 1) || i == 0 || i == 15 || j == 0 || j == 15;
            m[idx] = v ? 1 : 0;
        }
        if (lane == 0) {
            unsigned int s = seeds[w];
            for (int i = 0; i < MT_N; ++i) {
                mto[w][i] = s;
                s = 1812433253u * (s ^ (s >> 30)) + (unsigned int)(i + 1);
            }
        }
        __syncthreads();
        for (int i = lane; i < MT_N - MT_M; i += 64) {
            unsigned int y = (mto[w][i] & MT_UP) | (mto[w][i + 1] & MT_LOW);
            mtn[w][i] = mto[w][i + MT_M] ^ (y >> 1) ^ ((y & 1u) ? MT_MAT : 0u);
        }
        __syncthreads();
        for (int i = 227 + lane; i < 454; i += 64) {
            unsigned int y = (mto[w][i] & MT_UP) | (mto[w][i + 1] & MT_LOW);
            mtn[w][i] = mtn[w][i - 227] ^ (y >> 1) ^ ((y & 1u) ? MT_MAT : 0u);
        }
        __syncthreads();
        for (int i = 454 + lane; i < MT_N - 1; i += 64) {
            unsigned int y = (mto[w][i] & MT_UP) | (mto[w][i + 1] & MT_LOW);
            mtn[w][i] = mtn[w][i - 227] ^ (y >> 1) ^ ((y & 1u) ? MT_MAT : 0u);
        }
        __syncthreads();
        if (lane == 0) {
            unsigned int y = (mto[w][MT_N - 1] & MT_UP) | (mtn[w][0] & MT_LOW);
            mtn[w][MT_N - 1] = mtn[w][MT_M - 1] ^ (y >> 1) ^ ((y & 1u) ? MT_MAT : 0u);
        }
        __syncthreads();
        if (lane == 0) {
            int idx = 0;
            for (int i = 0; i < 16; ++i) {
                unsigned long long arr = 0xFEDCBA9876543210ULL;
                for (int k = 15; k > 0; --k) {
                    unsigned int mask = k;
                    mask |= mask >> 1; mask |= mask >> 2; mask |= mask >> 4;
                    unsigned int j;
                    for (;;) {
                        if (idx >= MT_N) {
                            int i2 = 0;
                            for (; i2 < MT_N - MT_M; ++i2) {
                                unsigned int y2 = (mtn[w][i2] & MT_UP) | (mtn[w][i2 + 1] & MT_LOW);
                                mtn[w][i2] = mtn[w][i2 + MT_M] ^ (y2 >> 1) ^ ((y2 & 1u) ? MT_MAT : 0u);
                            }
                            for (; i2 < MT_N - 1; ++i2) {
                                unsigned int y2 = (mtn[w][i2] & MT_UP) | (mtn[w][i2 + 1] & MT_LOW);
                                mtn[w][i2] = mtn[w][i2 - 227] ^ (y2 >> 1) ^ ((y2 & 1u) ? MT_MAT : 0u);
                            }
                            unsigned int y2 = (mtn[w][MT_N - 1] & MT_UP) | (mtn[w][0] & MT_LOW);
                            mtn[w][MT_N - 1] = mtn[w][MT_M - 1] ^ (y2 >> 1) ^ ((y2 & 1u) ? MT_MAT : 0u);
                            idx = 0;
                        }
                        j = mt_temper(mtn[w][idx++]) & mask;
                        if (j <= (unsigned int)k) break;
                    }
                    unsigned int a = (unsigned int)(arr >> (4 * k)) & 15u;
                    unsigned int bnib = (unsigned int)(arr >> (4 * j)) & 15u;
                    arr &= ~((15ULL << (4 * k)) | (15ULL << (4 * j)));
                    arr |= ((unsigned long long)a << (4 * j)) | ((unsigned long long)bnib << (4 * k));
                }
                m[i * 16 + ((arr >> 0) & 15)] = 1;
                m[i * 16 + ((arr >> 4) & 15)] = 1;
                m[i * 16 + ((arr >> 8) & 15)] = 1;
            }
        }
        return;
    }
    const float* W = p.s[z];
    bf16* Wt = p.d[z];
    int k0 = blockIdx.x * 32, n0 = blockIdx.y * 32;
    int lx = threadIdx.x & 31, ly = threadIdx.x >> 5;
    for (int r = ly; r < 32; r += 8)
        Ts[r][lx] = W[(size_t)(k0 + r) * E_ + n0 + lx];
    __syncthreads();
    for (int r = ly; r < 32; r += 8)
        Wt[(size_t)(n0 + r) * E_ + k0 + lx] = __float2bfloat16(Ts[lx][r]);
}

// ---------------- mlp w1 + w2 transpose+convert (one launch) ----------------
__global__ __launch_bounds__(256)
void tconv_mlp_kernel(const float* __restrict__ w1, const float* __restrict__ w2,
                      bf16* __restrict__ w1t, bf16* __restrict__ w2t) {
    __shared__ float Ts[32][33];
    int z = blockIdx.z;
    const float* W; bf16* Wt; int K, N, k0, n0;
    if (z < 2) {
        W = w1 + (size_t)z * E_ * M_; Wt = w1t + (size_t)z * E_ * M_;
        K = E_; N = M_; k0 = blockIdx.y * 32; n0 = blockIdx.x * 32;
    } else {
        W = w2 + (size_t)(z - 2) * M_ * E_; Wt = w2t + (size_t)(z - 2) * M_ * E_;
        K = M_; N = E_; k0 = blockIdx.x * 32; n0 = blockIdx.y * 32;
    }
    int lx = threadIdx.x & 31, ly = threadIdx.x >> 5;
    for (int r = ly; r < 32; r += 8)
        Ts[r][lx] = W[(size_t)(k0 + r) * N + n0 + lx];
    __syncthreads();
    for (int r = ly; r < 32; r += 8)
        Wt[(size_t)(n0 + r) * K + k0 + lx] = __float2bfloat16(Ts[lx][r]);
}

// ---------------- generic transpose+convert (logits weight) ----------------
__global__ __launch_bounds__(256)
void tconv_kernel(const float* __restrict__ W, bf16* __restrict__ Wt, int K, int N) {
    __shared__ float Ts[32][33];
    int k0 = blockIdx.x * 32, n0 = blockIdx.y * 32;
    int lx = threadIdx.x & 31, ly = threadIdx.x >> 5;
    for (int r = ly; r < 32; r += 8)
        Ts[r][lx] = W[(size_t)(k0 + r) * N + n0 + lx];
    __syncthreads();
    for (int r = ly; r < 32; r += 8)
        Wt[(size_t)(n0 + r) * K + k0 + lx] = __float2bfloat16(Ts[lx][r]);
}

// ---------------- layernorm f32 -> bf16 ----------------
__global__ __launch_bounds__(256)
void ln_kernel(const float* __restrict__ x, bf16* __restrict__ y,
               const float* __restrict__ sc, const float* __restrict__ bi) {
    int row = blockIdx.x;
    int t = threadIdx.x;
    const float* xr = x + (size_t)row * E_;
    float2 v = *(const float2*)&xr[t * 2];
    float sum = v.x + v.y;
    float sq = v.x * v.x + v.y * v.y;
    for (int off = 32; off > 0; off >>= 1) {
        sum += __shfl_xor(sum, off);
        sq  += __shfl_xor(sq, off);
    }
    __shared__ float s0[4], s1[4];
    int w = t >> 6;
    if ((t & 63) == 0) { s0[w] = sum; s1[w] = sq; }
    __syncthreads();
    sum = s0[0] + s0[1] + s0[2] + s0[3];
    sq  = s1[0] + s1[1] + s1[2] + s1[3];
    float mu = sum * (1.0f / (float)E_);
    float var = sq * (1.0f / (float)E_) - mu * mu;
    float rs = rsqrtf(var + 1e-6f);
    float2 s2 = *(const float2*)&sc[t * 2];
    float2 b2 = *(const float2*)&bi[t * 2];
    bf16* yr = y + (size_t)row * E_ + t * 2;
    yr[0] = __float2bfloat16((v.x - mu) * rs * s2.x + b2.x);
    yr[1] = __float2bfloat16((v.y - mu) * rs * s2.y + b2.y);
}

// ---------------- bf16 MFMA GEMM (m97 structure, XCD-swizzled) ----------------
// FM = per-wave M fragments (4 -> BM=128, 2 -> BM=64).
// VS = fuse column-sum of bf16-rounded V-range outputs into vsum (atomics).
// Swapped-operand MFMA -> vectorized float4/uint2 epilogue.
template<int OBF, int FM, int VS>
__global__ __launch_bounds__(256)
void gemm_mfma(const bf16* __restrict__ A, const bf16* __restrict__ Wt,
               const float* __restrict__ bias, const float* __restrict__ resid,
               void* __restrict__ Cv, int M, int N, int K, float alpha, int relu,
               float* __restrict__ vsum, int vlo)
{
    __shared__ bf16 As[FM * 32 * 64];
    __shared__ bf16 Bs[128 * 64];
    const int t = threadIdx.x;
    const int lane = t & 63, w = t >> 6;
    int m0, n0;
    {
        int nwg = gridDim.x * gridDim.y;
        int lin = blockIdx.x + gridDim.x * blockIdx.y;
        int q = nwg >> 3, r = nwg & 7;
        int xcd = lin & 7, off8 = lin >> 3;
        int swz = ((xcd < r) ? xcd * (q + 1) : r * (q + 1) + (xcd - r) * q) + off8;
        int gridM = gridDim.y;
        m0 = (swz % gridM) * (FM * 32);
        n0 = (swz / gridM) * 128;
    }
    const int wr = w >> 1, wc = w & 1;
    const int srow = w * 8 + (lane >> 3);
    const int sslot = lane & 7;
    f32x4 acc[FM][4] = {};

    for (int k0 = 0; k0 < K; k0 += 64) {
        __syncthreads();
        #pragma unroll
        for (int i = 0; i < FM; ++i) {
            int r = i * 32 + srow;
            int gslot = sslot ^ (r & 7);
            const bf16* ga = A + (size_t)(m0 + r) * K + k0 + gslot * 8;
            __builtin_amdgcn_global_load_lds((const __attribute__((address_space(1))) void*)ga,
                                             (__attribute__((address_space(3))) void*)&As[r * 64 + sslot * 8],
                                             16, 0, 0);
        }
        #pragma unroll
        for (int i = 0; i < 4; ++i) {
            int r = i * 32 + srow;
            int gslot = sslot ^ (r & 7);
            const bf16* gb = Wt + (size_t)(n0 + r) * K + k0 + gslot * 8;
            __builtin_amdgcn_global_load_lds((const __attribute__((address_space(1))) void*)gb,
                                             (__attribute__((address_space(3))) void*)&Bs[r * 64 + sslot * 8],
                                             16, 0, 0);
        }
        __syncthreads();
        #pragma unroll
        for (int kk = 0; kk < 2; ++kk) {
            short8 af[FM], bq[4];
            const int q = kk * 4 + (lane >> 4);
            #pragma unroll
            for (int m = 0; m < FM; ++m) {
                int r = wr * (FM * 16) + m * 16 + (lane & 15);
                af[m] = *(const short8*)&As[r * 64 + (q ^ (r & 7)) * 8];
            }
            #pragma unroll
            for (int n = 0; n < 4; ++n) {
                int r = wc * 64 + n * 16 + (lane & 15);
                bq[n] = *(const short8*)&Bs[r * 64 + (q ^ (r & 7)) * 8];
            }
            #pragma unroll
            for (int m = 0; m < FM; ++m)
                #pragma unroll
                for (int n = 0; n < 4; ++n)
                    acc[m][n] = __builtin_amdgcn_mfma_f32_16x16x32_bf16(bq[n], af[m], acc[m][n], 0, 0, 0);
        }
    }

    const int lr = lane >> 4, lc = lane & 15;
    float vpart[4][4] = {};
    #pragma unroll
    for (int m = 0; m < FM; ++m) {
        int row = m0 + wr * (FM * 16) + m * 16 + lc;
        #pragma unroll
        for (int n = 0; n < 4; ++n) {
            int colb = n0 + wc * 64 + n * 16 + lr * 4;
            float v0 = acc[m][n][0] * alpha, v1 = acc[m][n][1] * alpha;
            float v2 = acc[m][n][2] * alpha, v3 = acc[m][n][3] * alpha;
            if (bias) {
                float4 bv = *(const float4*)&bias[colb];
                v0 += bv.x; v1 += bv.y; v2 += bv.z; v3 += bv.w;
            }
            if (relu) {
                v0 = fmaxf(v0, 0.0f); v1 = fmaxf(v1, 0.0f);
                v2 = fmaxf(v2, 0.0f); v3 = fmaxf(v3, 0.0f);
            }
            if (resid) {
                float4 rv = *(const float4*)&resid[(size_t)row * N + colb];
                v0 += rv.x; v1 += rv.y; v2 += rv.z; v3 += rv.w;
            }
            if (OBF) {
                uint2 pp = {pack2bf(v0, v1), pack2bf(v2, v3)};
                *(uint2*)((bf16*)Cv + (size_t)row * N + colb) = pp;
                if constexpr (VS) {
                    vpart[n][0] += __uint_as_float(pp.x << 16);
                    vpart[n][1] += __uint_as_float(pp.x & 0xffff0000u);
                    vpart[n][2] += __uint_as_float(pp.y << 16);
                    vpart[n][3] += __uint_as_float(pp.y & 0xffff0000u);
                }
            } else {
                float4 o = {v0, v1, v2, v3};
                *(float4*)((float*)Cv + (size_t)row * N + colb) = o;
            }
        }
    }
    if constexpr (VS) {
        int bidx = (m0 + wr * (FM * 16)) >> 10;
        #pragma unroll
        for (int n = 0; n < 4; ++n) {
            #pragma unroll
            for (int j = 0; j < 4; ++j) {
                float s = vpart[n][j];
                s += __shfl_xor(s, 1); s += __shfl_xor(s, 2);
                s += __shfl_xor(s, 4); s += __shfl_xor(s, 8);
                vpart[n][j] = s;
            }
            if (lc == 0) {
                int colb = n0 + wc * 64 + n * 16 + lr * 4;
                int rr = colb - vlo;
                if (rr >= 0) {
                    int g = rr >> 10, d = rr & 1023;
                    if (d < 512) {
                        float* dst = vsum + g * (B_ * 512) + bidx * 512 + d;
                        atomicAdd(dst + 0, vpart[n][0]);
                        atomicAdd(dst + 1, vpart[n][1]);
                        atomicAdd(dst + 2, vpart[n][2]);
                        atomicAdd(dst + 3, vpart[n][3]);
                    }
                }
            }
        }
    }
}

// ---------------- MFMA flash attention ----------------
__global__ __launch_bounds__(128)
void attn_mfma(const bf16* __restrict__ qp, const bf16* __restrict__ kp,
               const bf16* __restrict__ vp, bf16* __restrict__ op,
               const unsigned char* __restrict__ bm,
               const int* __restrict__ targets, const float* __restrict__ srcmask,
               const float* __restrict__ vmean,
               int sq, int sk, int sv, int causal)
{
    __shared__ __align__(16) unsigned char lds[24592];
    unsigned long long* padb = (unsigned long long*)(lds + 24576);

    const int bid = blockIdx.x;
    const int qb = bid & 15, h = (bid >> 4) & 7, b = bid >> 7;
    const int tid = threadIdx.x;
    const int wq = tid >> 6, lane = tid & 63;
    const int h5 = lane >> 5, l31 = lane & 31;

    unsigned char* Ks = lds;
    unsigned char* Vt = lds + 8192;
    unsigned char* Qs = lds + 16384;

    #pragma unroll
    for (int j = 0; j < 4; ++j) {
        int r = wq * 32 + j * 8 + (lane >> 3);
        int g = (lane & 7) ^ (r & 7);
        const bf16* src = qp + (size_t)(b * S_ + qb * 64 + r) * sq + h * 64 + g * 8;
        __builtin_amdgcn_global_load_lds((const __attribute__((address_space(1))) void*)src,
            (__attribute__((address_space(3))) void*)(Qs + wq * 4096 + j * 1024 + lane * 16),
            16, 0, 0);
    }
    __syncthreads();
    short8 qfrag[4];
    {
        int qrow = wq * 32 + l31;
        #pragma unroll
        for (int t = 0; t < 4; ++t) {
            int c = (2 * t + h5) ^ (qrow & 7);
            qfrag[t] = *(const short8*)(Qs + qrow * 128 + c * 16);
        }
    }

    const int q_in = wq * 32 + l31;
    const int qg = qb * 64 + q_in;
    const bool padq = targets[b * S_ + qg] > 0;

    unsigned long long lstpk = 0ULL;
    int myn = 0;
    {
        int kbmax = causal ? qb : 15;
        for (int kb = 0; kb <= kbmax; ++kb)
            if (bm[qb * 16 + kb]) { lstpk |= ((unsigned long long)kb) << (4 * myn); ++myn; }
    }

    float mrun = -3.0e38f, lrun = 0.0f;
    f32x16 acc0 = {}, acc1 = {};

    for (int it = 0; it < myn; ++it) {
        int kb = (int)((lstpk >> (4 * it)) & 15ULL);
        #pragma unroll
        for (int j = 0; j < 4; ++j) {
            int r = j * 16 + wq * 8 + (lane >> 3);
            int g = (lane & 7) ^ (r & 7);
            const bf16* src = kp + (size_t)(b * S_ + kb * 64 + r) * sk + h * 64 + g * 8;
            __builtin_amdgcn_global_load_lds((const __attribute__((address_space(1))) void*)src,
                (__attribute__((address_space(3))) void*)(Ks + (j * 16 + wq * 8) * 128 + lane * 16),
                16, 0, 0);
        }
        #pragma unroll
        for (int itv = 0; itv < 2; ++itv) {
            int k2 = 2 * l31;
            int d0 = h5 * 8 + (wq * 2 + itv) * 16;
            const unsigned short* v0 = (const unsigned short*)vp +
                (size_t)(b * S_ + kb * 64 + k2) * sv + h * 64 + d0;
            short8 va = *(const short8*)v0;
            short8 vb = *(const short8*)(v0 + sv);
            #pragma unroll
            for (int j2 = 0; j2 < 8; ++j2) {
                int d = d0 + j2;
                unsigned int pkv = ((unsigned int)(unsigned short)va[j2]) |
                                   (((unsigned int)(unsigned short)vb[j2]) << 16);
                int off = d * 128 + (((k2 >> 3) ^ (d & 7)) * 16) + (k2 & 7) * 2;
                *(unsigned int*)(Vt + off) = pkv;
            }
        }
        if (wq == 0) {
            int pos = b * S_ + kb * 64 + lane;
            bool pk_ = srcmask ? (srcmask[pos] > 0.0f) : (targets[pos] > 0);
            unsigned long long bits = __ballot(pk_);
            if (lane == 0) padb[0] = bits;
        }
        __syncthreads();
        {
            bool diag = causal && (kb == qb);
            unsigned long long pb = padb[0];
            #pragma unroll
            for (int ks = 0; ks < 2; ++ks) {
                f32x16 sacc = {};
                #pragma unroll
                for (int t = 0; t < 4; ++t) {
                    int row = ks * 32 + l31;
                    int c = (2 * t + h5) ^ (row & 7);
                    short8 kfrag = *(const short8*)(Ks + row * 128 + c * 16);
                    sacc = __builtin_amdgcn_mfma_f32_32x32x16_bf16(kfrag, qfrag[t], sacc, 0, 0, 0);
                }
                float p[16];
                float mloc = -3.0e38f;
                #pragma unroll
                for (int r = 0; r < 16; ++r) {
                    int kl = ks * 32 + (r & 3) + 8 * (r >> 2) + 4 * h5;
                    bool ok = padq && (((pb >> kl) & 1ULL) != 0) && (!diag || kl <= q_in);
                    p[r] = ok ? sacc[r] * 0.125f : -1.0e9f;
                    mloc = fmaxf(mloc, p[r]);
                }
                mloc = fmaxf(mloc, __shfl_xor(mloc, 32));
                float mnew = fmaxf(mrun, mloc);
                float rescale = __expf(mrun - mnew);
                float lsum = 0.0f;
                #pragma unroll
                for (int r = 0; r < 16; ++r) { p[r] = __expf(p[r] - mnew); lsum += p[r]; }
                lsum += __shfl_xor(lsum, 32);
                lrun = lrun * rescale + lsum;
                mrun = mnew;
                acc0 *= rescale;
                acc1 *= rescale;
                unsigned int pk_hi[4][2], pk_lo[4][2];
                #pragma unroll
                for (int t4 = 0; t4 < 4; ++t4)
                    #pragma unroll
                    for (int u = 0; u < 2; ++u) {
                        float a = p[4 * t4 + 2 * u];
                        float c = p[4 * t4 + 2 * u + 1];
                        unsigned int ph = pack2bf(a, c);
                        float ah = __uint_as_float(ph << 16);
                        float ch = __uint_as_float(ph & 0xffff0000u);
                        pk_hi[t4][u] = ph;
                        pk_lo[t4][u] = pack2bf(a - ah, c - ch);
                    }
                #pragma unroll
                for (int Hh = 0; Hh < 2; ++Hh) {
                    unsigned int hu0 = (unsigned int)__shfl_xor((int)pk_hi[2 * Hh + 1][0], 32);
                    unsigned int hu1 = (unsigned int)__shfl_xor((int)pk_hi[2 * Hh + 1][1], 32);
                    unsigned int hl0 = (unsigned int)__shfl_xor((int)pk_hi[2 * Hh][0], 32);
                    unsigned int hl1 = (unsigned int)__shfl_xor((int)pk_hi[2 * Hh][1], 32);
                    uint4v hv = {h5 ? hu0 : pk_hi[2 * Hh][0],
                                 h5 ? hu1 : pk_hi[2 * Hh][1],
                                 h5 ? pk_hi[2 * Hh + 1][0] : hl0,
                                 h5 ? pk_hi[2 * Hh + 1][1] : hl1};
                    short8 bfrag_hi = __builtin_bit_cast(short8, hv);
                    unsigned int lu0 = (unsigned int)__shfl_xor((int)pk_lo[2 * Hh + 1][0], 32);
                    unsigned int lu1 = (unsigned int)__shfl_xor((int)pk_lo[2 * Hh + 1][1], 32);
                    unsigned int ll0 = (unsigned int)__shfl_xor((int)pk_lo[2 * Hh][0], 32);
                    unsigned int ll1 = (unsigned int)__shfl_xor((int)pk_lo[2 * Hh][1], 32);
                    uint4v lv = {h5 ? lu0 : pk_lo[2 * Hh][0],
                                 h5 ? lu1 : pk_lo[2 * Hh][1],
                                 h5 ? pk_lo[2 * Hh + 1][0] : ll0,
                                 h5 ? pk_lo[2 * Hh + 1][1] : ll1};
                    short8 bfrag_lo = __builtin_bit_cast(short8, lv);
                    #pragma unroll
                    for (int f = 0; f < 2; ++f) {
                        int row = f * 32 + l31;
                        int c = (4 * ks + 2 * Hh + h5) ^ (row & 7);
                        short8 vfrag = *(const short8*)(Vt + row * 128 + c * 16);
                        if (f == 0) {
                            acc0 = __builtin_amdgcn_mfma_f32_32x32x16_bf16(vfrag, bfrag_hi, acc0, 0, 0, 0);
                            acc0 = __builtin_amdgcn_mfma_f32_32x32x16_bf16(vfrag, bfrag_lo, acc0, 0, 0, 0);
                        } else {
                            acc1 = __builtin_amdgcn_mfma_f32_32x32x16_bf16(vfrag, bfrag_hi, acc1, 0, 0, 0);
                            acc1 = __builtin_amdgcn_mfma_f32_32x32x16_bf16(vfrag, bfrag_lo, acc1, 0, 0, 0);
                        }
                    }
                }
            }
        }
        __syncthreads();
    }

    bool okrow = mrun > -5.0e8f;
    float inv = okrow ? 1.0f / lrun : 0.0f;
    const float* vmp = vmean + (b * 8 + h) * 64;
    const float invS = 1.0f / (float)S_;
    unsigned short* orow = (unsigned short*)op + (size_t)(b * S_ + qg) * E_ + h * 64;
    #pragma unroll
    for (int f = 0; f < 2; ++f)
        #pragma unroll
        for (int t4 = 0; t4 < 4; ++t4)
            #pragma unroll
            for (int u = 0; u < 2; ++u) {
                int r = 4 * t4 + 2 * u;
                int d = f * 32 + 2 * u + 8 * t4 + 4 * h5;
                float a0 = f ? acc1[r] : acc0[r];
                float a1 = f ? acc1[r + 1] : acc0[r + 1];
                float v0 = a0 * inv;
                float v1 = a1 * inv;
                if (!okrow) { v0 = vmp[d] * invS; v1 = vmp[d + 1] * invS; }
                *(unsigned int*)(orow + d) = pack2bf(v0, v1);
            }
}

extern "C" void kernel_launch(void* const* d_in, const int* in_sizes, int n_in,
                              void* d_out, int out_size, void* d_ws, size_t ws_size,
                              hipStream_t stream)
{
    const float* encoded  = (const float*)d_in[0];
    const float* srcmask  = (const float*)d_in[1];
    const int*   targets  = (const int*)d_in[2];
    const float* table    = (const float*)d_in[3];
    const float* pos      = (const float*)d_in[4];
    const float* ln1_s = (const float*)d_in[5];
    const float* ln1_b = (const float*)d_in[6];
    const float* ln2_s = (const float*)d_in[7];
    const float* ln2_b = (const float*)d_in[8];
    const float* ln3_s = (const float*)d_in[9];
    const float* ln3_b = (const float*)d_in[10];
    const float* self_wq = (const float*)d_in[11];
    const float* self_wk = (const float*)d_in[12];
    const float* self_wv = (const float*)d_in[13];
    const float* self_wo = (const float*)d_in[14];
    const float* cross_wq = (const float*)d_in[15];
    const float* cross_wk = (const float*)d_in[16];
    const float* cross_wv = (const float*)d_in[17];
    const float* cross_wo = (const float*)d_in[18];
    const float* mlp_w1 = (const float*)d_in[19];
    const float* mlp_b1 = (const float*)d_in[20];
    const float* mlp_w2 = (const float*)d_in[21];
    const float* mlp_b2 = (const float*)d_in[22];
    const float* final_s = (const float*)d_in[23];
    const float* final_b = (const float*)d_in[24];
    const float* logit_w = (const float*)d_in[25];
    const float* logit_b = (const float*)d_in[26];
    float* out = (float*)d_out;

    char* ws = (char*)d_ws;
    unsigned char* masks = (unsigned char*)ws;
    size_t off = 1024;
    auto alloc = [&](size_t bytes) {
        char* p = ws + off;
        off += (bytes + 255) & ~(size_t)255;
        return p;
    };
    const size_t RS = (size_t)B_ * S_;   // 2048
    const size_t EE = (size_t)E_ * E_;
    float* y    = (float*)alloc(RS * E_ * 4);
    float* xb   = (float*)alloc(RS * E_ * 4);
    float* zb   = (float*)alloc(RS * E_ * 4);
    bf16* lnb   = (bf16*)alloc(RS * E_ * 2);
    bf16* qkvb  = (bf16*)alloc(RS * 3 * E_ * 2);
    bf16* kvb   = (bf16*)alloc(RS * 4 * E_ * 2);   // [k0|v0|k1|v1] per row
    bf16* qb2   = (bf16*)alloc(RS * E_ * 2);
    bf16* ob    = (bf16*)alloc(RS * E_ * 2);
    bf16* hid   = (bf16*)alloc(RS * M_ * 2);
    bf16* encb  = (bf16*)alloc(RS * E_ * 2);
    float* vmbase = (float*)alloc(4096 * 4);       // vms[2][B][512] + vmc[2][B][512]
    float* vms = vmbase;
    float* vmc = vmbase + 2048;
    bf16* qkv_t = (bf16*)alloc((size_t)L_ * 3 * EE * 2);
    bf16* swo_t = (bf16*)alloc((size_t)L_ * EE * 2);
    bf16* cq_t  = (bf16*)alloc((size_t)L_ * EE * 2);
    bf16* ckv_t = (bf16*)alloc((size_t)L_ * 2 * EE * 2);
    bf16* cwo_t = (bf16*)alloc((size_t)L_ * EE * 2);
    bf16* w1_t  = (bf16*)alloc((size_t)L_ * E_ * M_ * 2);
    bf16* w2_t  = (bf16*)alloc((size_t)L_ * M_ * E_ * 2);
    bf16* wl_t  = (bf16*)alloc((size_t)E_ * V_ * 2);

    const int R = (int)RS;

    prep_kernel<<<3088, 256, 0, stream>>>(targets, table, pos, y, encoded, encb, vmbase);

    {
        TP16 p;
        for (int l = 0; l < L_; ++l) {
            p.s[l * 8 + 0] = self_wq + l * EE;  p.d[l * 8 + 0] = qkv_t + (size_t)l * 3 * EE + 0 * EE;
            p.s[l * 8 + 1] = self_wk + l * EE;  p.d[l * 8 + 1] = qkv_t + (size_t)l * 3 * EE + 1 * EE;
            p.s[l * 8 + 2] = self_wv + l * EE;  p.d[l * 8 + 2] = qkv_t + (size_t)l * 3 * EE + 2 * EE;
            p.s[l * 8 + 3] = self_wo + l * EE;  p.d[l * 8 + 3] = swo_t + (size_t)l * EE;
            p.s[l * 8 + 4] = cross_wq + l * EE; p.d[l * 8 + 4] = cq_t + (size_t)l * EE;
            p.s[l * 8 + 5] = cross_wk + l * EE; p.d[l * 8 + 5] = ckv_t + (size_t)l * 2 * EE + 0 * EE;
            p.s[l * 8 + 6] = cross_wv + l * EE; p.d[l * 8 + 6] = ckv_t + (size_t)l * 2 * EE + 1 * EE;
            p.s[l * 8 + 7] = cross_wo + l * EE; p.d[l * 8 + 7] = cwo_t + (size_t)l * EE;
        }
        dim3 gf(E_ / 32, E_ / 32, 17);
        tconv16m_kernel<<<gf, 256, 0, stream>>>(p, masks);
        dim3 gm(64, 16, 4);
        tconv_mlp_kernel<<<gm, 256, 0, stream>>>(mlp_w1, mlp_w2, w1_t, w2_t);
        dim3 g3(E_ / 32, V_ / 32, 1);
        tconv_kernel<<<g3, 256, 0, stream>>>(logit_w, wl_t, E_, V_);
    }

    // all GEMMs at BM=64 (FM=2) for max workgroup count / latency hiding
    dim3 gqkv2(3 * E_ / 128, R / 64);    // 12 x 32 = 384 WGs
    dim3 gkv42(4 * E_ / 128, R / 64);    // 16 x 32 = 512 WGs
    dim3 gp2(E_ / 128, R / 64);          // 4 x 32 = 128 WGs
    dim3 g12(M_ / 128, R / 64);          // 16 x 32 = 512 WGs
    dim3 gl2(V_ / 128, R / 64);          // 250 x 32 = 8000 WGs
    const int attn_grid = B_ * H_ * 16;

    // cross K/V for BOTH layers upfront, vmeans fused via atomics
    gemm_mfma<1, 2, 1><<<gkv42, 256, 0, stream>>>(encb, ckv_t, nullptr, nullptr, kvb, R, 4 * E_, E_, 1.0f, 0, vmc, 512);

    for (int l = 0; l < L_; ++l) {
        // ---- self attention ----
        ln_kernel<<<R, 256, 0, stream>>>(y, lnb, ln1_s + l * E_, ln1_b + l * E_);
        gemm_mfma<1, 2, 1><<<gqkv2, 256, 0, stream>>>(lnb, qkv_t + (size_t)l * 3 * EE, nullptr, nullptr, qkvb, R, 3 * E_, E_, 1.0f, 0, vms + l * (B_ * 512), 1024);
        attn_mfma<<<attn_grid, 128, 0, stream>>>(qkvb, qkvb + E_, qkvb + 2 * E_, ob, masks + l * 256,
                                                 targets, nullptr, vms + l * (B_ * 512), 3 * E_, 3 * E_, 3 * E_, 1);
        gemm_mfma<0, 2, 0><<<gp2, 256, 0, stream>>>(ob, swo_t + (size_t)l * EE, nullptr, y, xb, R, E_, E_, 1.0f, 0, nullptr, 0);
        // ---- cross attention ----
        ln_kernel<<<R, 256, 0, stream>>>(xb, lnb, ln2_s + l * E_, ln2_b + l * E_);
        gemm_mfma<1, 2, 0><<<gp2, 256, 0, stream>>>(lnb, cq_t + (size_t)l * EE, nullptr, nullptr, qb2, R, E_, E_, 1.0f, 0, nullptr, 0);
        attn_mfma<<<attn_grid, 128, 0, stream>>>(qb2, kvb + (size_t)l * 2 * E_, kvb + (size_t)l * 2 * E_ + E_, ob,
                                                 masks + (2 + l) * 256, targets, srcmask,
                                                 vmc + l * (B_ * 512), E_, 4 * E_, 4 * E_, 0);
        gemm_mfma<0, 2, 0><<<gp2, 256, 0, stream>>>(ob, cwo_t + (size_t)l * EE, nullptr, xb, zb, R, E_, E_, 1.0f, 0, nullptr, 0);
        // ---- MLP ----
        ln_kernel<<<R, 256, 0, stream>>>(zb, lnb, ln3_s + l * E_, ln3_b + l * E_);
        gemm_mfma<1, 2, 0><<<g12, 256, 0, stream>>>(lnb, w1_t + (size_t)l * E_ * M_, mlp_b1 + (size_t)l * M_, nullptr, hid, R, M_, E_, 1.0f, 1, nullptr, 0);
        gemm_mfma<0, 2, 0><<<gp2, 256, 0, stream>>>(hid, w2_t + (size_t)l * M_ * E_, mlp_b2 + (size_t)l * E_, zb, y, R, E_, M_, 1.0f, 0, nullptr, 0);
    }

    ln_kernel<<<R, 256, 0, stream>>>(y, lnb, final_s, final_b);
    gemm_mfma<0, 2, 0><<<gl2, 256, 0, stream>>>(lnb, wl_t, logit_b, nullptr, out, R, V_, E_, 1.0f, 0, nullptr, 0);
}